// Round 1
// baseline (769.612 us; speedup 1.0000x reference)
//
#include <hip/hip_runtime.h>
#include <math.h>

#define NN   65536
#define BB   128
#define GGR  512
#define EE   65536
#define INF_ 512
#define HIDD 64

static __device__ __forceinline__ float sigmoidf_(float x){ return 1.0f/(1.0f+__expf(-x)); }
static __device__ __forceinline__ float lrelu_(float x){ return x>=0.0f ? x : 0.2f*x; }

// ---------------- hc1/hc2 = root @ W_claim{1,2}  [128,64] ----------------
__global__ void k_hc(const float* __restrict__ root, const float* __restrict__ Wc1,
                     const float* __restrict__ Wc2, float* __restrict__ hc1,
                     float* __restrict__ hc2){
  int b = blockIdx.x, f = threadIdx.x;
  const float* r = root + (size_t)b*INF_;
  float a1 = 0.f, a2 = 0.f;
  for (int k = 0; k < INF_; ++k){
    float rv = r[k];
    a1 = fmaf(rv, Wc1[k*HIDD+f], a1);
    a2 = fmaf(rv, Wc2[k*HIDD+f], a2);
  }
  hc1[b*HIDD+f] = a1; hc2[b*HIDD+f] = a2;
}

// ---------------- h1 = gated(x@W_post1, hc1) : [N,128] ----------------
__global__ __launch_bounds__(256) void k_gemm1(const float* __restrict__ x,
                                               const float* __restrict__ Wp,
                                               const float* __restrict__ hc1,
                                               float* __restrict__ h1){
  __shared__ __align__(16) float As[16][64];
  __shared__ __align__(16) float Bs[16][64];
  int tid = threadIdx.x;
  int node0 = blockIdx.x * 64;
  int tx = tid & 15, ty = tid >> 4;
  int nl = tid >> 2, kk = (tid & 3) * 4;
  int kr = tid >> 4, ff = (tid & 15) * 4;
  float acc[4][4] = {};
  for (int k0 = 0; k0 < 512; k0 += 16){
    float4 va = *(const float4*)&x[(size_t)(node0+nl)*512 + k0 + kk];
    As[kk+0][nl]=va.x; As[kk+1][nl]=va.y; As[kk+2][nl]=va.z; As[kk+3][nl]=va.w;
    *(float4*)&Bs[kr][ff] = *(const float4*)&Wp[(size_t)(k0+kr)*64 + ff];
    __syncthreads();
    #pragma unroll
    for (int k = 0; k < 16; ++k){
      float4 a4 = *(const float4*)&As[k][ty*4];
      float4 b4 = *(const float4*)&Bs[k][tx*4];
      float av[4]={a4.x,a4.y,a4.z,a4.w}, bv[4]={b4.x,b4.y,b4.z,b4.w};
      #pragma unroll
      for (int i = 0; i < 4; ++i)
        #pragma unroll
        for (int j = 0; j < 4; ++j) acc[i][j] = fmaf(av[i], bv[j], acc[i][j]);
    }
    __syncthreads();
  }
  int g = node0 >> 9;
  float4 hcv = *(const float4*)&hc1[g*64 + tx*4];
  float hc[4] = {hcv.x, hcv.y, hcv.z, hcv.w};
  #pragma unroll
  for (int i = 0; i < 4; ++i){
    int n = node0 + ty*4 + i;
    float fo[4], ho[4];
    #pragma unroll
    for (int j = 0; j < 4; ++j){
      float hx = acc[i][j];
      float gg = sigmoidf_(hx + hc[j]);
      fo[j] = gg*hx + (1.f-gg)*hc[j];
      ho[j] = hx;
    }
    *(float4*)&h1[(size_t)n*128 + tx*4]      = make_float4(fo[0],fo[1],fo[2],fo[3]);
    *(float4*)&h1[(size_t)n*128 + 64 + tx*4] = make_float4(ho[0],ho[1],ho[2],ho[3]);
  }
}

// ------------- h = A@W [N,256] tile + per-head att logits (asrc/adst) -------------
template<int K>
__global__ __launch_bounds__(256) void k_gemm_att(const float* __restrict__ A,
                                                  const float* __restrict__ W,
                                                  const float* __restrict__ att_s,
                                                  const float* __restrict__ att_d,
                                                  float* __restrict__ Hout,
                                                  float* __restrict__ asrc,
                                                  float* __restrict__ adst){
  __shared__ __align__(16) float As[16][64];
  __shared__ __align__(16) float Bs[16][64];
  __shared__ float red[64][17];
  int tid = threadIdx.x;
  int node0 = blockIdx.x * 64;
  int head = blockIdx.y;
  int tx = tid & 15, ty = tid >> 4;
  int nl = tid >> 2, kk = (tid & 3) * 4;
  int kr = tid >> 4, ff = (tid & 15) * 4;
  float acc[4][4] = {};
  for (int k0 = 0; k0 < K; k0 += 16){
    float4 va = *(const float4*)&A[(size_t)(node0+nl)*K + k0 + kk];
    As[kk+0][nl]=va.x; As[kk+1][nl]=va.y; As[kk+2][nl]=va.z; As[kk+3][nl]=va.w;
    *(float4*)&Bs[kr][ff] = *(const float4*)&W[(size_t)(k0+kr)*256 + head*64 + ff];
    __syncthreads();
    #pragma unroll
    for (int k = 0; k < 16; ++k){
      float4 a4 = *(const float4*)&As[k][ty*4];
      float4 b4 = *(const float4*)&Bs[k][tx*4];
      float av[4]={a4.x,a4.y,a4.z,a4.w}, bv[4]={b4.x,b4.y,b4.z,b4.w};
      #pragma unroll
      for (int i = 0; i < 4; ++i)
        #pragma unroll
        for (int j = 0; j < 4; ++j) acc[i][j] = fmaf(av[i], bv[j], acc[i][j]);
    }
    __syncthreads();
  }
  #pragma unroll
  for (int i = 0; i < 4; ++i){
    int n = node0 + ty*4 + i;
    *(float4*)&Hout[(size_t)n*256 + head*64 + tx*4] =
        make_float4(acc[i][0], acc[i][1], acc[i][2], acc[i][3]);
  }
  // asrc = sum_c h*att_src  (reduce over tx groups via LDS)
  float4 sv = *(const float4*)&att_s[head*64 + tx*4];
  float s_[4] = {sv.x, sv.y, sv.z, sv.w};
  #pragma unroll
  for (int i = 0; i < 4; ++i){
    float p = acc[i][0]*s_[0] + acc[i][1]*s_[1] + acc[i][2]*s_[2] + acc[i][3]*s_[3];
    red[ty*4+i][tx] = p;
  }
  __syncthreads();
  if (tid < 64){
    float s = 0.f;
    #pragma unroll
    for (int t = 0; t < 16; ++t) s += red[tid][t];
    asrc[(size_t)(node0+tid)*4 + head] = s;
  }
  __syncthreads();
  float4 dv = *(const float4*)&att_d[head*64 + tx*4];
  float d_[4] = {dv.x, dv.y, dv.z, dv.w};
  #pragma unroll
  for (int i = 0; i < 4; ++i){
    float p = acc[i][0]*d_[0] + acc[i][1]*d_[1] + acc[i][2]*d_[2] + acc[i][3]*d_[3];
    red[ty*4+i][tx] = p;
  }
  __syncthreads();
  if (tid < 64){
    float s = 0.f;
    #pragma unroll
    for (int t = 0; t < 16; ++t) s += red[tid][t];
    adst[(size_t)(node0+tid)*4 + head] = s;
  }
}

// ---------------- CSR build ----------------
__global__ void k_count(const int* __restrict__ ei, int* __restrict__ deg){
  int t = blockIdx.x*256 + threadIdx.x;
  int s = ei[t], d = ei[EE + t];
  atomicAdd(&deg[d], 1);
  atomicAdd(&deg[s], 1);
}

__global__ void k_scan1(const int* __restrict__ deg, int* __restrict__ offa,
                        int* __restrict__ bsum){
  __shared__ int sm[256];
  int tid = threadIdx.x, idx = blockIdx.x*256 + tid;
  int v = deg[idx] + 1;                 // +1 self-loop
  sm[tid] = v; __syncthreads();
  for (int o = 1; o < 256; o <<= 1){
    int t = (tid >= o) ? sm[tid-o] : 0;
    __syncthreads();
    sm[tid] += t;
    __syncthreads();
  }
  offa[idx] = sm[tid] - v;
  if (tid == 255) bsum[blockIdx.x] = sm[255];
}

__global__ void k_scan2(int* __restrict__ bsum){
  __shared__ int sm[256];
  int tid = threadIdx.x;
  int v = bsum[tid];
  sm[tid] = v; __syncthreads();
  for (int o = 1; o < 256; o <<= 1){
    int t = (tid >= o) ? sm[tid-o] : 0;
    __syncthreads();
    sm[tid] += t;
    __syncthreads();
  }
  bsum[tid] = sm[tid] - v;
}

__global__ void k_scan3(int* __restrict__ offa, const int* __restrict__ bsum){
  int idx = blockIdx.x*256 + threadIdx.x;
  offa[idx] += bsum[idx >> 8];
}

__global__ void k_fill(const int* __restrict__ ei, const int* __restrict__ offa,
                       int* __restrict__ cur, int* __restrict__ elist){
  int t = blockIdx.x*256 + threadIdx.x;
  int s = ei[t], d = ei[EE + t];
  int p = atomicAdd(&cur[d], 1); elist[offa[d] + p] = s;   // TD edge
  p = atomicAdd(&cur[s], 1);     elist[offa[s] + p] = d;   // BU (flipped) edge
  p = atomicAdd(&cur[t], 1);     elist[offa[t] + p] = t;   // self-loop (E==N)
}

// ------------- GAT softmax-aggregate; LAYER1: concat+b1+relu, LAYER2: mean+b2+relu -------------
template<int LAYER>
__global__ __launch_bounds__(256) void k_agg(const int* __restrict__ offa,
                                             const int* __restrict__ deg,
                                             const int* __restrict__ elist,
                                             const float* __restrict__ h,
                                             const float* __restrict__ asrc,
                                             const float* __restrict__ adst,
                                             const float* __restrict__ bias,
                                             float* __restrict__ out){
  int tid = threadIdx.x;
  int wave = tid >> 6, lane = tid & 63;
  int grp = lane >> 4, l = lane & 15;           // 4 dst nodes per wave, 16 lanes each
  int n = blockIdx.x*16 + wave*4 + grp;
  int o0 = offa[n], cnt = deg[n] + 1;
  float4 adv = *(const float4*)&adst[(size_t)n*4];
  float ad[4] = {adv.x, adv.y, adv.z, adv.w};
  // pass 1: per-head max over incoming edges
  float m[4] = {-1e30f, -1e30f, -1e30f, -1e30f};
  for (int i = l; i < cnt; i += 16){
    int s = elist[o0 + i];
    float4 asv = *(const float4*)&asrc[(size_t)s*4];
    float as_[4] = {asv.x, asv.y, asv.z, asv.w};
    #pragma unroll
    for (int hh = 0; hh < 4; ++hh){
      float e = lrelu_(as_[hh] + ad[hh]);
      m[hh] = fmaxf(m[hh], e);
    }
  }
  #pragma unroll
  for (int mask = 1; mask < 16; mask <<= 1)
    #pragma unroll
    for (int hh = 0; hh < 4; ++hh) m[hh] = fmaxf(m[hh], __shfl_xor(m[hh], mask));
  // pass 2: accumulate exp-weighted features; lane owns 16 channels (c = l*16..)
  int myh = l >> 2;
  float mm = m[myh];
  float den = 0.f;
  float accv[16] = {};
  for (int i = 0; i < cnt; ++i){
    int s = elist[o0 + i];
    float4 asv = *(const float4*)&asrc[(size_t)s*4];
    float as_[4] = {asv.x, asv.y, asv.z, asv.w};
    float e = lrelu_(as_[myh] + ad[myh]);
    float ex = __expf(e - mm);
    den += ex;
    const float4* hp = (const float4*)&h[(size_t)s*256 + l*16];
    #pragma unroll
    for (int r = 0; r < 4; ++r){
      float4 hv = hp[r];
      accv[r*4+0] = fmaf(ex, hv.x, accv[r*4+0]);
      accv[r*4+1] = fmaf(ex, hv.y, accv[r*4+1]);
      accv[r*4+2] = fmaf(ex, hv.z, accv[r*4+2]);
      accv[r*4+3] = fmaf(ex, hv.w, accv[r*4+3]);
    }
  }
  float inv = 1.0f / den;
  if (LAYER == 1){
    #pragma unroll
    for (int r = 0; r < 4; ++r){
      int c = l*16 + r*4;
      float4 bv = *(const float4*)&bias[c];
      float4 o;
      o.x = fmaxf(accv[r*4+0]*inv + bv.x, 0.f);
      o.y = fmaxf(accv[r*4+1]*inv + bv.y, 0.f);
      o.z = fmaxf(accv[r*4+2]*inv + bv.z, 0.f);
      o.w = fmaxf(accv[r*4+3]*inv + bv.w, 0.f);
      *(float4*)&out[(size_t)n*256 + c] = o;
    }
  } else {
    #pragma unroll
    for (int r = 0; r < 16; ++r) accv[r] *= inv;
    #pragma unroll
    for (int r = 0; r < 16; ++r){
      accv[r] += __shfl_xor(accv[r], 4);
      accv[r] += __shfl_xor(accv[r], 8);
    }
    if (l < 4){
      #pragma unroll
      for (int r = 0; r < 4; ++r){
        int c = l*16 + r*4;
        float4 bv = *(const float4*)&bias[c];
        float4 o;
        o.x = fmaxf(accv[r*4+0]*0.25f + bv.x, 0.f);
        o.y = fmaxf(accv[r*4+1]*0.25f + bv.y, 0.f);
        o.z = fmaxf(accv[r*4+2]*0.25f + bv.z, 0.f);
        o.w = fmaxf(accv[r*4+3]*0.25f + bv.w, 0.f);
        *(float4*)&out[(size_t)n*64 + c] = o;
      }
    }
  }
}

// ------------- PostLevelAttention2: x3 [N,512] from xr [N,256] -------------
__global__ __launch_bounds__(256) void k_post2(const float* __restrict__ xr,
                                               const float* __restrict__ Wp2,
                                               const float* __restrict__ hc2,
                                               float* __restrict__ x3){
  __shared__ __align__(16) float Ws[64*64];
  __shared__ __align__(16) float xs[4][256];
  int tid = threadIdx.x;
  for (int i = tid*4; i < 4096; i += 1024)
    *(float4*)&Ws[i] = *(const float4*)&Wp2[i];
  __syncthreads();
  int wave = tid >> 6, f = tid & 63;
  int wid = blockIdx.x*4 + wave;
  for (int it = 0; it < 4; ++it){
    int n = wid*4 + it;
    *(float4*)&xs[wave][f*4] = *(const float4*)&xr[(size_t)n*256 + f*4];
    __syncthreads();
    int g = n >> 9;
    float hc = hc2[g*64 + f];
    #pragma unroll
    for (int hd = 0; hd < 4; ++hd){
      float a = 0.f;
      for (int h2 = 0; h2 < 64; h2 += 4){
        float4 xv = *(const float4*)&xs[wave][hd*64 + h2];
        a = fmaf(xv.x, Ws[(h2+0)*64+f], a);
        a = fmaf(xv.y, Ws[(h2+1)*64+f], a);
        a = fmaf(xv.z, Ws[(h2+2)*64+f], a);
        a = fmaf(xv.w, Ws[(h2+3)*64+f], a);
      }
      float gg = sigmoidf_(a + hc);
      x3[(size_t)n*512 + hd*128 + f]      = gg*a + (1.f-gg)*hc;
      x3[(size_t)n*512 + hd*128 + 64 + f] = a;
    }
    __syncthreads();
  }
}

// ------------- beta = softmax(tanh(h_joint@W_fc+b)); partial graph sums -------------
__global__ __launch_bounds__(256) void k_pool(const float* __restrict__ xr2,
                                              const float* __restrict__ Wfc,
                                              const float* __restrict__ bfc,
                                              float* __restrict__ shat,
                                              float* __restrict__ ssum){
  __shared__ __align__(16) float Ws2[192*64];    // W_fc rows 64..255
  __shared__ __align__(16) float hjs[4][192];
  __shared__ float rs[64];
  __shared__ float baseS[64];
  int tid = threadIdx.x;
  int gph = blockIdx.x >> 2;
  for (int i = tid*4; i < 192*64; i += 1024)
    *(float4*)&Ws2[i] = *(const float4*)&Wfc[64*64 + i];
  if (tid < 64) rs[tid] = xr2[(size_t)(gph << 9)*64 + tid];
  __syncthreads();
  if (tid < 64){
    // first 64 rows of W_fc see only the (per-graph constant) root features
    float b = bfc[tid];
    for (int j = 0; j < 64; ++j) b = fmaf(rs[j], Wfc[j*64 + tid], b);
    baseS[tid] = b;
  }
  __syncthreads();
  int wave = tid >> 6, f = tid & 63;
  int base = blockIdx.x*128 + wave*32;
  float rv = rs[f];
  float acc_sh = 0.f, acc_s = 0.f;
  for (int it = 0; it < 32; ++it){
    int n = base + it;
    float xv = xr2[(size_t)n*64 + f];
    hjs[wave][f]       = xv;
    hjs[wave][64 + f]  = xv*rv;
    hjs[wave][128 + f] = fabsf(rv - xv);
    __syncthreads();
    float a = baseS[f];
    for (int j = 0; j < 192; j += 4){
      float4 hv = *(const float4*)&hjs[wave][j];
      a = fmaf(hv.x, Ws2[(j+0)*64+f], a);
      a = fmaf(hv.y, Ws2[(j+1)*64+f], a);
      a = fmaf(hv.z, Ws2[(j+2)*64+f], a);
      a = fmaf(hv.w, Ws2[(j+3)*64+f], a);
    }
    float t = tanhf(a);
    float mx = t;
    #pragma unroll
    for (int mask = 1; mask < 64; mask <<= 1) mx = fmaxf(mx, __shfl_xor(mx, mask));
    float e = __expf(t - mx);
    float s = e;
    #pragma unroll
    for (int mask = 1; mask < 64; mask <<= 1) s += __shfl_xor(s, mask);
    float beta = e / s;
    acc_sh = fmaf(beta, xv, acc_sh);
    acc_s += xv;
    __syncthreads();
  }
  atomicAdd(&shat[gph*64 + f], acc_sh);
  atomicAdd(&ssum[gph*64 + f], acc_s);
}

// ------------- final logits + log_softmax -------------
__global__ void k_final(const float* __restrict__ shat, const float* __restrict__ ssum,
                        const float* __restrict__ Wc, const float* __restrict__ bc,
                        float* __restrict__ outp){
  int g = threadIdx.x;   // 128 graphs
  float l0 = bc[0], l1 = bc[1], l2 = bc[2], l3 = bc[3];
  const float s512 = 1.0f/512.0f;
  for (int j = 0; j < 64; ++j){
    float sh = shat[g*64 + j]*s512;
    float ss = ssum[g*64 + j]*s512;
    float4 w1 = *(const float4*)&Wc[j*4];
    float4 w2 = *(const float4*)&Wc[(64+j)*4];
    l0 = fmaf(sh, w1.x, fmaf(ss, w2.x, l0));
    l1 = fmaf(sh, w1.y, fmaf(ss, w2.y, l1));
    l2 = fmaf(sh, w1.z, fmaf(ss, w2.z, l2));
    l3 = fmaf(sh, w1.w, fmaf(ss, w2.w, l3));
  }
  float mx = fmaxf(fmaxf(l0,l1), fmaxf(l2,l3));
  float s = __expf(l0-mx)+__expf(l1-mx)+__expf(l2-mx)+__expf(l3-mx);
  float lse = mx + logf(s);
  outp[g*4+0] = l0 - lse;
  outp[g*4+1] = l1 - lse;
  outp[g*4+2] = l2 - lse;
  outp[g*4+3] = l3 - lse;
}

extern "C" void kernel_launch(void* const* d_in, const int* in_sizes, int n_in,
                              void* d_out, int out_size, void* d_ws, size_t ws_size,
                              hipStream_t stream){
  const float* x        = (const float*)d_in[0];
  const float* root     = (const float*)d_in[1];
  const int*   ei       = (const int*)d_in[2];
  const float* W_post1  = (const float*)d_in[5];
  const float* W_claim1 = (const float*)d_in[6];
  const float* W1       = (const float*)d_in[7];
  const float* att_src1 = (const float*)d_in[8];
  const float* att_dst1 = (const float*)d_in[9];
  const float* b1       = (const float*)d_in[10];
  const float* W_post2  = (const float*)d_in[11];
  const float* W_claim2 = (const float*)d_in[12];
  const float* W2       = (const float*)d_in[13];
  const float* att_src2 = (const float*)d_in[14];
  const float* att_dst2 = (const float*)d_in[15];
  const float* b2       = (const float*)d_in[16];
  const float* W_fc     = (const float*)d_in[17];
  const float* b_fc     = (const float*)d_in[18];
  const float* W_clf    = (const float*)d_in[19];
  const float* b_clf    = (const float*)d_in[20];
  float* out = (float*)d_out;

  char* w = (char*)d_ws;
  size_t o = 0;
  auto alloc = [&](size_t bytes)->char*{ char* p = w + o; o += (bytes + 255) & ~(size_t)255; return p; };
  float* R1   = (float*)alloc((size_t)NN*512*4);   // h1 | h2, later x3
  float* R2   = (float*)alloc((size_t)NN*256*4);   // xr, later h3
  float* R3   = (float*)alloc((size_t)NN*64*4);    // xr2
  float* asrc = (float*)alloc((size_t)NN*4*4);
  float* adst = (float*)alloc((size_t)NN*4*4);
  float* hc1  = (float*)alloc(128*64*4);
  float* hc2  = (float*)alloc(128*64*4);
  int*   deg  = (int*)alloc((size_t)NN*4);
  int*   offa = (int*)alloc((size_t)NN*4);
  int*   cur  = (int*)alloc((size_t)NN*4);
  int*   bsum = (int*)alloc(256*4);
  int*   elist= (int*)alloc((size_t)(2*EE+NN)*4);
  float* shat = (float*)alloc(128*64*4);
  float* ssumv= (float*)alloc(128*64*4);

  float* h1 = R1;                       // [N,128]
  float* h2 = R1 + (size_t)NN*128;      // [N,256]
  float* x3 = R1;                       // [N,512] (h1/h2 dead by then)
  float* xr = R2;                       // [N,256]
  float* h3 = R2;                       // [N,256] (xr dead by then)
  float* xr2 = R3;                      // [N,64]

  hipMemsetAsync(deg,   0, (size_t)NN*4, stream);
  hipMemsetAsync(cur,   0, (size_t)NN*4, stream);
  hipMemsetAsync(shat,  0, 128*64*4, stream);
  hipMemsetAsync(ssumv, 0, 128*64*4, stream);

  k_hc<<<128, 64, 0, stream>>>(root, W_claim1, W_claim2, hc1, hc2);
  k_gemm1<<<1024, 256, 0, stream>>>(x, W_post1, hc1, h1);
  k_gemm_att<128><<<dim3(1024,4), 256, 0, stream>>>(h1, W1, att_src1, att_dst1, h2, asrc, adst);
  k_count<<<256, 256, 0, stream>>>(ei, deg);
  k_scan1<<<256, 256, 0, stream>>>(deg, offa, bsum);
  k_scan2<<<1, 256, 0, stream>>>(bsum);
  k_scan3<<<256, 256, 0, stream>>>(offa, bsum);
  k_fill<<<256, 256, 0, stream>>>(ei, offa, cur, elist);
  k_agg<1><<<4096, 256, 0, stream>>>(offa, deg, elist, h2, asrc, adst, b1, xr);
  k_post2<<<4096, 256, 0, stream>>>(xr, W_post2, hc2, x3);
  k_gemm_att<512><<<dim3(1024,4), 256, 0, stream>>>(x3, W2, att_src2, att_dst2, h3, asrc, adst);
  k_agg<2><<<4096, 256, 0, stream>>>(offa, deg, elist, h3, asrc, adst, b2, xr2);
  k_pool<<<512, 256, 0, stream>>>(xr2, W_fc, b_fc, shat, ssumv);
  k_final<<<1, 128, 0, stream>>>(shat, ssumv, W_clf, b_clf, out);
  (void)in_sizes; (void)n_in; (void)out_size; (void)ws_size;
}

// Round 2
// 561.022 us; speedup vs baseline: 1.3718x; 1.3718x over previous
//
#include <hip/hip_runtime.h>
#include <math.h>

#define NN   65536
#define BB   128
#define GGR  512
#define EE   65536
#define INF_ 512
#define HIDD 64

typedef __attribute__((ext_vector_type(8))) short bf16x8;
typedef __attribute__((ext_vector_type(4))) float f32x4;
typedef unsigned short ushort_t;
typedef unsigned int uint_t;

static __device__ __forceinline__ float sigmoidf_(float x){ return 1.0f/(1.0f+__expf(-x)); }
static __device__ __forceinline__ float lrelu_(float x){ return x>=0.0f ? x : 0.2f*x; }

// f32 -> bf16 bits, round-to-nearest-even
static __device__ __forceinline__ ushort_t f2b(float f){
  union { float f; uint_t u; } v; v.f = f;
  uint_t u = v.u;
  uint_t r = (u + 0x7fffu + ((u >> 16) & 1u)) >> 16;
  return (ushort_t)r;
}
// bf16 bits -> f32 (exact)
static __device__ __forceinline__ float b2f(uint_t u16){
  union { uint_t u; float f; } v; v.u = u16 << 16; return v.f;
}

// ---------------- hc1/hc2 = root @ W_claim{1,2}  [128,64] ----------------
__global__ void k_hc(const float* __restrict__ root, const float* __restrict__ Wc1,
                     const float* __restrict__ Wc2, float* __restrict__ hc1,
                     float* __restrict__ hc2){
  int b = blockIdx.x, f = threadIdx.x;
  const float* r = root + (size_t)b*INF_;
  float a1 = 0.f, a2 = 0.f;
  for (int k = 0; k < INF_; ++k){
    float rv = r[k];
    a1 = fmaf(rv, Wc1[k*HIDD+f], a1);
    a2 = fmaf(rv, Wc2[k*HIDD+f], a2);
  }
  hc1[b*HIDD+f] = a1; hc2[b*HIDD+f] = a2;
}

// -------------- transpose+cast weights: dst[c*K+k] = bf16(src[k*C+c]) --------------
__global__ void k_tcast(const float* __restrict__ src, ushort_t* __restrict__ dst,
                        int K, int C){
  int idx = blockIdx.x*256 + threadIdx.x;
  if (idx >= K*C) return;
  int k = idx / C, c = idx - k*C;
  dst[(size_t)c*K + k] = f2b(src[idx]);
}

// -------- h1 = gated(x@W_post1, hc1) via MFMA; writes [N,128] bf16 --------
__global__ __launch_bounds__(256) void k_gemm1_mfma(
    const float* __restrict__ x,        // [N,512] f32
    const ushort_t* __restrict__ Wt,    // [64,512] bf16 (W_post1^T)
    const float* __restrict__ hc1,      // [128,64]
    ushort_t* __restrict__ h1b){        // [N,128] bf16
  int tid = threadIdx.x;
  int w = tid >> 6, lane = tid & 63;
  int lr = lane & 15, lk = lane >> 4;
  int n0 = blockIdx.x * 64;
  int arow = n0 + w*16 + lr;
  f32x4 acc[4];
  #pragma unroll
  for (int ci = 0; ci < 4; ++ci) acc[ci] = (f32x4){0.f,0.f,0.f,0.f};
  const float* Ap = x + (size_t)arow*512 + lk*8;
  const ushort_t* Bb = Wt + (size_t)lr*512 + lk*8;
  for (int k0 = 0; k0 < 512; k0 += 32){
    float4 a0 = *(const float4*)(Ap + k0);
    float4 a1 = *(const float4*)(Ap + k0 + 4);
    bf16x8 af;
    af[0]=(short)f2b(a0.x); af[1]=(short)f2b(a0.y); af[2]=(short)f2b(a0.z); af[3]=(short)f2b(a0.w);
    af[4]=(short)f2b(a1.x); af[5]=(short)f2b(a1.y); af[6]=(short)f2b(a1.z); af[7]=(short)f2b(a1.w);
    #pragma unroll
    for (int ci = 0; ci < 4; ++ci){
      bf16x8 bfv = *(const bf16x8*)(Bb + (size_t)ci*16*512 + k0);
      acc[ci] = __builtin_amdgcn_mfma_f32_16x16x32_bf16(af, bfv, acc[ci], 0, 0, 0);
    }
  }
  int g = n0 >> 9;
  #pragma unroll
  for (int ci = 0; ci < 4; ++ci){
    int col = ci*16 + lr;
    float hc = hc1[g*64 + col];
    #pragma unroll
    for (int q = 0; q < 4; ++q){
      int row = n0 + w*16 + lk*4 + q;
      float hx = acc[ci][q];
      float gg = sigmoidf_(hx + hc);
      float fo = gg*hx + (1.f-gg)*hc;
      h1b[(size_t)row*128 + col]      = f2b(fo);
      h1b[(size_t)row*128 + 64 + col] = f2b(hx);
    }
  }
}

// ---- GAT linear: H = A@W [N,256] bf16-in/bf16-out MFMA + fused att logits ----
// block = 64 rows x 256 cols; wave w == head w (cols 64w..64w+63)
template<int K>
__global__ __launch_bounds__(256) void k_gat_mfma(
    const ushort_t* __restrict__ A,     // [N,K] bf16
    const ushort_t* __restrict__ Wt,    // [256,K] bf16 (W^T)
    const float* __restrict__ att_s,    // [4,64]
    const float* __restrict__ att_d,    // [4,64]
    ushort_t* __restrict__ Hout,        // [N,256] bf16
    float* __restrict__ asrc,           // [N,4]
    float* __restrict__ adst){          // [N,4]
  int tid = threadIdx.x;
  int w = tid >> 6, lane = tid & 63;
  int lr = lane & 15, lk = lane >> 4;
  int n0 = blockIdx.x * 64;
  int c0 = w * 64;
  f32x4 acc[4][4];
  #pragma unroll
  for (int ri = 0; ri < 4; ++ri)
    #pragma unroll
    for (int ci = 0; ci < 4; ++ci) acc[ri][ci] = (f32x4){0.f,0.f,0.f,0.f};
  const ushort_t* Ab = A + (size_t)(n0 + lr)*K + lk*8;
  const ushort_t* Bb = Wt + (size_t)(c0 + lr)*K + lk*8;
  for (int k0 = 0; k0 < K; k0 += 32){
    bf16x8 af[4], bfv[4];
    #pragma unroll
    for (int ri = 0; ri < 4; ++ri)
      af[ri] = *(const bf16x8*)(Ab + (size_t)ri*16*K + k0);
    #pragma unroll
    for (int ci = 0; ci < 4; ++ci)
      bfv[ci] = *(const bf16x8*)(Bb + (size_t)ci*16*K + k0);
    #pragma unroll
    for (int ri = 0; ri < 4; ++ri)
      #pragma unroll
      for (int ci = 0; ci < 4; ++ci)
        acc[ri][ci] = __builtin_amdgcn_mfma_f32_16x16x32_bf16(af[ri], bfv[ci], acc[ri][ci], 0, 0, 0);
  }
  float as_[4], ad_[4];
  #pragma unroll
  for (int ci = 0; ci < 4; ++ci){
    as_[ci] = att_s[c0 + ci*16 + lr];
    ad_[ci] = att_d[c0 + ci*16 + lr];
  }
  #pragma unroll
  for (int ri = 0; ri < 4; ++ri){
    #pragma unroll
    for (int q = 0; q < 4; ++q){
      int row = n0 + ri*16 + lk*4 + q;
      float ps = 0.f, pd = 0.f;
      #pragma unroll
      for (int ci = 0; ci < 4; ++ci){
        float v = acc[ri][ci][q];
        Hout[(size_t)row*256 + c0 + ci*16 + lr] = f2b(v);
        ps = fmaf(v, as_[ci], ps);
        pd = fmaf(v, ad_[ci], pd);
      }
      #pragma unroll
      for (int m = 1; m < 16; m <<= 1){
        ps += __shfl_xor(ps, m);
        pd += __shfl_xor(pd, m);
      }
      if (lr == 0){
        asrc[(size_t)row*4 + w] = ps;
        adst[(size_t)row*4 + w] = pd;
      }
    }
  }
}

// ---------------- CSR build ----------------
__global__ void k_count(const int* __restrict__ ei, int* __restrict__ deg){
  int t = blockIdx.x*256 + threadIdx.x;
  int s = ei[t], d = ei[EE + t];
  atomicAdd(&deg[d], 1);
  atomicAdd(&deg[s], 1);
}

__global__ void k_scan1(const int* __restrict__ deg, int* __restrict__ offa,
                        int* __restrict__ bsum){
  __shared__ int sm[256];
  int tid = threadIdx.x, idx = blockIdx.x*256 + tid;
  int v = deg[idx] + 1;                 // +1 self-loop
  sm[tid] = v; __syncthreads();
  for (int o = 1; o < 256; o <<= 1){
    int t = (tid >= o) ? sm[tid-o] : 0;
    __syncthreads();
    sm[tid] += t;
    __syncthreads();
  }
  offa[idx] = sm[tid] - v;
  if (tid == 255) bsum[blockIdx.x] = sm[255];
}

__global__ void k_scan2(int* __restrict__ bsum){
  __shared__ int sm[256];
  int tid = threadIdx.x;
  int v = bsum[tid];
  sm[tid] = v; __syncthreads();
  for (int o = 1; o < 256; o <<= 1){
    int t = (tid >= o) ? sm[tid-o] : 0;
    __syncthreads();
    sm[tid] += t;
    __syncthreads();
  }
  bsum[tid] = sm[tid] - v;
}

__global__ void k_scan3(int* __restrict__ offa, const int* __restrict__ bsum){
  int idx = blockIdx.x*256 + threadIdx.x;
  offa[idx] += bsum[idx >> 8];
}

__global__ void k_fill(const int* __restrict__ ei, const int* __restrict__ offa,
                       int* __restrict__ cur, int* __restrict__ elist){
  int t = blockIdx.x*256 + threadIdx.x;
  int s = ei[t], d = ei[EE + t];
  int p = atomicAdd(&cur[d], 1); elist[offa[d] + p] = s;   // TD edge
  p = atomicAdd(&cur[s], 1);     elist[offa[s] + p] = d;   // BU (flipped) edge
  p = atomicAdd(&cur[t], 1);     elist[offa[t] + p] = t;   // self-loop (E==N)
}

// ------ GAT softmax-aggregate (h in bf16); L1: concat+b1+relu, L2: mean+b2+relu ------
template<int LAYER>
__global__ __launch_bounds__(256) void k_agg(const int* __restrict__ offa,
                                             const int* __restrict__ deg,
                                             const int* __restrict__ elist,
                                             const ushort_t* __restrict__ h,  // [N,256] bf16
                                             const float* __restrict__ asrc,
                                             const float* __restrict__ adst,
                                             const float* __restrict__ bias,
                                             float* __restrict__ out){
  int tid = threadIdx.x;
  int wave = tid >> 6, lane = tid & 63;
  int grp = lane >> 4, l = lane & 15;           // 4 dst nodes per wave, 16 lanes each
  int n = blockIdx.x*16 + wave*4 + grp;
  int o0 = offa[n], cnt = deg[n] + 1;
  float4 adv = *(const float4*)&adst[(size_t)n*4];
  float ad[4] = {adv.x, adv.y, adv.z, adv.w};
  // pass 1: per-head max over incoming edges
  float m[4] = {-1e30f, -1e30f, -1e30f, -1e30f};
  for (int i = l; i < cnt; i += 16){
    int s = elist[o0 + i];
    float4 asv = *(const float4*)&asrc[(size_t)s*4];
    float as_[4] = {asv.x, asv.y, asv.z, asv.w};
    #pragma unroll
    for (int hh = 0; hh < 4; ++hh){
      float e = lrelu_(as_[hh] + ad[hh]);
      m[hh] = fmaxf(m[hh], e);
    }
  }
  #pragma unroll
  for (int mask = 1; mask < 16; mask <<= 1)
    #pragma unroll
    for (int hh = 0; hh < 4; ++hh) m[hh] = fmaxf(m[hh], __shfl_xor(m[hh], mask));
  // pass 2: accumulate exp-weighted features; lane owns 16 channels (c = l*16..)
  int myh = l >> 2;
  float mm = m[myh];
  float den = 0.f;
  float accv[16] = {};
  for (int i = 0; i < cnt; ++i){
    int s = elist[o0 + i];
    float4 asv = *(const float4*)&asrc[(size_t)s*4];
    float e = lrelu_(((const float*)&asv)[myh] + ad[myh]);
    float ex = __expf(e - mm);
    den += ex;
    const uint4* hp = (const uint4*)(h + (size_t)s*256 + l*16);
    uint4 h0 = hp[0], h1v = hp[1];
    uint_t uu[8] = {h0.x, h0.y, h0.z, h0.w, h1v.x, h1v.y, h1v.z, h1v.w};
    #pragma unroll
    for (int r = 0; r < 8; ++r){
      accv[2*r+0] = fmaf(ex, b2f(uu[r] & 0xffffu), accv[2*r+0]);
      accv[2*r+1] = fmaf(ex, b2f(uu[r] >> 16),     accv[2*r+1]);
    }
  }
  float inv = 1.0f / den;
  if (LAYER == 1){
    #pragma unroll
    for (int r = 0; r < 4; ++r){
      int c = l*16 + r*4;
      float4 bv = *(const float4*)&bias[c];
      float4 o;
      o.x = fmaxf(accv[r*4+0]*inv + bv.x, 0.f);
      o.y = fmaxf(accv[r*4+1]*inv + bv.y, 0.f);
      o.z = fmaxf(accv[r*4+2]*inv + bv.z, 0.f);
      o.w = fmaxf(accv[r*4+3]*inv + bv.w, 0.f);
      *(float4*)&out[(size_t)n*256 + c] = o;
    }
  } else {
    #pragma unroll
    for (int r = 0; r < 16; ++r) accv[r] *= inv;
    #pragma unroll
    for (int r = 0; r < 16; ++r){
      accv[r] += __shfl_xor(accv[r], 4);
      accv[r] += __shfl_xor(accv[r], 8);
    }
    if (l < 4){
      #pragma unroll
      for (int r = 0; r < 4; ++r){
        int c = l*16 + r*4;
        float4 bv = *(const float4*)&bias[c];
        float4 o;
        o.x = fmaxf(accv[r*4+0]*0.25f + bv.x, 0.f);
        o.y = fmaxf(accv[r*4+1]*0.25f + bv.y, 0.f);
        o.z = fmaxf(accv[r*4+2]*0.25f + bv.z, 0.f);
        o.w = fmaxf(accv[r*4+3]*0.25f + bv.w, 0.f);
        *(float4*)&out[(size_t)n*64 + c] = o;
      }
    }
  }
}

// ------------- PostLevelAttention2: x3 [N,512] bf16 from xr [N,256] f32 -------------
__global__ __launch_bounds__(256) void k_post2(const float* __restrict__ xr,
                                               const float* __restrict__ Wp2,
                                               const float* __restrict__ hc2,
                                               ushort_t* __restrict__ x3){
  __shared__ __align__(16) float Ws[64*64];
  __shared__ __align__(16) float xs[4][256];
  int tid = threadIdx.x;
  for (int i = tid*4; i < 4096; i += 1024)
    *(float4*)&Ws[i] = *(const float4*)&Wp2[i];
  __syncthreads();
  int wave = tid >> 6, f = tid & 63;
  int wid = blockIdx.x*4 + wave;
  for (int it = 0; it < 4; ++it){
    int n = wid*4 + it;
    *(float4*)&xs[wave][f*4] = *(const float4*)&xr[(size_t)n*256 + f*4];
    __syncthreads();
    int g = n >> 9;
    float hc = hc2[g*64 + f];
    #pragma unroll
    for (int hd = 0; hd < 4; ++hd){
      float a = 0.f;
      for (int h2 = 0; h2 < 64; h2 += 4){
        float4 xv = *(const float4*)&xs[wave][hd*64 + h2];
        a = fmaf(xv.x, Ws[(h2+0)*64+f], a);
        a = fmaf(xv.y, Ws[(h2+1)*64+f], a);
        a = fmaf(xv.z, Ws[(h2+2)*64+f], a);
        a = fmaf(xv.w, Ws[(h2+3)*64+f], a);
      }
      float gg = sigmoidf_(a + hc);
      x3[(size_t)n*512 + hd*128 + f]      = f2b(gg*a + (1.f-gg)*hc);
      x3[(size_t)n*512 + hd*128 + 64 + f] = f2b(a);
    }
    __syncthreads();
  }
}

// ------------- beta = softmax(tanh(h_joint@W_fc+b)); partial graph sums -------------
__global__ __launch_bounds__(256) void k_pool(const float* __restrict__ xr2,
                                              const float* __restrict__ Wfc,
                                              const float* __restrict__ bfc,
                                              float* __restrict__ shat,
                                              float* __restrict__ ssum){
  __shared__ __align__(16) float Ws2[192*64];    // W_fc rows 64..255
  __shared__ __align__(16) float hjs[4][192];
  __shared__ float rs[64];
  __shared__ float baseS[64];
  int tid = threadIdx.x;
  int gph = blockIdx.x >> 2;
  for (int i = tid*4; i < 192*64; i += 1024)
    *(float4*)&Ws2[i] = *(const float4*)&Wfc[64*64 + i];
  if (tid < 64) rs[tid] = xr2[(size_t)(gph << 9)*64 + tid];
  __syncthreads();
  if (tid < 64){
    float b = bfc[tid];
    for (int j = 0; j < 64; ++j) b = fmaf(rs[j], Wfc[j*64 + tid], b);
    baseS[tid] = b;
  }
  __syncthreads();
  int wave = tid >> 6, f = tid & 63;
  int base = blockIdx.x*128 + wave*32;
  float rv = rs[f];
  float acc_sh = 0.f, acc_s = 0.f;
  for (int it = 0; it < 32; ++it){
    int n = base + it;
    float xv = xr2[(size_t)n*64 + f];
    hjs[wave][f]       = xv;
    hjs[wave][64 + f]  = xv*rv;
    hjs[wave][128 + f] = fabsf(rv - xv);
    __syncthreads();
    float a = baseS[f];
    for (int j = 0; j < 192; j += 4){
      float4 hv = *(const float4*)&hjs[wave][j];
      a = fmaf(hv.x, Ws2[(j+0)*64+f], a);
      a = fmaf(hv.y, Ws2[(j+1)*64+f], a);
      a = fmaf(hv.z, Ws2[(j+2)*64+f], a);
      a = fmaf(hv.w, Ws2[(j+3)*64+f], a);
    }
    float t = tanhf(a);
    float mx = t;
    #pragma unroll
    for (int mask = 1; mask < 64; mask <<= 1) mx = fmaxf(mx, __shfl_xor(mx, mask));
    float e = __expf(t - mx);
    float s = e;
    #pragma unroll
    for (int mask = 1; mask < 64; mask <<= 1) s += __shfl_xor(s, mask);
    float beta = e / s;
    acc_sh = fmaf(beta, xv, acc_sh);
    acc_s += xv;
    __syncthreads();
  }
  atomicAdd(&shat[gph*64 + f], acc_sh);
  atomicAdd(&ssum[gph*64 + f], acc_s);
}

// ------------- final logits + log_softmax -------------
__global__ void k_final(const float* __restrict__ shat, const float* __restrict__ ssum,
                        const float* __restrict__ Wc, const float* __restrict__ bc,
                        float* __restrict__ outp){
  int g = threadIdx.x;   // 128 graphs
  float l0 = bc[0], l1 = bc[1], l2 = bc[2], l3 = bc[3];
  const float s512 = 1.0f/512.0f;
  for (int j = 0; j < 64; ++j){
    float sh = shat[g*64 + j]*s512;
    float ss = ssum[g*64 + j]*s512;
    float4 w1 = *(const float4*)&Wc[j*4];
    float4 w2 = *(const float4*)&Wc[(64+j)*4];
    l0 = fmaf(sh, w1.x, fmaf(ss, w2.x, l0));
    l1 = fmaf(sh, w1.y, fmaf(ss, w2.y, l1));
    l2 = fmaf(sh, w1.z, fmaf(ss, w2.z, l2));
    l3 = fmaf(sh, w1.w, fmaf(ss, w2.w, l3));
  }
  float mx = fmaxf(fmaxf(l0,l1), fmaxf(l2,l3));
  float s = __expf(l0-mx)+__expf(l1-mx)+__expf(l2-mx)+__expf(l3-mx);
  float lse = mx + logf(s);
  outp[g*4+0] = l0 - lse;
  outp[g*4+1] = l1 - lse;
  outp[g*4+2] = l2 - lse;
  outp[g*4+3] = l3 - lse;
}

extern "C" void kernel_launch(void* const* d_in, const int* in_sizes, int n_in,
                              void* d_out, int out_size, void* d_ws, size_t ws_size,
                              hipStream_t stream){
  const float* x        = (const float*)d_in[0];
  const float* root     = (const float*)d_in[1];
  const int*   ei       = (const int*)d_in[2];
  const float* W_post1  = (const float*)d_in[5];
  const float* W_claim1 = (const float*)d_in[6];
  const float* W1       = (const float*)d_in[7];
  const float* att_src1 = (const float*)d_in[8];
  const float* att_dst1 = (const float*)d_in[9];
  const float* b1       = (const float*)d_in[10];
  const float* W_post2  = (const float*)d_in[11];
  const float* W_claim2 = (const float*)d_in[12];
  const float* W2       = (const float*)d_in[13];
  const float* att_src2 = (const float*)d_in[14];
  const float* att_dst2 = (const float*)d_in[15];
  const float* b2       = (const float*)d_in[16];
  const float* W_fc     = (const float*)d_in[17];
  const float* b_fc     = (const float*)d_in[18];
  const float* W_clf    = (const float*)d_in[19];
  const float* b_clf    = (const float*)d_in[20];
  float* out = (float*)d_out;

  char* w = (char*)d_ws;
  size_t o = 0;
  auto alloc = [&](size_t bytes)->char*{ char* p = w + o; o += (bytes + 255) & ~(size_t)255; return p; };
  // RA: h1b [N,128]bf16 then x3b [N,512]bf16 (h1b dead before x3b written)
  ushort_t* RA   = (ushort_t*)alloc((size_t)NN*512*2);
  // RB: h2b then h3b [N,256]bf16
  ushort_t* RB   = (ushort_t*)alloc((size_t)NN*256*2);
  float* xr   = (float*)alloc((size_t)NN*256*4);
  float* xr2  = (float*)alloc((size_t)NN*64*4);
  float* asrc = (float*)alloc((size_t)NN*4*4);
  float* adst = (float*)alloc((size_t)NN*4*4);
  float* hc1  = (float*)alloc(128*64*4);
  float* hc2  = (float*)alloc(128*64*4);
  ushort_t* W1t  = (ushort_t*)alloc((size_t)256*128*2);
  ushort_t* W2t  = (ushort_t*)alloc((size_t)256*512*2);
  ushort_t* Wp1t = (ushort_t*)alloc((size_t)64*512*2);
  int*   deg  = (int*)alloc((size_t)NN*4);
  int*   offa = (int*)alloc((size_t)NN*4);
  int*   cur  = (int*)alloc((size_t)NN*4);
  int*   bsum = (int*)alloc(256*4);
  int*   elist= (int*)alloc((size_t)(2*EE+NN)*4);
  float* shat = (float*)alloc(128*64*4);
  float* ssumv= (float*)alloc(128*64*4);

  ushort_t* h1b = RA;    // [N,128] bf16
  ushort_t* x3b = RA;    // [N,512] bf16 (h1b dead by then)
  ushort_t* h2b = RB;    // [N,256] bf16
  ushort_t* h3b = RB;    // [N,256] bf16 (h2b dead by then)

  hipMemsetAsync(deg,   0, (size_t)NN*4, stream);
  hipMemsetAsync(cur,   0, (size_t)NN*4, stream);
  hipMemsetAsync(shat,  0, 128*64*4, stream);
  hipMemsetAsync(ssumv, 0, 128*64*4, stream);

  // weight prep (transpose + bf16 cast)
  k_tcast<<<(128*256+255)/256, 256, 0, stream>>>(W1, W1t, 128, 256);
  k_tcast<<<(512*256+255)/256, 256, 0, stream>>>(W2, W2t, 512, 256);
  k_tcast<<<(512*64+255)/256, 256, 0, stream>>>(W_post1, Wp1t, 512, 64);

  k_hc<<<128, 64, 0, stream>>>(root, W_claim1, W_claim2, hc1, hc2);
  k_gemm1_mfma<<<1024, 256, 0, stream>>>(x, Wp1t, hc1, h1b);
  k_gat_mfma<128><<<1024, 256, 0, stream>>>(h1b, W1t, att_src1, att_dst1, h2b, asrc, adst);
  k_count<<<256, 256, 0, stream>>>(ei, deg);
  k_scan1<<<256, 256, 0, stream>>>(deg, offa, bsum);
  k_scan2<<<1, 256, 0, stream>>>(bsum);
  k_scan3<<<256, 256, 0, stream>>>(offa, bsum);
  k_fill<<<256, 256, 0, stream>>>(ei, offa, cur, elist);
  k_agg<1><<<4096, 256, 0, stream>>>(offa, deg, elist, h2b, asrc, adst, b1, xr);
  k_post2<<<4096, 256, 0, stream>>>(xr, W_post2, hc2, x3b);
  k_gat_mfma<512><<<1024, 256, 0, stream>>>(x3b, W2t, att_src2, att_dst2, h3b, asrc, adst);
  k_agg<2><<<4096, 256, 0, stream>>>(offa, deg, elist, h3b, asrc, adst, b2, xr2);
  k_pool<<<512, 256, 0, stream>>>(xr2, W_fc, b_fc, shat, ssumv);
  k_final<<<1, 128, 0, stream>>>(shat, ssumv, W_clf, b_clf, out);
  (void)in_sizes; (void)n_in; (void)out_size; (void)ws_size;
}

// Round 3
// 354.842 us; speedup vs baseline: 2.1689x; 1.5810x over previous
//
#include <hip/hip_runtime.h>
#include <math.h>

#define NN   65536
#define BB   128
#define GGR  512
#define EE   65536
#define INF_ 512
#define HIDD 64

typedef __attribute__((ext_vector_type(8))) short bf16x8;
typedef __attribute__((ext_vector_type(4))) float f32x4;
typedef unsigned short ushort_t;
typedef unsigned int uint_t;

static __device__ __forceinline__ float sigmoidf_(float x){ return 1.0f/(1.0f+__expf(-x)); }
static __device__ __forceinline__ float lrelu_(float x){ return x>=0.0f ? x : 0.2f*x; }
static __device__ __forceinline__ float tanhf_(float x){
  float e = __expf(2.f*x);
  return 1.f - 2.f/(e + 1.f);
}

// f32 -> bf16 bits, round-to-nearest-even
static __device__ __forceinline__ ushort_t f2b(float f){
  union { float f; uint_t u; } v; v.f = f;
  uint_t u = v.u;
  uint_t r = (u + 0x7fffu + ((u >> 16) & 1u)) >> 16;
  return (ushort_t)r;
}
// bf16 bits -> f32 (exact)
static __device__ __forceinline__ float b2f(uint_t u16){
  union { uint_t u; float f; } v; v.u = u16 << 16; return v.f;
}

// ---------------- hc1/hc2 = root @ W_claim{1,2}  [128,64] ----------------
__global__ void k_hc(const float* __restrict__ root, const float* __restrict__ Wc1,
                     const float* __restrict__ Wc2, float* __restrict__ hc1,
                     float* __restrict__ hc2){
  int b = blockIdx.x, f = threadIdx.x;
  const float* r = root + (size_t)b*INF_;
  float a1 = 0.f, a2 = 0.f;
  for (int k = 0; k < INF_; ++k){
    float rv = r[k];
    a1 = fmaf(rv, Wc1[k*HIDD+f], a1);
    a2 = fmaf(rv, Wc2[k*HIDD+f], a2);
  }
  hc1[b*HIDD+f] = a1; hc2[b*HIDD+f] = a2;
}

// -------------- transpose+cast weights: dst[c*K+k] = bf16(src[k*C+c]) --------------
__global__ void k_tcast(const float* __restrict__ src, ushort_t* __restrict__ dst,
                        int K, int C){
  int idx = blockIdx.x*256 + threadIdx.x;
  if (idx >= K*C) return;
  int k = idx / C, c = idx - k*C;
  dst[(size_t)c*K + k] = f2b(src[idx]);
}

// -------- h1 = gated(x@W_post1, hc1) via MFMA; writes [N,128] bf16 --------
__global__ __launch_bounds__(256) void k_gemm1_mfma(
    const float* __restrict__ x,        // [N,512] f32
    const ushort_t* __restrict__ Wt,    // [64,512] bf16 (W_post1^T)
    const float* __restrict__ hc1,      // [128,64]
    ushort_t* __restrict__ h1b){        // [N,128] bf16
  int tid = threadIdx.x;
  int w = tid >> 6, lane = tid & 63;
  int lr = lane & 15, lk = lane >> 4;
  int n0 = blockIdx.x * 64;
  int arow = n0 + w*16 + lr;
  f32x4 acc[4];
  #pragma unroll
  for (int ci = 0; ci < 4; ++ci) acc[ci] = (f32x4){0.f,0.f,0.f,0.f};
  const float* Ap = x + (size_t)arow*512 + lk*8;
  const ushort_t* Bb = Wt + (size_t)lr*512 + lk*8;
  for (int k0 = 0; k0 < 512; k0 += 32){
    float4 a0 = *(const float4*)(Ap + k0);
    float4 a1 = *(const float4*)(Ap + k0 + 4);
    bf16x8 af;
    af[0]=(short)f2b(a0.x); af[1]=(short)f2b(a0.y); af[2]=(short)f2b(a0.z); af[3]=(short)f2b(a0.w);
    af[4]=(short)f2b(a1.x); af[5]=(short)f2b(a1.y); af[6]=(short)f2b(a1.z); af[7]=(short)f2b(a1.w);
    #pragma unroll
    for (int ci = 0; ci < 4; ++ci){
      bf16x8 bfv = *(const bf16x8*)(Bb + (size_t)ci*16*512 + k0);
      acc[ci] = __builtin_amdgcn_mfma_f32_16x16x32_bf16(af, bfv, acc[ci], 0, 0, 0);
    }
  }
  int g = n0 >> 9;
  #pragma unroll
  for (int ci = 0; ci < 4; ++ci){
    int col = ci*16 + lr;
    float hc = hc1[g*64 + col];
    #pragma unroll
    for (int q = 0; q < 4; ++q){
      int row = n0 + w*16 + lk*4 + q;
      float hx = acc[ci][q];
      float gg = sigmoidf_(hx + hc);
      float fo = gg*hx + (1.f-gg)*hc;
      h1b[(size_t)row*128 + col]      = f2b(fo);
      h1b[(size_t)row*128 + 64 + col] = f2b(hx);
    }
  }
}

// ---- GAT linear: H = A@W [N,256] bf16-in/bf16-out MFMA + fused att logits ----
template<int K>
__global__ __launch_bounds__(256) void k_gat_mfma(
    const ushort_t* __restrict__ A,     // [N,K] bf16
    const ushort_t* __restrict__ Wt,    // [256,K] bf16 (W^T)
    const float* __restrict__ att_s,    // [4,64]
    const float* __restrict__ att_d,    // [4,64]
    ushort_t* __restrict__ Hout,        // [N,256] bf16
    float* __restrict__ asrc,           // [N,4]
    float* __restrict__ adst){          // [N,4]
  int tid = threadIdx.x;
  int w = tid >> 6, lane = tid & 63;
  int lr = lane & 15, lk = lane >> 4;
  int n0 = blockIdx.x * 64;
  int c0 = w * 64;
  f32x4 acc[4][4];
  #pragma unroll
  for (int ri = 0; ri < 4; ++ri)
    #pragma unroll
    for (int ci = 0; ci < 4; ++ci) acc[ri][ci] = (f32x4){0.f,0.f,0.f,0.f};
  const ushort_t* Ab = A + (size_t)(n0 + lr)*K + lk*8;
  const ushort_t* Bb = Wt + (size_t)(c0 + lr)*K + lk*8;
  for (int k0 = 0; k0 < K; k0 += 32){
    bf16x8 af[4], bfv[4];
    #pragma unroll
    for (int ri = 0; ri < 4; ++ri)
      af[ri] = *(const bf16x8*)(Ab + (size_t)ri*16*K + k0);
    #pragma unroll
    for (int ci = 0; ci < 4; ++ci)
      bfv[ci] = *(const bf16x8*)(Bb + (size_t)ci*16*K + k0);
    #pragma unroll
    for (int ri = 0; ri < 4; ++ri)
      #pragma unroll
      for (int ci = 0; ci < 4; ++ci)
        acc[ri][ci] = __builtin_amdgcn_mfma_f32_16x16x32_bf16(af[ri], bfv[ci], acc[ri][ci], 0, 0, 0);
  }
  float as_[4], ad_[4];
  #pragma unroll
  for (int ci = 0; ci < 4; ++ci){
    as_[ci] = att_s[c0 + ci*16 + lr];
    ad_[ci] = att_d[c0 + ci*16 + lr];
  }
  #pragma unroll
  for (int ri = 0; ri < 4; ++ri){
    #pragma unroll
    for (int q = 0; q < 4; ++q){
      int row = n0 + ri*16 + lk*4 + q;
      float ps = 0.f, pd = 0.f;
      #pragma unroll
      for (int ci = 0; ci < 4; ++ci){
        float v = acc[ri][ci][q];
        Hout[(size_t)row*256 + c0 + ci*16 + lr] = f2b(v);
        ps = fmaf(v, as_[ci], ps);
        pd = fmaf(v, ad_[ci], pd);
      }
      #pragma unroll
      for (int m = 1; m < 16; m <<= 1){
        ps += __shfl_xor(ps, m);
        pd += __shfl_xor(pd, m);
      }
      if (lr == 0){
        asrc[(size_t)row*4 + w] = ps;
        adst[(size_t)row*4 + w] = pd;
      }
    }
  }
}

// ---------------- CSR build ----------------
__global__ void k_count(const int* __restrict__ ei, int* __restrict__ deg){
  int t = blockIdx.x*256 + threadIdx.x;
  int s = ei[t], d = ei[EE + t];
  atomicAdd(&deg[d], 1);
  atomicAdd(&deg[s], 1);
}

__global__ void k_scan1(const int* __restrict__ deg, int* __restrict__ offa,
                        int* __restrict__ bsum){
  __shared__ int sm[256];
  int tid = threadIdx.x, idx = blockIdx.x*256 + tid;
  int v = deg[idx] + 1;                 // +1 self-loop
  sm[tid] = v; __syncthreads();
  for (int o = 1; o < 256; o <<= 1){
    int t = (tid >= o) ? sm[tid-o] : 0;
    __syncthreads();
    sm[tid] += t;
    __syncthreads();
  }
  offa[idx] = sm[tid] - v;
  if (tid == 255) bsum[blockIdx.x] = sm[255];
}

__global__ void k_scan2(int* __restrict__ bsum){
  __shared__ int sm[256];
  int tid = threadIdx.x;
  int v = bsum[tid];
  sm[tid] = v; __syncthreads();
  for (int o = 1; o < 256; o <<= 1){
    int t = (tid >= o) ? sm[tid-o] : 0;
    __syncthreads();
    sm[tid] += t;
    __syncthreads();
  }
  bsum[tid] = sm[tid] - v;
}

__global__ void k_scan3(int* __restrict__ offa, const int* __restrict__ bsum){
  int idx = blockIdx.x*256 + threadIdx.x;
  offa[idx] += bsum[idx >> 8];
}

__global__ void k_fill(const int* __restrict__ ei, const int* __restrict__ offa,
                       int* __restrict__ cur, int* __restrict__ elist){
  int t = blockIdx.x*256 + threadIdx.x;
  int s = ei[t], d = ei[EE + t];
  int p = atomicAdd(&cur[d], 1); elist[offa[d] + p] = s;   // TD edge
  p = atomicAdd(&cur[s], 1);     elist[offa[s] + p] = d;   // BU (flipped) edge
  p = atomicAdd(&cur[t], 1);     elist[offa[t] + p] = t;   // self-loop (E==N)
}

// ------ GAT softmax-aggregate (h bf16); L1: concat+b1+relu -> bf16, L2: mean+b2+relu -> f32 ------
template<int LAYER>
__global__ __launch_bounds__(256) void k_agg(const int* __restrict__ offa,
                                             const int* __restrict__ deg,
                                             const int* __restrict__ elist,
                                             const ushort_t* __restrict__ h,  // [N,256] bf16
                                             const float* __restrict__ asrc,
                                             const float* __restrict__ adst,
                                             const float* __restrict__ bias,
                                             ushort_t* __restrict__ outb,
                                             float* __restrict__ outf){
  int tid = threadIdx.x;
  int wave = tid >> 6, lane = tid & 63;
  int grp = lane >> 4, l = lane & 15;           // 4 dst nodes per wave, 16 lanes each
  int n = blockIdx.x*16 + wave*4 + grp;
  int o0 = offa[n], cnt = deg[n] + 1;
  float4 adv = *(const float4*)&adst[(size_t)n*4];
  float ad[4] = {adv.x, adv.y, adv.z, adv.w};
  // pass 1: per-head max over incoming edges
  float m[4] = {-1e30f, -1e30f, -1e30f, -1e30f};
  for (int i = l; i < cnt; i += 16){
    int s = elist[o0 + i];
    float4 asv = *(const float4*)&asrc[(size_t)s*4];
    float as_[4] = {asv.x, asv.y, asv.z, asv.w};
    #pragma unroll
    for (int hh = 0; hh < 4; ++hh){
      float e = lrelu_(as_[hh] + ad[hh]);
      m[hh] = fmaxf(m[hh], e);
    }
  }
  #pragma unroll
  for (int mask = 1; mask < 16; mask <<= 1)
    #pragma unroll
    for (int hh = 0; hh < 4; ++hh) m[hh] = fmaxf(m[hh], __shfl_xor(m[hh], mask));
  // pass 2: accumulate exp-weighted features; lane owns 16 channels (c = l*16..)
  int myh = l >> 2;
  float mm = m[myh];
  float den = 0.f;
  float accv[16] = {};
  for (int i = 0; i < cnt; ++i){
    int s = elist[o0 + i];
    float4 asv = *(const float4*)&asrc[(size_t)s*4];
    float e = lrelu_(((const float*)&asv)[myh] + ad[myh]);
    float ex = __expf(e - mm);
    den += ex;
    const uint4* hp = (const uint4*)(h + (size_t)s*256 + l*16);
    uint4 h0 = hp[0], h1v = hp[1];
    uint_t uu[8] = {h0.x, h0.y, h0.z, h0.w, h1v.x, h1v.y, h1v.z, h1v.w};
    #pragma unroll
    for (int r = 0; r < 8; ++r){
      accv[2*r+0] = fmaf(ex, b2f(uu[r] & 0xffffu), accv[2*r+0]);
      accv[2*r+1] = fmaf(ex, b2f(uu[r] >> 16),     accv[2*r+1]);
    }
  }
  float inv = 1.0f / den;
  if (LAYER == 1){
    #pragma unroll
    for (int r = 0; r < 4; ++r){
      int c = l*16 + r*4;
      float4 bv = *(const float4*)&bias[c];
      float o0v = fmaxf(accv[r*4+0]*inv + bv.x, 0.f);
      float o1v = fmaxf(accv[r*4+1]*inv + bv.y, 0.f);
      float o2v = fmaxf(accv[r*4+2]*inv + bv.z, 0.f);
      float o3v = fmaxf(accv[r*4+3]*inv + bv.w, 0.f);
      uint2 pk;
      pk.x = (uint_t)f2b(o0v) | ((uint_t)f2b(o1v) << 16);
      pk.y = (uint_t)f2b(o2v) | ((uint_t)f2b(o3v) << 16);
      *(uint2*)&outb[(size_t)n*256 + c] = pk;
    }
  } else {
    #pragma unroll
    for (int r = 0; r < 16; ++r) accv[r] *= inv;
    #pragma unroll
    for (int r = 0; r < 16; ++r){
      accv[r] += __shfl_xor(accv[r], 4);
      accv[r] += __shfl_xor(accv[r], 8);
    }
    if (l < 4){
      #pragma unroll
      for (int r = 0; r < 4; ++r){
        int c = l*16 + r*4;
        float4 bv = *(const float4*)&bias[c];
        float4 o;
        o.x = fmaxf(accv[r*4+0]*0.25f + bv.x, 0.f);
        o.y = fmaxf(accv[r*4+1]*0.25f + bv.y, 0.f);
        o.z = fmaxf(accv[r*4+2]*0.25f + bv.z, 0.f);
        o.w = fmaxf(accv[r*4+3]*0.25f + bv.w, 0.f);
        *(float4*)&outf[(size_t)n*64 + c] = o;
      }
    }
  }
}

// ---- PostLevelAttention2 via MFMA: x3b [N,512] bf16 from xrb [N,256] bf16 ----
// block = 64 nodes; wave w == head w. K=64 per head.
__global__ __launch_bounds__(256) void k_post2_mfma(
    const ushort_t* __restrict__ xrb,   // [N,256] bf16
    const ushort_t* __restrict__ Wp2t,  // [64,64] bf16 (W_post2^T)
    const float* __restrict__ hc2,      // [128,64]
    ushort_t* __restrict__ x3b){        // [N,512] bf16
  int tid = threadIdx.x;
  int w = tid >> 6, lane = tid & 63;
  int lr = lane & 15, lk = lane >> 4;
  int n0 = blockIdx.x * 64;
  int g = n0 >> 9;
  f32x4 acc[4][4];
  #pragma unroll
  for (int ri = 0; ri < 4; ++ri)
    #pragma unroll
    for (int ci = 0; ci < 4; ++ci) acc[ri][ci] = (f32x4){0.f,0.f,0.f,0.f};
  const ushort_t* Ab = xrb + (size_t)(n0 + lr)*256 + w*64 + lk*8;
  const ushort_t* Bb = Wp2t + (size_t)lr*64 + lk*8;
  #pragma unroll
  for (int k0 = 0; k0 < 64; k0 += 32){
    bf16x8 af[4], bfv[4];
    #pragma unroll
    for (int ri = 0; ri < 4; ++ri)
      af[ri] = *(const bf16x8*)(Ab + (size_t)ri*16*256 + k0);
    #pragma unroll
    for (int ci = 0; ci < 4; ++ci)
      bfv[ci] = *(const bf16x8*)(Bb + (size_t)ci*16*64 + k0);
    #pragma unroll
    for (int ri = 0; ri < 4; ++ri)
      #pragma unroll
      for (int ci = 0; ci < 4; ++ci)
        acc[ri][ci] = __builtin_amdgcn_mfma_f32_16x16x32_bf16(af[ri], bfv[ci], acc[ri][ci], 0, 0, 0);
  }
  #pragma unroll
  for (int ci = 0; ci < 4; ++ci){
    int col = ci*16 + lr;
    float hc = hc2[g*64 + col];
    #pragma unroll
    for (int ri = 0; ri < 4; ++ri){
      #pragma unroll
      for (int q = 0; q < 4; ++q){
        int row = n0 + ri*16 + lk*4 + q;
        float a = acc[ri][ci][q];
        float gg = sigmoidf_(a + hc);
        x3b[(size_t)row*512 + w*128 + col]      = f2b(gg*a + (1.f-gg)*hc);
        x3b[(size_t)row*512 + w*128 + 64 + col] = f2b(a);
      }
    }
  }
}

// ---- baseS[g][c] = b_fc[c] + sum_j xr2[root_g][j] * W_fc[j][c] (h_c3 part) ----
__global__ void k_base(const float* __restrict__ xr2, const float* __restrict__ Wfc,
                       const float* __restrict__ bfc, float* __restrict__ baseS){
  int g = blockIdx.x, c = threadIdx.x;
  const float* r = xr2 + (size_t)g*GGR*64;
  float b = bfc[c];
  for (int j = 0; j < 64; ++j) b = fmaf(r[j], Wfc[j*64 + c], b);
  baseS[g*64 + c] = b;
}

// ---- pool via MFMA: block = 64 nodes (one graph slice) x 64 outputs, K=192 ----
// A (on the fly) = [xv, xv*r, |r-xv|] bf16; B = W_fc rows 64..255 transposed bf16.
__global__ __launch_bounds__(256) void k_pool_mfma(
    const float* __restrict__ xr2,      // [N,64] f32
    const ushort_t* __restrict__ Wfct,  // [64,192] bf16 (W_fc[64:256]^T)
    const float* __restrict__ baseS,    // [128,64]
    float* __restrict__ shat,
    float* __restrict__ ssum){
  __shared__ __align__(16) float xs[64][68];
  __shared__ float rls[64];
  __shared__ float bs[64];
  __shared__ float ls_sh[64];
  __shared__ float ls_s[64];
  int tid = threadIdx.x;
  int n0 = blockIdx.x * 64;
  int g = n0 >> 9;
  // stage node tile + root row + baseS
  {
    int row = tid >> 4, col4 = (tid & 15) * 4;
    #pragma unroll
    for (int i = 0; i < 4; ++i){
      float4 v = *(const float4*)&xr2[(size_t)(n0 + row + i*16)*64 + col4];
      *(float4*)&xs[row + i*16][col4] = v;
    }
    if (tid < 16){
      float4 v = *(const float4*)&xr2[(size_t)((size_t)g*GGR)*64 + tid*4];
      *(float4*)&rls[tid*4] = v;
    }
    if (tid >= 64 && tid < 128) bs[tid-64] = baseS[g*64 + (tid-64)];
    if (tid >= 128 && tid < 192){ ls_sh[tid-128] = 0.f; ls_s[tid-128] = 0.f; }
  }
  __syncthreads();
  int w = tid >> 6, lane = tid & 63;
  int lr = lane & 15, lk = lane >> 4;
  f32x4 acc[4];
  #pragma unroll
  for (int ci = 0; ci < 4; ++ci) acc[ci] = (f32x4){0.f,0.f,0.f,0.f};
  int arow = w*16 + lr;
  #pragma unroll
  for (int k0 = 0; k0 < 192; k0 += 32){
    int seg = k0 >> 6;
    int cb = (k0 & 63) + lk*8;
    bf16x8 af;
    #pragma unroll
    for (int j = 0; j < 8; ++j){
      float xv = xs[arow][cb + j];
      float rv = rls[cb + j];
      float v = (seg == 0) ? xv : (seg == 1 ? xv*rv : fabsf(rv - xv));
      af[j] = (short)f2b(v);
    }
    #pragma unroll
    for (int ci = 0; ci < 4; ++ci){
      bf16x8 bfv = *(const bf16x8*)(Wfct + (size_t)(ci*16+lr)*192 + k0 + lk*8);
      acc[ci] = __builtin_amdgcn_mfma_f32_16x16x32_bf16(af, bfv, acc[ci], 0, 0, 0);
    }
  }
  // epilogue: tanh -> softmax over 64 cols -> beta*xv partial sums
  float bsv[4];
  #pragma unroll
  for (int ci = 0; ci < 4; ++ci) bsv[ci] = bs[ci*16 + lr];
  float c_sh[4] = {0.f,0.f,0.f,0.f}, c_s[4] = {0.f,0.f,0.f,0.f};
  #pragma unroll
  for (int q = 0; q < 4; ++q){
    int rrow = w*16 + lk*4 + q;
    float t[4];
    float mx = -1e30f;
    #pragma unroll
    for (int ci = 0; ci < 4; ++ci){
      t[ci] = tanhf_(acc[ci][q] + bsv[ci]);
      mx = fmaxf(mx, t[ci]);
    }
    #pragma unroll
    for (int mask = 1; mask < 16; mask <<= 1) mx = fmaxf(mx, __shfl_xor(mx, mask));
    float e[4], s = 0.f;
    #pragma unroll
    for (int ci = 0; ci < 4; ++ci){ e[ci] = __expf(t[ci] - mx); s += e[ci]; }
    #pragma unroll
    for (int mask = 1; mask < 16; mask <<= 1) s += __shfl_xor(s, mask);
    float invs = 1.0f / s;
    #pragma unroll
    for (int ci = 0; ci < 4; ++ci){
      float xv = xs[rrow][ci*16 + lr];
      c_sh[ci] = fmaf(e[ci]*invs, xv, c_sh[ci]);
      c_s[ci] += xv;
    }
  }
  // reduce across lk groups (rows) then into LDS, then global atomics
  #pragma unroll
  for (int ci = 0; ci < 4; ++ci){
    c_sh[ci] += __shfl_xor(c_sh[ci], 16); c_sh[ci] += __shfl_xor(c_sh[ci], 32);
    c_s[ci]  += __shfl_xor(c_s[ci], 16);  c_s[ci]  += __shfl_xor(c_s[ci], 32);
  }
  if (lk == 0){
    #pragma unroll
    for (int ci = 0; ci < 4; ++ci){
      atomicAdd(&ls_sh[ci*16 + lr], c_sh[ci]);
      atomicAdd(&ls_s[ci*16 + lr], c_s[ci]);
    }
  }
  __syncthreads();
  if (tid < 64){
    atomicAdd(&shat[g*64 + tid], ls_sh[tid]);
    atomicAdd(&ssum[g*64 + tid], ls_s[tid]);
  }
}

// ------------- final logits + log_softmax -------------
__global__ void k_final(const float* __restrict__ shat, const float* __restrict__ ssum,
                        const float* __restrict__ Wc, const float* __restrict__ bc,
                        float* __restrict__ outp){
  int g = threadIdx.x;   // 128 graphs
  float l0 = bc[0], l1 = bc[1], l2 = bc[2], l3 = bc[3];
  const float s512 = 1.0f/512.0f;
  for (int j = 0; j < 64; ++j){
    float sh = shat[g*64 + j]*s512;
    float ss = ssum[g*64 + j]*s512;
    float4 w1 = *(const float4*)&Wc[j*4];
    float4 w2 = *(const float4*)&Wc[(64+j)*4];
    l0 = fmaf(sh, w1.x, fmaf(ss, w2.x, l0));
    l1 = fmaf(sh, w1.y, fmaf(ss, w2.y, l1));
    l2 = fmaf(sh, w1.z, fmaf(ss, w2.z, l2));
    l3 = fmaf(sh, w1.w, fmaf(ss, w2.w, l3));
  }
  float mx = fmaxf(fmaxf(l0,l1), fmaxf(l2,l3));
  float s = __expf(l0-mx)+__expf(l1-mx)+__expf(l2-mx)+__expf(l3-mx);
  float lse = mx + logf(s);
  outp[g*4+0] = l0 - lse;
  outp[g*4+1] = l1 - lse;
  outp[g*4+2] = l2 - lse;
  outp[g*4+3] = l3 - lse;
}

extern "C" void kernel_launch(void* const* d_in, const int* in_sizes, int n_in,
                              void* d_out, int out_size, void* d_ws, size_t ws_size,
                              hipStream_t stream){
  const float* x        = (const float*)d_in[0];
  const float* root     = (const float*)d_in[1];
  const int*   ei       = (const int*)d_in[2];
  const float* W_post1  = (const float*)d_in[5];
  const float* W_claim1 = (const float*)d_in[6];
  const float* W1       = (const float*)d_in[7];
  const float* att_src1 = (const float*)d_in[8];
  const float* att_dst1 = (const float*)d_in[9];
  const float* b1       = (const float*)d_in[10];
  const float* W_post2  = (const float*)d_in[11];
  const float* W_claim2 = (const float*)d_in[12];
  const float* W2       = (const float*)d_in[13];
  const float* att_src2 = (const float*)d_in[14];
  const float* att_dst2 = (const float*)d_in[15];
  const float* b2       = (const float*)d_in[16];
  const float* W_fc     = (const float*)d_in[17];
  const float* b_fc     = (const float*)d_in[18];
  const float* W_clf    = (const float*)d_in[19];
  const float* b_clf    = (const float*)d_in[20];
  float* out = (float*)d_out;

  char* w = (char*)d_ws;
  size_t o = 0;
  auto alloc = [&](size_t bytes)->char*{ char* p = w + o; o += (bytes + 255) & ~(size_t)255; return p; };
  // RA: h1b [N,128]bf16 then x3b [N,512]bf16 (h1b dead before x3b written)
  ushort_t* RA   = (ushort_t*)alloc((size_t)NN*512*2);
  // RB: h2b then h3b [N,256]bf16
  ushort_t* RB   = (ushort_t*)alloc((size_t)NN*256*2);
  ushort_t* xrb  = (ushort_t*)alloc((size_t)NN*256*2);
  float* xr2  = (float*)alloc((size_t)NN*64*4);
  float* asrc = (float*)alloc((size_t)NN*4*4);
  float* adst = (float*)alloc((size_t)NN*4*4);
  float* hc1  = (float*)alloc(128*64*4);
  float* hc2  = (float*)alloc(128*64*4);
  float* baseS= (float*)alloc(128*64*4);
  ushort_t* W1t  = (ushort_t*)alloc((size_t)256*128*2);
  ushort_t* W2t  = (ushort_t*)alloc((size_t)256*512*2);
  ushort_t* Wp1t = (ushort_t*)alloc((size_t)64*512*2);
  ushort_t* Wp2t = (ushort_t*)alloc((size_t)64*64*2);
  ushort_t* Wfct = (ushort_t*)alloc((size_t)64*192*2);
  int*   deg  = (int*)alloc((size_t)NN*4);
  int*   offa = (int*)alloc((size_t)NN*4);
  int*   cur  = (int*)alloc((size_t)NN*4);
  int*   bsum = (int*)alloc(256*4);
  int*   elist= (int*)alloc((size_t)(2*EE+NN)*4);
  float* shat = (float*)alloc(128*64*4);
  float* ssumv= (float*)alloc(128*64*4);

  ushort_t* h1b = RA;    // [N,128] bf16
  ushort_t* x3b = RA;    // [N,512] bf16 (h1b dead by then)
  ushort_t* h2b = RB;    // [N,256] bf16
  ushort_t* h3b = RB;    // [N,256] bf16 (h2b dead by then)

  hipMemsetAsync(deg,   0, (size_t)NN*4, stream);
  hipMemsetAsync(cur,   0, (size_t)NN*4, stream);
  hipMemsetAsync(shat,  0, 128*64*4, stream);
  hipMemsetAsync(ssumv, 0, 128*64*4, stream);

  // weight prep (transpose + bf16 cast)
  k_tcast<<<(128*256+255)/256, 256, 0, stream>>>(W1, W1t, 128, 256);
  k_tcast<<<(512*256+255)/256, 256, 0, stream>>>(W2, W2t, 512, 256);
  k_tcast<<<(512*64+255)/256, 256, 0, stream>>>(W_post1, Wp1t, 512, 64);
  k_tcast<<<(64*64+255)/256, 256, 0, stream>>>(W_post2, Wp2t, 64, 64);
  k_tcast<<<(192*64+255)/256, 256, 0, stream>>>(W_fc + 64*64, Wfct, 192, 64);

  k_hc<<<128, 64, 0, stream>>>(root, W_claim1, W_claim2, hc1, hc2);
  k_gemm1_mfma<<<1024, 256, 0, stream>>>(x, Wp1t, hc1, h1b);
  k_gat_mfma<128><<<1024, 256, 0, stream>>>(h1b, W1t, att_src1, att_dst1, h2b, asrc, adst);
  k_count<<<256, 256, 0, stream>>>(ei, deg);
  k_scan1<<<256, 256, 0, stream>>>(deg, offa, bsum);
  k_scan2<<<1, 256, 0, stream>>>(bsum);
  k_scan3<<<256, 256, 0, stream>>>(offa, bsum);
  k_fill<<<256, 256, 0, stream>>>(ei, offa, cur, elist);
  k_agg<1><<<4096, 256, 0, stream>>>(offa, deg, elist, h2b, asrc, adst, b1, xrb, nullptr);
  k_post2_mfma<<<1024, 256, 0, stream>>>(xrb, Wp2t, hc2, x3b);
  k_gat_mfma<512><<<1024, 256, 0, stream>>>(x3b, W2t, att_src2, att_dst2, h3b, asrc, adst);
  k_agg<2><<<4096, 256, 0, stream>>>(offa, deg, elist, h3b, asrc, adst, b2, nullptr, xr2);
  k_base<<<128, 64, 0, stream>>>(xr2, W_fc, b_fc, baseS);
  k_pool_mfma<<<1024, 256, 0, stream>>>(xr2, Wfct, baseS, shat, ssumv);
  k_final<<<1, 128, 0, stream>>>(shat, ssumv, W_clf, b_clf, out);
  (void)in_sizes; (void)n_in; (void)out_size; (void)ws_size;
}

// Round 4
// 328.564 us; speedup vs baseline: 2.3423x; 1.0800x over previous
//
#include <hip/hip_runtime.h>
#include <math.h>

#define NN   65536
#define BB   128
#define GGR  512
#define EE   65536
#define INF_ 512
#define HIDD 64

typedef __attribute__((ext_vector_type(8))) short bf16x8;
typedef __attribute__((ext_vector_type(4))) float f32x4;
typedef unsigned short ushort_t;
typedef unsigned int uint_t;

static __device__ __forceinline__ float sigmoidf_(float x){ return 1.0f/(1.0f+__expf(-x)); }
static __device__ __forceinline__ float lrelu_(float x){ return x>=0.0f ? x : 0.2f*x; }
static __device__ __forceinline__ float tanhf_(float x){
  float e = __expf(2.f*x);
  return 1.f - 2.f/(e + 1.f);
}

// f32 -> bf16 bits, round-to-nearest-even
static __device__ __forceinline__ ushort_t f2b(float f){
  union { float f; uint_t u; } v; v.f = f;
  uint_t u = v.u;
  uint_t r = (u + 0x7fffu + ((u >> 16) & 1u)) >> 16;
  return (ushort_t)r;
}
// bf16 bits -> f32 (exact)
static __device__ __forceinline__ float b2f(uint_t u16){
  union { uint_t u; float f; } v; v.u = u16 << 16; return v.f;
}

// async global->LDS, 16 bytes per lane; LDS dest = wave-uniform base + lane*16
static __device__ __forceinline__ void gld16(const void* g, void* l){
  __builtin_amdgcn_global_load_lds((const __attribute__((address_space(1))) void*)g,
                                   (__attribute__((address_space(3))) void*)l, 16, 0, 0);
}

// ---------------- hc1/hc2 = root @ W_claim{1,2}  [128,64] ----------------
__global__ void k_hc(const float* __restrict__ root, const float* __restrict__ Wc1,
                     const float* __restrict__ Wc2, float* __restrict__ hc1,
                     float* __restrict__ hc2){
  int b = blockIdx.x, f = threadIdx.x;
  const float* r = root + (size_t)b*INF_;
  float a1 = 0.f, a2 = 0.f;
  for (int k = 0; k < INF_; ++k){
    float rv = r[k];
    a1 = fmaf(rv, Wc1[k*HIDD+f], a1);
    a2 = fmaf(rv, Wc2[k*HIDD+f], a2);
  }
  hc1[b*HIDD+f] = a1; hc2[b*HIDD+f] = a2;
}

// -------------- transpose+cast weights: dst[c*K+k] = bf16(src[k*C+c]) --------------
__global__ void k_tcast(const float* __restrict__ src, ushort_t* __restrict__ dst,
                        int K, int C){
  int idx = blockIdx.x*256 + threadIdx.x;
  if (idx >= K*C) return;
  int k = idx / C, c = idx - k*C;
  dst[(size_t)c*K + k] = f2b(src[idx]);
}

// -------- h1 = gated(x@W_post1, hc1) via MFMA + LDS-staged A; writes [N,128] bf16 --------
__global__ __launch_bounds__(256) void k_gemm1_mfma(
    const float* __restrict__ x,        // [N,512] f32
    const ushort_t* __restrict__ Wt,    // [64,512] bf16 (W_post1^T)
    const float* __restrict__ hc1,      // [128,64]
    ushort_t* __restrict__ h1b){        // [N,128] bf16
  constexpr int BK = 128;               // f32 cols per stage
  constexpr int ROWB = BK*4;            // 512 B per row in LDS
  __shared__ __align__(16) float As[64*BK];   // 32 KB
  int tid = threadIdx.x;
  int w = tid >> 6, lane = tid & 63;
  int lr = lane & 15, lk = lane >> 4;
  int n0 = blockIdx.x * 64;
  int sw = (lr & 7) << 4;
  f32x4 acc[4];
  #pragma unroll
  for (int ci = 0; ci < 4; ++ci) acc[ci] = (f32x4){0.f,0.f,0.f,0.f};
  const char* xg = (const char*)(x + (size_t)n0*512);
  char* Ls = (char*)As;
  const ushort_t* Bb = Wt + (size_t)lr*512 + lk*8;
  int rl = w*16 + lr;
  for (int s = 0; s < 4; ++s){
    #pragma unroll
    for (int i = 0; i < 8; ++i){        // 32768 B / (256 thr * 16 B)
      int p = i*4096 + tid*16;
      int row = p >> 9;
      int l = p ^ ((row & 7) << 4);
      gld16(xg + (size_t)row*2048 + s*512 + (l & 511), Ls + p);
    }
    __syncthreads();
    #pragma unroll
    for (int k0 = 0; k0 < BK; k0 += 32){
      int lg = rl*ROWB + (k0 + lk*8)*4;
      float4 fa = *(const float4*)(Ls + (lg ^ sw));
      float4 fb = *(const float4*)(Ls + ((lg + 16) ^ sw));
      bf16x8 af;
      af[0]=(short)f2b(fa.x); af[1]=(short)f2b(fa.y); af[2]=(short)f2b(fa.z); af[3]=(short)f2b(fa.w);
      af[4]=(short)f2b(fb.x); af[5]=(short)f2b(fb.y); af[6]=(short)f2b(fb.z); af[7]=(short)f2b(fb.w);
      #pragma unroll
      for (int ci = 0; ci < 4; ++ci){
        bf16x8 bfv = *(const bf16x8*)(Bb + (size_t)ci*16*512 + s*BK + k0);
        acc[ci] = __builtin_amdgcn_mfma_f32_16x16x32_bf16(af, bfv, acc[ci], 0, 0, 0);
      }
    }
    if (s < 3) __syncthreads();
  }
  int g = n0 >> 9;
  #pragma unroll
  for (int ci = 0; ci < 4; ++ci){
    int col = ci*16 + lr;
    float hc = hc1[g*64 + col];
    #pragma unroll
    for (int q = 0; q < 4; ++q){
      int row = n0 + w*16 + lk*4 + q;
      float hx = acc[ci][q];
      float gg = sigmoidf_(hx + hc);
      float fo = gg*hx + (1.f-gg)*hc;
      h1b[(size_t)row*128 + col]      = f2b(fo);
      h1b[(size_t)row*128 + 64 + col] = f2b(hx);
    }
  }
}

// ---- GAT linear: H = A@W [N,256] MFMA, LDS-staged A + fused att logits ----
// block = 64 rows x 256 cols; wave w == head w (cols 64w..64w+63)
template<int K>
__global__ __launch_bounds__(256) void k_gat_mfma(
    const ushort_t* __restrict__ A,     // [N,K] bf16
    const ushort_t* __restrict__ Wt,    // [256,K] bf16 (W^T)
    const float* __restrict__ att_s,    // [4,64]
    const float* __restrict__ att_d,    // [4,64]
    ushort_t* __restrict__ Hout,        // [N,256] bf16
    float* __restrict__ asrc,           // [N,4]
    float* __restrict__ adst){          // [N,4]
  constexpr int BK = (K > 256) ? 256 : K;
  constexpr int NS = K / BK;
  constexpr int ROWB = BK * 2;          // bytes per LDS row (256 or 512)
  constexpr int RSH = (ROWB == 256) ? 8 : 9;
  __shared__ __align__(16) ushort_t As[64*BK];   // 16 or 32 KB
  int tid = threadIdx.x;
  int w = tid >> 6, lane = tid & 63;
  int lr = lane & 15, lk = lane >> 4;
  int n0 = blockIdx.x * 64;
  int c0 = w * 64;
  int sw = (lr & 7) << 4;
  f32x4 acc[4][4];
  #pragma unroll
  for (int ri = 0; ri < 4; ++ri)
    #pragma unroll
    for (int ci = 0; ci < 4; ++ci) acc[ri][ci] = (f32x4){0.f,0.f,0.f,0.f};
  const char* Ag = (const char*)(A + (size_t)n0*K);
  char* Ls = (char*)As;
  const ushort_t* Bb = Wt + (size_t)(c0 + lr)*K + lk*8;
  for (int s = 0; s < NS; ++s){
    #pragma unroll
    for (int i = 0; i < (64*ROWB)/4096; ++i){
      int p = i*4096 + tid*16;
      int row = p >> RSH;
      int l = p ^ ((row & 7) << 4);
      gld16(Ag + (size_t)row*(K*2) + s*ROWB + (l & (ROWB-1)), Ls + p);
    }
    __syncthreads();
    #pragma unroll
    for (int k0 = 0; k0 < BK; k0 += 32){
      bf16x8 af[4], bfv[4];
      #pragma unroll
      for (int ri = 0; ri < 4; ++ri){
        int lg = (ri*16 + lr)*ROWB + (k0 + lk*8)*2;
        af[ri] = *(const bf16x8*)(Ls + (lg ^ sw));
      }
      #pragma unroll
      for (int ci = 0; ci < 4; ++ci)
        bfv[ci] = *(const bf16x8*)(Bb + (size_t)ci*16*K + s*BK + k0);
      #pragma unroll
      for (int ri = 0; ri < 4; ++ri)
        #pragma unroll
        for (int ci = 0; ci < 4; ++ci)
          acc[ri][ci] = __builtin_amdgcn_mfma_f32_16x16x32_bf16(af[ri], bfv[ci], acc[ri][ci], 0, 0, 0);
    }
    if (s + 1 < NS) __syncthreads();
  }
  float as_[4], ad_[4];
  #pragma unroll
  for (int ci = 0; ci < 4; ++ci){
    as_[ci] = att_s[c0 + ci*16 + lr];
    ad_[ci] = att_d[c0 + ci*16 + lr];
  }
  #pragma unroll
  for (int ri = 0; ri < 4; ++ri){
    #pragma unroll
    for (int q = 0; q < 4; ++q){
      int row = n0 + ri*16 + lk*4 + q;
      float ps = 0.f, pd = 0.f;
      #pragma unroll
      for (int ci = 0; ci < 4; ++ci){
        float v = acc[ri][ci][q];
        Hout[(size_t)row*256 + c0 + ci*16 + lr] = f2b(v);
        ps = fmaf(v, as_[ci], ps);
        pd = fmaf(v, ad_[ci], pd);
      }
      #pragma unroll
      for (int m = 1; m < 16; m <<= 1){
        ps += __shfl_xor(ps, m);
        pd += __shfl_xor(pd, m);
      }
      if (lr == 0){
        asrc[(size_t)row*4 + w] = ps;
        adst[(size_t)row*4 + w] = pd;
      }
    }
  }
}

// ---------------- CSR build ----------------
__global__ void k_count(const int* __restrict__ ei, int* __restrict__ deg){
  int t = blockIdx.x*256 + threadIdx.x;
  int s = ei[t], d = ei[EE + t];
  atomicAdd(&deg[d], 1);
  atomicAdd(&deg[s], 1);
}

__global__ void k_scan1(const int* __restrict__ deg, int* __restrict__ offa,
                        int* __restrict__ bsum){
  __shared__ int sm[256];
  int tid = threadIdx.x, idx = blockIdx.x*256 + tid;
  int v = deg[idx] + 1;                 // +1 self-loop
  sm[tid] = v; __syncthreads();
  for (int o = 1; o < 256; o <<= 1){
    int t = (tid >= o) ? sm[tid-o] : 0;
    __syncthreads();
    sm[tid] += t;
    __syncthreads();
  }
  offa[idx] = sm[tid] - v;
  if (tid == 255) bsum[blockIdx.x] = sm[255];
}

__global__ void k_scan2(int* __restrict__ bsum){
  __shared__ int sm[256];
  int tid = threadIdx.x;
  int v = bsum[tid];
  sm[tid] = v; __syncthreads();
  for (int o = 1; o < 256; o <<= 1){
    int t = (tid >= o) ? sm[tid-o] : 0;
    __syncthreads();
    sm[tid] += t;
    __syncthreads();
  }
  bsum[tid] = sm[tid] - v;
}

__global__ void k_scan3(int* __restrict__ offa, const int* __restrict__ bsum){
  int idx = blockIdx.x*256 + threadIdx.x;
  offa[idx] += bsum[idx >> 8];
}

__global__ void k_fill(const int* __restrict__ ei, const int* __restrict__ offa,
                       int* __restrict__ cur, int* __restrict__ elist){
  int t = blockIdx.x*256 + threadIdx.x;
  int s = ei[t], d = ei[EE + t];
  int p = atomicAdd(&cur[d], 1); elist[offa[d] + p] = s;   // TD edge
  p = atomicAdd(&cur[s], 1);     elist[offa[s] + p] = d;   // BU (flipped) edge
  p = atomicAdd(&cur[t], 1);     elist[offa[t] + p] = t;   // self-loop (E==N)
}

// ------ GAT softmax-aggregate (h bf16); L1: concat+b1+relu -> bf16, L2: mean+b2+relu -> f32 ------
template<int LAYER>
__global__ __launch_bounds__(256) void k_agg(const int* __restrict__ offa,
                                             const int* __restrict__ deg,
                                             const int* __restrict__ elist,
                                             const ushort_t* __restrict__ h,  // [N,256] bf16
                                             const float* __restrict__ asrc,
                                             const float* __restrict__ adst,
                                             const float* __restrict__ bias,
                                             ushort_t* __restrict__ outb,
                                             float* __restrict__ outf){
  int tid = threadIdx.x;
  int wave = tid >> 6, lane = tid & 63;
  int grp = lane >> 4, l = lane & 15;           // 4 dst nodes per wave, 16 lanes each
  int n = blockIdx.x*16 + wave*4 + grp;
  int o0 = offa[n], cnt = deg[n] + 1;
  float4 adv = *(const float4*)&adst[(size_t)n*4];
  float ad[4] = {adv.x, adv.y, adv.z, adv.w};
  // pass 1: per-head max over incoming edges
  float m[4] = {-1e30f, -1e30f, -1e30f, -1e30f};
  for (int i = l; i < cnt; i += 16){
    int s = elist[o0 + i];
    float4 asv = *(const float4*)&asrc[(size_t)s*4];
    float as_[4] = {asv.x, asv.y, asv.z, asv.w};
    #pragma unroll
    for (int hh = 0; hh < 4; ++hh){
      float e = lrelu_(as_[hh] + ad[hh]);
      m[hh] = fmaxf(m[hh], e);
    }
  }
  #pragma unroll
  for (int mask = 1; mask < 16; mask <<= 1)
    #pragma unroll
    for (int hh = 0; hh < 4; ++hh) m[hh] = fmaxf(m[hh], __shfl_xor(m[hh], mask));
  // pass 2: accumulate exp-weighted features; lane owns 16 channels (c = l*16..)
  int myh = l >> 2;
  float mm = m[myh];
  float den = 0.f;
  float accv[16] = {};
  for (int i = 0; i < cnt; ++i){
    int s = elist[o0 + i];
    float4 asv = *(const float4*)&asrc[(size_t)s*4];
    float e = lrelu_(((const float*)&asv)[myh] + ad[myh]);
    float ex = __expf(e - mm);
    den += ex;
    const uint4* hp = (const uint4*)(h + (size_t)s*256 + l*16);
    uint4 h0 = hp[0], h1v = hp[1];
    uint_t uu[8] = {h0.x, h0.y, h0.z, h0.w, h1v.x, h1v.y, h1v.z, h1v.w};
    #pragma unroll
    for (int r = 0; r < 8; ++r){
      accv[2*r+0] = fmaf(ex, b2f(uu[r] & 0xffffu), accv[2*r+0]);
      accv[2*r+1] = fmaf(ex, b2f(uu[r] >> 16),     accv[2*r+1]);
    }
  }
  float inv = 1.0f / den;
  if (LAYER == 1){
    #pragma unroll
    for (int r = 0; r < 4; ++r){
      int c = l*16 + r*4;
      float4 bv = *(const float4*)&bias[c];
      float o0v = fmaxf(accv[r*4+0]*inv + bv.x, 0.f);
      float o1v = fmaxf(accv[r*4+1]*inv + bv.y, 0.f);
      float o2v = fmaxf(accv[r*4+2]*inv + bv.z, 0.f);
      float o3v = fmaxf(accv[r*4+3]*inv + bv.w, 0.f);
      uint2 pk;
      pk.x = (uint_t)f2b(o0v) | ((uint_t)f2b(o1v) << 16);
      pk.y = (uint_t)f2b(o2v) | ((uint_t)f2b(o3v) << 16);
      *(uint2*)&outb[(size_t)n*256 + c] = pk;
    }
  } else {
    #pragma unroll
    for (int r = 0; r < 16; ++r) accv[r] *= inv;
    #pragma unroll
    for (int r = 0; r < 16; ++r){
      accv[r] += __shfl_xor(accv[r], 4);
      accv[r] += __shfl_xor(accv[r], 8);
    }
    if (l < 4){
      #pragma unroll
      for (int r = 0; r < 4; ++r){
        int c = l*16 + r*4;
        float4 bv = *(const float4*)&bias[c];
        float4 o;
        o.x = fmaxf(accv[r*4+0]*0.25f + bv.x, 0.f);
        o.y = fmaxf(accv[r*4+1]*0.25f + bv.y, 0.f);
        o.z = fmaxf(accv[r*4+2]*0.25f + bv.z, 0.f);
        o.w = fmaxf(accv[r*4+3]*0.25f + bv.w, 0.f);
        *(float4*)&outf[(size_t)n*64 + c] = o;
      }
    }
  }
}

// ---- PostLevelAttention2 via MFMA: x3b [N,512] bf16 from xrb [N,256] bf16 ----
__global__ __launch_bounds__(256) void k_post2_mfma(
    const ushort_t* __restrict__ xrb,   // [N,256] bf16
    const ushort_t* __restrict__ Wp2t,  // [64,64] bf16 (W_post2^T)
    const float* __restrict__ hc2,      // [128,64]
    ushort_t* __restrict__ x3b){        // [N,512] bf16
  int tid = threadIdx.x;
  int w = tid >> 6, lane = tid & 63;
  int lr = lane & 15, lk = lane >> 4;
  int n0 = blockIdx.x * 64;
  int g = n0 >> 9;
  f32x4 acc[4][4];
  #pragma unroll
  for (int ri = 0; ri < 4; ++ri)
    #pragma unroll
    for (int ci = 0; ci < 4; ++ci) acc[ri][ci] = (f32x4){0.f,0.f,0.f,0.f};
  const ushort_t* Ab = xrb + (size_t)(n0 + lr)*256 + w*64 + lk*8;
  const ushort_t* Bb = Wp2t + (size_t)lr*64 + lk*8;
  #pragma unroll
  for (int k0 = 0; k0 < 64; k0 += 32){
    bf16x8 af[4], bfv[4];
    #pragma unroll
    for (int ri = 0; ri < 4; ++ri)
      af[ri] = *(const bf16x8*)(Ab + (size_t)ri*16*256 + k0);
    #pragma unroll
    for (int ci = 0; ci < 4; ++ci)
      bfv[ci] = *(const bf16x8*)(Bb + (size_t)ci*16*64 + k0);
    #pragma unroll
    for (int ri = 0; ri < 4; ++ri)
      #pragma unroll
      for (int ci = 0; ci < 4; ++ci)
        acc[ri][ci] = __builtin_amdgcn_mfma_f32_16x16x32_bf16(af[ri], bfv[ci], acc[ri][ci], 0, 0, 0);
  }
  #pragma unroll
  for (int ci = 0; ci < 4; ++ci){
    int col = ci*16 + lr;
    float hc = hc2[g*64 + col];
    #pragma unroll
    for (int ri = 0; ri < 4; ++ri){
      #pragma unroll
      for (int q = 0; q < 4; ++q){
        int row = n0 + ri*16 + lk*4 + q;
        float a = acc[ri][ci][q];
        float gg = sigmoidf_(a + hc);
        x3b[(size_t)row*512 + w*128 + col]      = f2b(gg*a + (1.f-gg)*hc);
        x3b[(size_t)row*512 + w*128 + 64 + col] = f2b(a);
      }
    }
  }
}

// ---- baseS[g][c] = b_fc[c] + sum_j xr2[root_g][j] * W_fc[j][c] (h_c3 part) ----
__global__ void k_base(const float* __restrict__ xr2, const float* __restrict__ Wfc,
                       const float* __restrict__ bfc, float* __restrict__ baseS){
  int g = blockIdx.x, c = threadIdx.x;
  const float* r = xr2 + (size_t)g*GGR*64;
  float b = bfc[c];
  for (int j = 0; j < 64; ++j) b = fmaf(r[j], Wfc[j*64 + c], b);
  baseS[g*64 + c] = b;
}

// ---- pool via MFMA: block = 64 nodes (one graph slice) x 64 outputs, K=192 ----
__global__ __launch_bounds__(256) void k_pool_mfma(
    const float* __restrict__ xr2,      // [N,64] f32
    const ushort_t* __restrict__ Wfct,  // [64,192] bf16 (W_fc[64:256]^T)
    const float* __restrict__ baseS,    // [128,64]
    float* __restrict__ shat,
    float* __restrict__ ssum){
  __shared__ __align__(16) float xs[64][68];
  __shared__ float rls[64];
  __shared__ float bs[64];
  __shared__ float ls_sh[64];
  __shared__ float ls_s[64];
  int tid = threadIdx.x;
  int n0 = blockIdx.x * 64;
  int g = n0 >> 9;
  {
    int row = tid >> 4, col4 = (tid & 15) * 4;
    #pragma unroll
    for (int i = 0; i < 4; ++i){
      float4 v = *(const float4*)&xr2[(size_t)(n0 + row + i*16)*64 + col4];
      *(float4*)&xs[row + i*16][col4] = v;
    }
    if (tid < 16){
      float4 v = *(const float4*)&xr2[(size_t)((size_t)g*GGR)*64 + tid*4];
      *(float4*)&rls[tid*4] = v;
    }
    if (tid >= 64 && tid < 128) bs[tid-64] = baseS[g*64 + (tid-64)];
    if (tid >= 128 && tid < 192){ ls_sh[tid-128] = 0.f; ls_s[tid-128] = 0.f; }
  }
  __syncthreads();
  int w = tid >> 6, lane = tid & 63;
  int lr = lane & 15, lk = lane >> 4;
  f32x4 acc[4];
  #pragma unroll
  for (int ci = 0; ci < 4; ++ci) acc[ci] = (f32x4){0.f,0.f,0.f,0.f};
  int arow = w*16 + lr;
  #pragma unroll
  for (int k0 = 0; k0 < 192; k0 += 32){
    int seg = k0 >> 6;
    int cb = (k0 & 63) + lk*8;
    bf16x8 af;
    #pragma unroll
    for (int j = 0; j < 8; ++j){
      float xv = xs[arow][cb + j];
      float rv = rls[cb + j];
      float v = (seg == 0) ? xv : (seg == 1 ? xv*rv : fabsf(rv - xv));
      af[j] = (short)f2b(v);
    }
    #pragma unroll
    for (int ci = 0; ci < 4; ++ci){
      bf16x8 bfv = *(const bf16x8*)(Wfct + (size_t)(ci*16+lr)*192 + k0 + lk*8);
      acc[ci] = __builtin_amdgcn_mfma_f32_16x16x32_bf16(af, bfv, acc[ci], 0, 0, 0);
    }
  }
  float bsv[4];
  #pragma unroll
  for (int ci = 0; ci < 4; ++ci) bsv[ci] = bs[ci*16 + lr];
  float c_sh[4] = {0.f,0.f,0.f,0.f}, c_s[4] = {0.f,0.f,0.f,0.f};
  #pragma unroll
  for (int q = 0; q < 4; ++q){
    int rrow = w*16 + lk*4 + q;
    float t[4];
    float mx = -1e30f;
    #pragma unroll
    for (int ci = 0; ci < 4; ++ci){
      t[ci] = tanhf_(acc[ci][q] + bsv[ci]);
      mx = fmaxf(mx, t[ci]);
    }
    #pragma unroll
    for (int mask = 1; mask < 16; mask <<= 1) mx = fmaxf(mx, __shfl_xor(mx, mask));
    float e[4], s = 0.f;
    #pragma unroll
    for (int ci = 0; ci < 4; ++ci){ e[ci] = __expf(t[ci] - mx); s += e[ci]; }
    #pragma unroll
    for (int mask = 1; mask < 16; mask <<= 1) s += __shfl_xor(s, mask);
    float invs = 1.0f / s;
    #pragma unroll
    for (int ci = 0; ci < 4; ++ci){
      float xv = xs[rrow][ci*16 + lr];
      c_sh[ci] = fmaf(e[ci]*invs, xv, c_sh[ci]);
      c_s[ci] += xv;
    }
  }
  #pragma unroll
  for (int ci = 0; ci < 4; ++ci){
    c_sh[ci] += __shfl_xor(c_sh[ci], 16); c_sh[ci] += __shfl_xor(c_sh[ci], 32);
    c_s[ci]  += __shfl_xor(c_s[ci], 16);  c_s[ci]  += __shfl_xor(c_s[ci], 32);
  }
  if (lk == 0){
    #pragma unroll
    for (int ci = 0; ci < 4; ++ci){
      atomicAdd(&ls_sh[ci*16 + lr], c_sh[ci]);
      atomicAdd(&ls_s[ci*16 + lr], c_s[ci]);
    }
  }
  __syncthreads();
  if (tid < 64){
    atomicAdd(&shat[g*64 + tid], ls_sh[tid]);
    atomicAdd(&ssum[g*64 + tid], ls_s[tid]);
  }
}

// ------------- final logits + log_softmax -------------
__global__ void k_final(const float* __restrict__ shat, const float* __restrict__ ssum,
                        const float* __restrict__ Wc, const float* __restrict__ bc,
                        float* __restrict__ outp){
  int g = threadIdx.x;   // 128 graphs
  float l0 = bc[0], l1 = bc[1], l2 = bc[2], l3 = bc[3];
  const float s512 = 1.0f/512.0f;
  for (int j = 0; j < 64; ++j){
    float sh = shat[g*64 + j]*s512;
    float ss = ssum[g*64 + j]*s512;
    float4 w1 = *(const float4*)&Wc[j*4];
    float4 w2 = *(const float4*)&Wc[(64+j)*4];
    l0 = fmaf(sh, w1.x, fmaf(ss, w2.x, l0));
    l1 = fmaf(sh, w1.y, fmaf(ss, w2.y, l1));
    l2 = fmaf(sh, w1.z, fmaf(ss, w2.z, l2));
    l3 = fmaf(sh, w1.w, fmaf(ss, w2.w, l3));
  }
  float mx = fmaxf(fmaxf(l0,l1), fmaxf(l2,l3));
  float s = __expf(l0-mx)+__expf(l1-mx)+__expf(l2-mx)+__expf(l3-mx);
  float lse = mx + logf(s);
  outp[g*4+0] = l0 - lse;
  outp[g*4+1] = l1 - lse;
  outp[g*4+2] = l2 - lse;
  outp[g*4+3] = l3 - lse;
}

extern "C" void kernel_launch(void* const* d_in, const int* in_sizes, int n_in,
                              void* d_out, int out_size, void* d_ws, size_t ws_size,
                              hipStream_t stream){
  const float* x        = (const float*)d_in[0];
  const float* root     = (const float*)d_in[1];
  const int*   ei       = (const int*)d_in[2];
  const float* W_post1  = (const float*)d_in[5];
  const float* W_claim1 = (const float*)d_in[6];
  const float* W1       = (const float*)d_in[7];
  const float* att_src1 = (const float*)d_in[8];
  const float* att_dst1 = (const float*)d_in[9];
  const float* b1       = (const float*)d_in[10];
  const float* W_post2  = (const float*)d_in[11];
  const float* W_claim2 = (const float*)d_in[12];
  const float* W2       = (const float*)d_in[13];
  const float* att_src2 = (const float*)d_in[14];
  const float* att_dst2 = (const float*)d_in[15];
  const float* b2       = (const float*)d_in[16];
  const float* W_fc     = (const float*)d_in[17];
  const float* b_fc     = (const float*)d_in[18];
  const float* W_clf    = (const float*)d_in[19];
  const float* b_clf    = (const float*)d_in[20];
  float* out = (float*)d_out;

  char* w = (char*)d_ws;
  size_t o = 0;
  auto alloc = [&](size_t bytes)->char*{ char* p = w + o; o += (bytes + 255) & ~(size_t)255; return p; };
  ushort_t* RA   = (ushort_t*)alloc((size_t)NN*512*2);
  ushort_t* RB   = (ushort_t*)alloc((size_t)NN*256*2);
  ushort_t* xrb  = (ushort_t*)alloc((size_t)NN*256*2);
  float* xr2  = (float*)alloc((size_t)NN*64*4);
  float* asrc = (float*)alloc((size_t)NN*4*4);
  float* adst = (float*)alloc((size_t)NN*4*4);
  float* hc1  = (float*)alloc(128*64*4);
  float* hc2  = (float*)alloc(128*64*4);
  float* baseS= (float*)alloc(128*64*4);
  ushort_t* W1t  = (ushort_t*)alloc((size_t)256*128*2);
  ushort_t* W2t  = (ushort_t*)alloc((size_t)256*512*2);
  ushort_t* Wp1t = (ushort_t*)alloc((size_t)64*512*2);
  ushort_t* Wp2t = (ushort_t*)alloc((size_t)64*64*2);
  ushort_t* Wfct = (ushort_t*)alloc((size_t)64*192*2);
  int*   deg  = (int*)alloc((size_t)NN*4);
  int*   offa = (int*)alloc((size_t)NN*4);
  int*   cur  = (int*)alloc((size_t)NN*4);
  int*   bsum = (int*)alloc(256*4);
  int*   elist= (int*)alloc((size_t)(2*EE+NN)*4);
  float* shat = (float*)alloc(128*64*4);
  float* ssumv= (float*)alloc(128*64*4);

  ushort_t* h1b = RA;    // [N,128] bf16
  ushort_t* x3b = RA;    // [N,512] bf16 (h1b dead by then)
  ushort_t* h2b = RB;    // [N,256] bf16
  ushort_t* h3b = RB;    // [N,256] bf16 (h2b dead by then)

  hipMemsetAsync(deg,   0, (size_t)NN*4, stream);
  hipMemsetAsync(cur,   0, (size_t)NN*4, stream);
  hipMemsetAsync(shat,  0, 128*64*4, stream);
  hipMemsetAsync(ssumv, 0, 128*64*4, stream);

  k_tcast<<<(128*256+255)/256, 256, 0, stream>>>(W1, W1t, 128, 256);
  k_tcast<<<(512*256+255)/256, 256, 0, stream>>>(W2, W2t, 512, 256);
  k_tcast<<<(512*64+255)/256, 256, 0, stream>>>(W_post1, Wp1t, 512, 64);
  k_tcast<<<(64*64+255)/256, 256, 0, stream>>>(W_post2, Wp2t, 64, 64);
  k_tcast<<<(192*64+255)/256, 256, 0, stream>>>(W_fc + 64*64, Wfct, 192, 64);

  k_hc<<<128, 64, 0, stream>>>(root, W_claim1, W_claim2, hc1, hc2);
  k_gemm1_mfma<<<1024, 256, 0, stream>>>(x, Wp1t, hc1, h1b);
  k_gat_mfma<128><<<1024, 256, 0, stream>>>(h1b, W1t, att_src1, att_dst1, h2b, asrc, adst);
  k_count<<<256, 256, 0, stream>>>(ei, deg);
  k_scan1<<<256, 256, 0, stream>>>(deg, offa, bsum);
  k_scan2<<<1, 256, 0, stream>>>(bsum);
  k_scan3<<<256, 256, 0, stream>>>(offa, bsum);
  k_fill<<<256, 256, 0, stream>>>(ei, offa, cur, elist);
  k_agg<1><<<4096, 256, 0, stream>>>(offa, deg, elist, h2b, asrc, adst, b1, xrb, nullptr);
  k_post2_mfma<<<1024, 256, 0, stream>>>(xrb, Wp2t, hc2, x3b);
  k_gat_mfma<512><<<1024, 256, 0, stream>>>(x3b, W2t, att_src2, att_dst2, h3b, asrc, adst);
  k_agg<2><<<4096, 256, 0, stream>>>(offa, deg, elist, h3b, asrc, adst, b2, nullptr, xr2);
  k_base<<<128, 64, 0, stream>>>(xr2, W_fc, b_fc, baseS);
  k_pool_mfma<<<1024, 256, 0, stream>>>(xr2, Wfct, baseS, shat, ssumv);
  k_final<<<1, 128, 0, stream>>>(shat, ssumv, W_clf, b_clf, out);
  (void)in_sizes; (void)n_in; (void)out_size; (void)ws_size;
}

// Round 5
// 278.898 us; speedup vs baseline: 2.7595x; 1.1781x over previous
//
#include <hip/hip_runtime.h>
#include <math.h>

#define NN   65536
#define BB   128
#define GGR  512
#define EE   65536
#define INF_ 512
#define HIDD 64

typedef __attribute__((ext_vector_type(8))) short bf16x8;
typedef __attribute__((ext_vector_type(4))) float f32x4;
typedef unsigned short ushort_t;
typedef unsigned int uint_t;

static __device__ __forceinline__ float sigmoidf_(float x){ return 1.0f/(1.0f+__expf(-x)); }
static __device__ __forceinline__ float lrelu_(float x){ return x>=0.0f ? x : 0.2f*x; }
static __device__ __forceinline__ float tanhf_(float x){
  float e = __expf(2.f*x);
  return 1.f - 2.f/(e + 1.f);
}

// f32 -> bf16 bits, round-to-nearest-even
static __device__ __forceinline__ ushort_t f2b(float f){
  union { float f; uint_t u; } v; v.f = f;
  uint_t u = v.u;
  uint_t r = (u + 0x7fffu + ((u >> 16) & 1u)) >> 16;
  return (ushort_t)r;
}
// bf16 bits -> f32 (exact)
static __device__ __forceinline__ float b2f(uint_t u16){
  union { uint_t u; float f; } v; v.u = u16 << 16; return v.f;
}

// async global->LDS, 16 bytes per lane; LDS dest = wave-uniform base + lane*16
static __device__ __forceinline__ void gld16(const void* g, void* l){
  __builtin_amdgcn_global_load_lds((const __attribute__((address_space(1))) void*)g,
                                   (__attribute__((address_space(3))) void*)l, 16, 0, 0);
}

// ---- fused prep: 5 weight transpose+casts, plus hc1/hc2 (blocks >= 832) ----
__global__ void k_prep(const float* __restrict__ W1, const float* __restrict__ W2,
                       const float* __restrict__ Wp1, const float* __restrict__ Wp2,
                       const float* __restrict__ Wfc,
                       ushort_t* __restrict__ W1t, ushort_t* __restrict__ W2t,
                       ushort_t* __restrict__ Wp1t, ushort_t* __restrict__ Wp2t,
                       ushort_t* __restrict__ Wfct,
                       const float* __restrict__ root, const float* __restrict__ Wc1,
                       const float* __restrict__ Wc2, float* __restrict__ hc1,
                       float* __restrict__ hc2){
  if (blockIdx.x >= 832){
    // hc part: one block per graph, threads 0..63
    int b = blockIdx.x - 832;
    int f = threadIdx.x;
    if (f < 64){
      const float* r = root + (size_t)b*INF_;
      float a1 = 0.f, a2 = 0.f;
      for (int k = 0; k < INF_; ++k){
        float rv = r[k];
        a1 = fmaf(rv, Wc1[k*HIDD+f], a1);
        a2 = fmaf(rv, Wc2[k*HIDD+f], a2);
      }
      hc1[b*HIDD+f] = a1; hc2[b*HIDD+f] = a2;
    }
    return;
  }
  int idx = blockIdx.x*256 + threadIdx.x;
  if (idx < 32768){                     // W1 [128,256]
    int k = idx >> 8, c = idx & 255;
    W1t[(size_t)c*128 + k] = f2b(W1[idx]);
  } else if (idx < 163840){             // W2 [512,256]
    int j = idx - 32768; int k = j >> 8, c = j & 255;
    W2t[(size_t)c*512 + k] = f2b(W2[j]);
  } else if (idx < 196608){             // W_post1 [512,64]
    int j = idx - 163840; int k = j >> 6, c = j & 63;
    Wp1t[(size_t)c*512 + k] = f2b(Wp1[j]);
  } else if (idx < 200704){             // W_post2 [64,64]
    int j = idx - 196608; int k = j >> 6, c = j & 63;
    Wp2t[(size_t)c*64 + k] = f2b(Wp2[j]);
  } else if (idx < 212992){             // W_fc rows 64..255 [192,64]
    int j = idx - 200704; int k = j >> 6, c = j & 63;
    Wfct[(size_t)c*192 + k] = f2b(Wfc[4096 + j]);
  }
}

// -------- h1 = gated(x@W_post1, hc1) via MFMA + LDS-staged A; writes [N,128] bf16 --------
__global__ __launch_bounds__(256) void k_gemm1_mfma(
    const float* __restrict__ x,        // [N,512] f32
    const ushort_t* __restrict__ Wt,    // [64,512] bf16 (W_post1^T)
    const float* __restrict__ hc1,      // [128,64]
    ushort_t* __restrict__ h1b){        // [N,128] bf16
  constexpr int BK = 128;               // f32 cols per stage
  constexpr int ROWB = BK*4;            // 512 B per row in LDS
  __shared__ __align__(16) float As[64*BK];   // 32 KB
  int tid = threadIdx.x;
  int w = tid >> 6, lane = tid & 63;
  int lr = lane & 15, lk = lane >> 4;
  int n0 = blockIdx.x * 64;
  int sw = (lr & 7) << 4;
  f32x4 acc[4];
  #pragma unroll
  for (int ci = 0; ci < 4; ++ci) acc[ci] = (f32x4){0.f,0.f,0.f,0.f};
  const char* xg = (const char*)(x + (size_t)n0*512);
  char* Ls = (char*)As;
  const ushort_t* Bb = Wt + (size_t)lr*512 + lk*8;
  int rl = w*16 + lr;
  for (int s = 0; s < 4; ++s){
    #pragma unroll
    for (int i = 0; i < 8; ++i){        // 32768 B / (256 thr * 16 B)
      int p = i*4096 + tid*16;
      int row = p >> 9;
      int l = p ^ ((row & 7) << 4);
      gld16(xg + (size_t)row*2048 + s*512 + (l & 511), Ls + p);
    }
    __syncthreads();
    #pragma unroll
    for (int k0 = 0; k0 < BK; k0 += 32){
      int lg = rl*ROWB + (k0 + lk*8)*4;
      float4 fa = *(const float4*)(Ls + (lg ^ sw));
      float4 fb = *(const float4*)(Ls + ((lg + 16) ^ sw));
      bf16x8 af;
      af[0]=(short)f2b(fa.x); af[1]=(short)f2b(fa.y); af[2]=(short)f2b(fa.z); af[3]=(short)f2b(fa.w);
      af[4]=(short)f2b(fb.x); af[5]=(short)f2b(fb.y); af[6]=(short)f2b(fb.z); af[7]=(short)f2b(fb.w);
      #pragma unroll
      for (int ci = 0; ci < 4; ++ci){
        bf16x8 bfv = *(const bf16x8*)(Bb + (size_t)ci*16*512 + s*BK + k0);
        acc[ci] = __builtin_amdgcn_mfma_f32_16x16x32_bf16(af, bfv, acc[ci], 0, 0, 0);
      }
    }
    if (s < 3) __syncthreads();
  }
  int g = n0 >> 9;
  #pragma unroll
  for (int ci = 0; ci < 4; ++ci){
    int col = ci*16 + lr;
    float hc = hc1[g*64 + col];
    #pragma unroll
    for (int q = 0; q < 4; ++q){
      int row = n0 + w*16 + lk*4 + q;
      float hx = acc[ci][q];
      float gg = sigmoidf_(hx + hc);
      float fo = gg*hx + (1.f-gg)*hc;
      h1b[(size_t)row*128 + col]      = f2b(fo);
      h1b[(size_t)row*128 + 64 + col] = f2b(hx);
    }
  }
}

// ---- GAT linear: H = A@W [N,256] MFMA, LDS-staged A + fused att logits ----
template<int K>
__global__ __launch_bounds__(256) void k_gat_mfma(
    const ushort_t* __restrict__ A,     // [N,K] bf16
    const ushort_t* __restrict__ Wt,    // [256,K] bf16 (W^T)
    const float* __restrict__ att_s,    // [4,64]
    const float* __restrict__ att_d,    // [4,64]
    ushort_t* __restrict__ Hout,        // [N,256] bf16
    float* __restrict__ asrc,           // [N,4]
    float* __restrict__ adst){          // [N,4]
  constexpr int BK = (K > 256) ? 256 : K;
  constexpr int NS = K / BK;
  constexpr int ROWB = BK * 2;          // bytes per LDS row (256 or 512)
  constexpr int RSH = (ROWB == 256) ? 8 : 9;
  __shared__ __align__(16) ushort_t As[64*BK];   // 16 or 32 KB
  int tid = threadIdx.x;
  int w = tid >> 6, lane = tid & 63;
  int lr = lane & 15, lk = lane >> 4;
  int n0 = blockIdx.x * 64;
  int c0 = w * 64;
  int sw = (lr & 7) << 4;
  f32x4 acc[4][4];
  #pragma unroll
  for (int ri = 0; ri < 4; ++ri)
    #pragma unroll
    for (int ci = 0; ci < 4; ++ci) acc[ri][ci] = (f32x4){0.f,0.f,0.f,0.f};
  const char* Ag = (const char*)(A + (size_t)n0*K);
  char* Ls = (char*)As;
  const ushort_t* Bb = Wt + (size_t)(c0 + lr)*K + lk*8;
  for (int s = 0; s < NS; ++s){
    #pragma unroll
    for (int i = 0; i < (64*ROWB)/4096; ++i){
      int p = i*4096 + tid*16;
      int row = p >> RSH;
      int l = p ^ ((row & 7) << 4);
      gld16(Ag + (size_t)row*(K*2) + s*ROWB + (l & (ROWB-1)), Ls + p);
    }
    __syncthreads();
    #pragma unroll
    for (int k0 = 0; k0 < BK; k0 += 32){
      bf16x8 af[4], bfv[4];
      #pragma unroll
      for (int ri = 0; ri < 4; ++ri){
        int lg = (ri*16 + lr)*ROWB + (k0 + lk*8)*2;
        af[ri] = *(const bf16x8*)(Ls + (lg ^ sw));
      }
      #pragma unroll
      for (int ci = 0; ci < 4; ++ci)
        bfv[ci] = *(const bf16x8*)(Bb + (size_t)ci*16*K + s*BK + k0);
      #pragma unroll
      for (int ri = 0; ri < 4; ++ri)
        #pragma unroll
        for (int ci = 0; ci < 4; ++ci)
          acc[ri][ci] = __builtin_amdgcn_mfma_f32_16x16x32_bf16(af[ri], bfv[ci], acc[ri][ci], 0, 0, 0);
    }
    if (s + 1 < NS) __syncthreads();
  }
  float as_[4], ad_[4];
  #pragma unroll
  for (int ci = 0; ci < 4; ++ci){
    as_[ci] = att_s[c0 + ci*16 + lr];
    ad_[ci] = att_d[c0 + ci*16 + lr];
  }
  #pragma unroll
  for (int ri = 0; ri < 4; ++ri){
    #pragma unroll
    for (int q = 0; q < 4; ++q){
      int row = n0 + ri*16 + lk*4 + q;
      float ps = 0.f, pd = 0.f;
      #pragma unroll
      for (int ci = 0; ci < 4; ++ci){
        float v = acc[ri][ci][q];
        Hout[(size_t)row*256 + c0 + ci*16 + lr] = f2b(v);
        ps = fmaf(v, as_[ci], ps);
        pd = fmaf(v, ad_[ci], pd);
      }
      #pragma unroll
      for (int m = 1; m < 16; m <<= 1){
        ps += __shfl_xor(ps, m);
        pd += __shfl_xor(pd, m);
      }
      if (lr == 0){
        asrc[(size_t)row*4 + w] = ps;
        adst[(size_t)row*4 + w] = pd;
      }
    }
  }
}

// ---------------- CSR build ----------------
__global__ void k_count(const int* __restrict__ ei, int* __restrict__ deg){
  int t = blockIdx.x*256 + threadIdx.x;
  int s = ei[t], d = ei[EE + t];
  atomicAdd(&deg[d], 1);
  atomicAdd(&deg[s], 1);
}

__global__ void k_scan1(const int* __restrict__ deg, int* __restrict__ offa,
                        int* __restrict__ bsum){
  __shared__ int sm[256];
  int tid = threadIdx.x, idx = blockIdx.x*256 + tid;
  int v = deg[idx] + 1;                 // +1 self-loop
  sm[tid] = v; __syncthreads();
  for (int o = 1; o < 256; o <<= 1){
    int t = (tid >= o) ? sm[tid-o] : 0;
    __syncthreads();
    sm[tid] += t;
    __syncthreads();
  }
  offa[idx] = sm[tid] - v;
  if (tid == 255) bsum[blockIdx.x] = sm[255];
}

__global__ void k_scan2(int* __restrict__ bsum){
  __shared__ int sm[256];
  int tid = threadIdx.x;
  int v = bsum[tid];
  sm[tid] = v; __syncthreads();
  for (int o = 1; o < 256; o <<= 1){
    int t = (tid >= o) ? sm[tid-o] : 0;
    __syncthreads();
    sm[tid] += t;
    __syncthreads();
  }
  bsum[tid] = sm[tid] - v;
}

__global__ void k_scan3(int* __restrict__ offa, const int* __restrict__ bsum){
  int idx = blockIdx.x*256 + threadIdx.x;
  offa[idx] += bsum[idx >> 8];
}

__global__ void k_fill(const int* __restrict__ ei, const int* __restrict__ offa,
                       int* __restrict__ cur, int* __restrict__ elist){
  int t = blockIdx.x*256 + threadIdx.x;
  int s = ei[t], d = ei[EE + t];
  int p = atomicAdd(&cur[d], 1); elist[offa[d] + p] = s;   // TD edge
  p = atomicAdd(&cur[s], 1);     elist[offa[s] + p] = d;   // BU (flipped) edge
  p = atomicAdd(&cur[t], 1);     elist[offa[t] + p] = t;   // self-loop (E==N)
}

// ------ GAT softmax-aggregate (h bf16); XCD-swizzled; e-values cached in LDS ------
template<int LAYER>
__global__ __launch_bounds__(256) void k_agg(const int* __restrict__ offa,
                                             const int* __restrict__ deg,
                                             const int* __restrict__ elist,
                                             const ushort_t* __restrict__ h,  // [N,256] bf16
                                             const float* __restrict__ asrc,
                                             const float* __restrict__ adst,
                                             const float* __restrict__ bias,
                                             ushort_t* __restrict__ outb,
                                             float* __restrict__ outf){
  __shared__ float eS[4][4][17][4];     // [wave][grp][edge(pad17)][head]
  __shared__ int   sS[4][4][17];
  int bid = blockIdx.x;
  int swz = (bid & 7) * (4096/8) + (bid >> 3);   // XCD-contiguous graphs
  int tid = threadIdx.x;
  int wave = tid >> 6, lane = tid & 63;
  int grp = lane >> 4, l = lane & 15;           // 4 dst nodes per wave, 16 lanes each
  int n = swz*16 + wave*4 + grp;
  int o0 = offa[n], cnt = deg[n] + 1;
  float4 adv = *(const float4*)&adst[(size_t)n*4];
  float ad[4] = {adv.x, adv.y, adv.z, adv.w};
  int lim = (cnt < 16) ? cnt : 16;
  // pass 1: lane l owns edge l (if any); gather asrc once, stash e + s in LDS
  int s_l = elist[o0 + ((l < cnt) ? l : 0)];
  float4 asv = *(const float4*)&asrc[(size_t)s_l*4];
  float e_l[4];
  e_l[0] = lrelu_(asv.x + ad[0]); e_l[1] = lrelu_(asv.y + ad[1]);
  e_l[2] = lrelu_(asv.z + ad[2]); e_l[3] = lrelu_(asv.w + ad[3]);
  if (l < lim){
    sS[wave][grp][l] = s_l;
    *(float4*)&eS[wave][grp][l][0] = make_float4(e_l[0], e_l[1], e_l[2], e_l[3]);
  }
  float m[4];
  #pragma unroll
  for (int hh = 0; hh < 4; ++hh) m[hh] = (l < cnt) ? e_l[hh] : -1e30f;
  for (int i = 16 + l; i < cnt; i += 16){       // rare tail
    int s = elist[o0 + i];
    float4 a2 = *(const float4*)&asrc[(size_t)s*4];
    m[0] = fmaxf(m[0], lrelu_(a2.x + ad[0]));
    m[1] = fmaxf(m[1], lrelu_(a2.y + ad[1]));
    m[2] = fmaxf(m[2], lrelu_(a2.z + ad[2]));
    m[3] = fmaxf(m[3], lrelu_(a2.w + ad[3]));
  }
  #pragma unroll
  for (int mask = 1; mask < 16; mask <<= 1)
    #pragma unroll
    for (int hh = 0; hh < 4; ++hh) m[hh] = fmaxf(m[hh], __shfl_xor(m[hh], mask));
  // pass 2: lane owns 16 channels; only global access is the h gather
  int myh = l >> 2;
  float mm = m[myh];
  float den = 0.f;
  float accv[16] = {};
  for (int i = 0; i < lim; ++i){
    int s = sS[wave][grp][i];
    float e = eS[wave][grp][i][myh];
    float ex = __expf(e - mm);
    den += ex;
    const uint4* hp = (const uint4*)(h + (size_t)s*256 + l*16);
    uint4 h0 = hp[0], h1v = hp[1];
    uint_t uu[8] = {h0.x, h0.y, h0.z, h0.w, h1v.x, h1v.y, h1v.z, h1v.w};
    #pragma unroll
    for (int r = 0; r < 8; ++r){
      accv[2*r+0] = fmaf(ex, b2f(uu[r] & 0xffffu), accv[2*r+0]);
      accv[2*r+1] = fmaf(ex, b2f(uu[r] >> 16),     accv[2*r+1]);
    }
  }
  for (int i = 16; i < cnt; ++i){               // rare tail
    int s = elist[o0 + i];
    float4 a2 = *(const float4*)&asrc[(size_t)s*4];
    float e = lrelu_(((const float*)&a2)[myh] + ad[myh]);
    float ex = __expf(e - mm);
    den += ex;
    const uint4* hp = (const uint4*)(h + (size_t)s*256 + l*16);
    uint4 h0 = hp[0], h1v = hp[1];
    uint_t uu[8] = {h0.x, h0.y, h0.z, h0.w, h1v.x, h1v.y, h1v.z, h1v.w};
    #pragma unroll
    for (int r = 0; r < 8; ++r){
      accv[2*r+0] = fmaf(ex, b2f(uu[r] & 0xffffu), accv[2*r+0]);
      accv[2*r+1] = fmaf(ex, b2f(uu[r] >> 16),     accv[2*r+1]);
    }
  }
  float inv = 1.0f / den;
  if (LAYER == 1){
    #pragma unroll
    for (int r = 0; r < 4; ++r){
      int c = l*16 + r*4;
      float4 bv = *(const float4*)&bias[c];
      float o0v = fmaxf(accv[r*4+0]*inv + bv.x, 0.f);
      float o1v = fmaxf(accv[r*4+1]*inv + bv.y, 0.f);
      float o2v = fmaxf(accv[r*4+2]*inv + bv.z, 0.f);
      float o3v = fmaxf(accv[r*4+3]*inv + bv.w, 0.f);
      uint2 pk;
      pk.x = (uint_t)f2b(o0v) | ((uint_t)f2b(o1v) << 16);
      pk.y = (uint_t)f2b(o2v) | ((uint_t)f2b(o3v) << 16);
      *(uint2*)&outb[(size_t)n*256 + c] = pk;
    }
  } else {
    #pragma unroll
    for (int r = 0; r < 16; ++r) accv[r] *= inv;
    #pragma unroll
    for (int r = 0; r < 16; ++r){
      accv[r] += __shfl_xor(accv[r], 4);
      accv[r] += __shfl_xor(accv[r], 8);
    }
    if (l < 4){
      #pragma unroll
      for (int r = 0; r < 4; ++r){
        int c = l*16 + r*4;
        float4 bv = *(const float4*)&bias[c];
        float4 o;
        o.x = fmaxf(accv[r*4+0]*0.25f + bv.x, 0.f);
        o.y = fmaxf(accv[r*4+1]*0.25f + bv.y, 0.f);
        o.z = fmaxf(accv[r*4+2]*0.25f + bv.z, 0.f);
        o.w = fmaxf(accv[r*4+3]*0.25f + bv.w, 0.f);
        *(float4*)&outf[(size_t)n*64 + c] = o;
      }
    }
  }
}

// ---- PostLevelAttention2 via MFMA: x3b [N,512] bf16 from xrb [N,256] bf16 ----
__global__ __launch_bounds__(256) void k_post2_mfma(
    const ushort_t* __restrict__ xrb,   // [N,256] bf16
    const ushort_t* __restrict__ Wp2t,  // [64,64] bf16 (W_post2^T)
    const float* __restrict__ hc2,      // [128,64]
    ushort_t* __restrict__ x3b){        // [N,512] bf16
  int tid = threadIdx.x;
  int w = tid >> 6, lane = tid & 63;
  int lr = lane & 15, lk = lane >> 4;
  int n0 = blockIdx.x * 64;
  int g = n0 >> 9;
  f32x4 acc[4][4];
  #pragma unroll
  for (int ri = 0; ri < 4; ++ri)
    #pragma unroll
    for (int ci = 0; ci < 4; ++ci) acc[ri][ci] = (f32x4){0.f,0.f,0.f,0.f};
  const ushort_t* Ab = xrb + (size_t)(n0 + lr)*256 + w*64 + lk*8;
  const ushort_t* Bb = Wp2t + (size_t)lr*64 + lk*8;
  #pragma unroll
  for (int k0 = 0; k0 < 64; k0 += 32){
    bf16x8 af[4], bfv[4];
    #pragma unroll
    for (int ri = 0; ri < 4; ++ri)
      af[ri] = *(const bf16x8*)(Ab + (size_t)ri*16*256 + k0);
    #pragma unroll
    for (int ci = 0; ci < 4; ++ci)
      bfv[ci] = *(const bf16x8*)(Bb + (size_t)ci*16*64 + k0);
    #pragma unroll
    for (int ri = 0; ri < 4; ++ri)
      #pragma unroll
      for (int ci = 0; ci < 4; ++ci)
        acc[ri][ci] = __builtin_amdgcn_mfma_f32_16x16x32_bf16(af[ri], bfv[ci], acc[ri][ci], 0, 0, 0);
  }
  #pragma unroll
  for (int ci = 0; ci < 4; ++ci){
    int col = ci*16 + lr;
    float hc = hc2[g*64 + col];
    #pragma unroll
    for (int ri = 0; ri < 4; ++ri){
      #pragma unroll
      for (int q = 0; q < 4; ++q){
        int row = n0 + ri*16 + lk*4 + q;
        float a = acc[ri][ci][q];
        float gg = sigmoidf_(a + hc);
        x3b[(size_t)row*512 + w*128 + col]      = f2b(gg*a + (1.f-gg)*hc);
        x3b[(size_t)row*512 + w*128 + 64 + col] = f2b(a);
      }
    }
  }
}

// ---- baseS[g][c] = b_fc[c] + sum_j xr2[root_g][j] * W_fc[j][c] (h_c3 part) ----
__global__ void k_base(const float* __restrict__ xr2, const float* __restrict__ Wfc,
                       const float* __restrict__ bfc, float* __restrict__ baseS){
  int g = blockIdx.x, c = threadIdx.x;
  const float* r = xr2 + (size_t)g*GGR*64;
  float b = bfc[c];
  for (int j = 0; j < 64; ++j) b = fmaf(r[j], Wfc[j*64 + c], b);
  baseS[g*64 + c] = b;
}

// ---- pool via MFMA: block = 64 nodes (one graph slice) x 64 outputs, K=192 ----
__global__ __launch_bounds__(256) void k_pool_mfma(
    const float* __restrict__ xr2,      // [N,64] f32
    const ushort_t* __restrict__ Wfct,  // [64,192] bf16 (W_fc[64:256]^T)
    const float* __restrict__ baseS,    // [128,64]
    float* __restrict__ shat,
    float* __restrict__ ssum){
  __shared__ __align__(16) float xs[64][68];
  __shared__ float rls[64];
  __shared__ float bs[64];
  __shared__ float ls_sh[64];
  __shared__ float ls_s[64];
  int tid = threadIdx.x;
  int n0 = blockIdx.x * 64;
  int g = n0 >> 9;
  {
    int row = tid >> 4, col4 = (tid & 15) * 4;
    #pragma unroll
    for (int i = 0; i < 4; ++i){
      float4 v = *(const float4*)&xr2[(size_t)(n0 + row + i*16)*64 + col4];
      *(float4*)&xs[row + i*16][col4] = v;
    }
    if (tid < 16){
      float4 v = *(const float4*)&xr2[(size_t)((size_t)g*GGR)*64 + tid*4];
      *(float4*)&rls[tid*4] = v;
    }
    if (tid >= 64 && tid < 128) bs[tid-64] = baseS[g*64 + (tid-64)];
    if (tid >= 128 && tid < 192){ ls_sh[tid-128] = 0.f; ls_s[tid-128] = 0.f; }
  }
  __syncthreads();
  int w = tid >> 6, lane = tid & 63;
  int lr = lane & 15, lk = lane >> 4;
  f32x4 acc[4];
  #pragma unroll
  for (int ci = 0; ci < 4; ++ci) acc[ci] = (f32x4){0.f,0.f,0.f,0.f};
  int arow = w*16 + lr;
  #pragma unroll
  for (int k0 = 0; k0 < 192; k0 += 32){
    int seg = k0 >> 6;
    int cb = (k0 & 63) + lk*8;
    bf16x8 af;
    #pragma unroll
    for (int j = 0; j < 8; ++j){
      float xv = xs[arow][cb + j];
      float rv = rls[cb + j];
      float v = (seg == 0) ? xv : (seg == 1 ? xv*rv : fabsf(rv - xv));
      af[j] = (short)f2b(v);
    }
    #pragma unroll
    for (int ci = 0; ci < 4; ++ci){
      bf16x8 bfv = *(const bf16x8*)(Wfct + (size_t)(ci*16+lr)*192 + k0 + lk*8);
      acc[ci] = __builtin_amdgcn_mfma_f32_16x16x32_bf16(af, bfv, acc[ci], 0, 0, 0);
    }
  }
  float bsv[4];
  #pragma unroll
  for (int ci = 0; ci < 4; ++ci) bsv[ci] = bs[ci*16 + lr];
  float c_sh[4] = {0.f,0.f,0.f,0.f}, c_s[4] = {0.f,0.f,0.f,0.f};
  #pragma unroll
  for (int q = 0; q < 4; ++q){
    int rrow = w*16 + lk*4 + q;
    float t[4];
    float mx = -1e30f;
    #pragma unroll
    for (int ci = 0; ci < 4; ++ci){
      t[ci] = tanhf_(acc[ci][q] + bsv[ci]);
      mx = fmaxf(mx, t[ci]);
    }
    #pragma unroll
    for (int mask = 1; mask < 16; mask <<= 1) mx = fmaxf(mx, __shfl_xor(mx, mask));
    float e[4], s = 0.f;
    #pragma unroll
    for (int ci = 0; ci < 4; ++ci){ e[ci] = __expf(t[ci] - mx); s += e[ci]; }
    #pragma unroll
    for (int mask = 1; mask < 16; mask <<= 1) s += __shfl_xor(s, mask);
    float invs = 1.0f / s;
    #pragma unroll
    for (int ci = 0; ci < 4; ++ci){
      float xv = xs[rrow][ci*16 + lr];
      c_sh[ci] = fmaf(e[ci]*invs, xv, c_sh[ci]);
      c_s[ci] += xv;
    }
  }
  #pragma unroll
  for (int ci = 0; ci < 4; ++ci){
    c_sh[ci] += __shfl_xor(c_sh[ci], 16); c_sh[ci] += __shfl_xor(c_sh[ci], 32);
    c_s[ci]  += __shfl_xor(c_s[ci], 16);  c_s[ci]  += __shfl_xor(c_s[ci], 32);
  }
  if (lk == 0){
    #pragma unroll
    for (int ci = 0; ci < 4; ++ci){
      atomicAdd(&ls_sh[ci*16 + lr], c_sh[ci]);
      atomicAdd(&ls_s[ci*16 + lr], c_s[ci]);
    }
  }
  __syncthreads();
  if (tid < 64){
    atomicAdd(&shat[g*64 + tid], ls_sh[tid]);
    atomicAdd(&ssum[g*64 + tid], ls_s[tid]);
  }
}

// ------------- final logits + log_softmax -------------
__global__ void k_final(const float* __restrict__ shat, const float* __restrict__ ssum,
                        const float* __restrict__ Wc, const float* __restrict__ bc,
                        float* __restrict__ outp){
  int g = threadIdx.x;   // 128 graphs
  float l0 = bc[0], l1 = bc[1], l2 = bc[2], l3 = bc[3];
  const float s512 = 1.0f/512.0f;
  for (int j = 0; j < 64; ++j){
    float sh = shat[g*64 + j]*s512;
    float ss = ssum[g*64 + j]*s512;
    float4 w1 = *(const float4*)&Wc[j*4];
    float4 w2 = *(const float4*)&Wc[(64+j)*4];
    l0 = fmaf(sh, w1.x, fmaf(ss, w2.x, l0));
    l1 = fmaf(sh, w1.y, fmaf(ss, w2.y, l1));
    l2 = fmaf(sh, w1.z, fmaf(ss, w2.z, l2));
    l3 = fmaf(sh, w1.w, fmaf(ss, w2.w, l3));
  }
  float mx = fmaxf(fmaxf(l0,l1), fmaxf(l2,l3));
  float s = __expf(l0-mx)+__expf(l1-mx)+__expf(l2-mx)+__expf(l3-mx);
  float lse = mx + logf(s);
  outp[g*4+0] = l0 - lse;
  outp[g*4+1] = l1 - lse;
  outp[g*4+2] = l2 - lse;
  outp[g*4+3] = l3 - lse;
}

extern "C" void kernel_launch(void* const* d_in, const int* in_sizes, int n_in,
                              void* d_out, int out_size, void* d_ws, size_t ws_size,
                              hipStream_t stream){
  const float* x        = (const float*)d_in[0];
  const float* root     = (const float*)d_in[1];
  const int*   ei       = (const int*)d_in[2];
  const float* W_post1  = (const float*)d_in[5];
  const float* W_claim1 = (const float*)d_in[6];
  const float* W1       = (const float*)d_in[7];
  const float* att_src1 = (const float*)d_in[8];
  const float* att_dst1 = (const float*)d_in[9];
  const float* b1       = (const float*)d_in[10];
  const float* W_post2  = (const float*)d_in[11];
  const float* W_claim2 = (const float*)d_in[12];
  const float* W2       = (const float*)d_in[13];
  const float* att_src2 = (const float*)d_in[14];
  const float* att_dst2 = (const float*)d_in[15];
  const float* b2       = (const float*)d_in[16];
  const float* W_fc     = (const float*)d_in[17];
  const float* b_fc     = (const float*)d_in[18];
  const float* W_clf    = (const float*)d_in[19];
  const float* b_clf    = (const float*)d_in[20];
  float* out = (float*)d_out;

  char* w = (char*)d_ws;
  size_t o = 0;
  auto alloc = [&](size_t bytes)->char*{ char* p = w + o; o += (bytes + 255) & ~(size_t)255; return p; };
  ushort_t* RA   = (ushort_t*)alloc((size_t)NN*512*2);
  ushort_t* RB   = (ushort_t*)alloc((size_t)NN*256*2);
  ushort_t* xrb  = (ushort_t*)alloc((size_t)NN*256*2);
  float* xr2  = (float*)alloc((size_t)NN*64*4);
  float* asrc = (float*)alloc((size_t)NN*4*4);
  float* adst = (float*)alloc((size_t)NN*4*4);
  float* hc1  = (float*)alloc(128*64*4);
  float* hc2  = (float*)alloc(128*64*4);
  float* baseS= (float*)alloc(128*64*4);
  ushort_t* W1t  = (ushort_t*)alloc((size_t)256*128*2);
  ushort_t* W2t  = (ushort_t*)alloc((size_t)256*512*2);
  ushort_t* Wp1t = (ushort_t*)alloc((size_t)64*512*2);
  ushort_t* Wp2t = (ushort_t*)alloc((size_t)64*64*2);
  ushort_t* Wfct = (ushort_t*)alloc((size_t)64*192*2);
  int*   deg  = (int*)alloc((size_t)NN*4);
  int*   cur  = (int*)alloc((size_t)NN*4);      // adjacent to deg: one memset
  int*   offa = (int*)alloc((size_t)NN*4);
  int*   bsum = (int*)alloc(256*4);
  int*   elist= (int*)alloc((size_t)(2*EE+NN)*4);
  float* shat = (float*)alloc(128*64*4);
  float* ssumv= (float*)alloc(128*64*4);        // adjacent to shat: one memset

  ushort_t* h1b = RA;    // [N,128] bf16
  ushort_t* x3b = RA;    // [N,512] bf16 (h1b dead by then)
  ushort_t* h2b = RB;    // [N,256] bf16
  ushort_t* h3b = RB;    // [N,256] bf16 (h2b dead by then)

  hipMemsetAsync(deg,  0, (size_t)NN*8, stream);     // deg + cur
  hipMemsetAsync(shat, 0, 2*128*64*4 + 256, stream); // shat + ssumv (ssumv starts at shat+8448 floats? padded alloc) 

  // NOTE: shat alloc is 32768 B -> padded to 32768 (multiple of 256), so ssumv = shat + 32768 B.
  // The memset above covers 65536+256 B which spans both (and nothing else is after ssumv yet used before init).

  k_prep<<<960, 256, 0, stream>>>(W1, W2, W_post1, W_post2, W_fc,
                                  W1t, W2t, Wp1t, Wp2t, Wfct,
                                  root, W_claim1, W_claim2, hc1, hc2);
  k_gemm1_mfma<<<1024, 256, 0, stream>>>(x, Wp1t, hc1, h1b);
  k_gat_mfma<128><<<1024, 256, 0, stream>>>(h1b, W1t, att_src1, att_dst1, h2b, asrc, adst);
  k_count<<<256, 256, 0, stream>>>(ei, deg);
  k_scan1<<<256, 256, 0, stream>>>(deg, offa, bsum);
  k_scan2<<<1, 256, 0, stream>>>(bsum);
  k_scan3<<<256, 256, 0, stream>>>(offa, bsum);
  k_fill<<<256, 256, 0, stream>>>(ei, offa, cur, elist);
  k_agg<1><<<4096, 256, 0, stream>>>(offa, deg, elist, h2b, asrc, adst, b1, xrb, nullptr);
  k_post2_mfma<<<1024, 256, 0, stream>>>(xrb, Wp2t, hc2, x3b);
  k_gat_mfma<512><<<1024, 256, 0, stream>>>(x3b, W2t, att_src2, att_dst2, h3b, asrc, adst);
  k_agg<2><<<4096, 256, 0, stream>>>(offa, deg, elist, h3b, asrc, adst, b2, nullptr, xr2);
  k_base<<<128, 64, 0, stream>>>(xr2, W_fc, b_fc, baseS);
  k_pool_mfma<<<1024, 256, 0, stream>>>(xr2, Wfct, baseS, shat, ssumv);
  k_final<<<1, 128, 0, stream>>>(shat, ssumv, W_clf, b_clf, out);
  (void)in_sizes; (void)n_in; (void)out_size; (void)ws_size;
}

// Round 6
// 263.774 us; speedup vs baseline: 2.9177x; 1.0573x over previous
//
#include <hip/hip_runtime.h>
#include <math.h>

#define NN   65536
#define BB   128
#define GGR  512
#define EE   65536
#define INF_ 512
#define HIDD 64

typedef __attribute__((ext_vector_type(8))) short bf16x8;
typedef __attribute__((ext_vector_type(4))) float f32x4;
typedef unsigned short ushort_t;
typedef unsigned int uint_t;

static __device__ __forceinline__ float sigmoidf_(float x){ return 1.0f/(1.0f+__expf(-x)); }
static __device__ __forceinline__ float lrelu_(float x){ return x>=0.0f ? x : 0.2f*x; }
static __device__ __forceinline__ float tanhf_(float x){
  float e = __expf(2.f*x);
  return 1.f - 2.f/(e + 1.f);
}

// f32 -> bf16 bits, round-to-nearest-even
static __device__ __forceinline__ ushort_t f2b(float f){
  union { float f; uint_t u; } v; v.f = f;
  uint_t u = v.u;
  uint_t r = (u + 0x7fffu + ((u >> 16) & 1u)) >> 16;
  return (ushort_t)r;
}
// bf16 bits -> f32 (exact)
static __device__ __forceinline__ float b2f(uint_t u16){
  union { uint_t u; float f; } v; v.u = u16 << 16; return v.f;
}

// async global->LDS, 16 bytes per lane
static __device__ __forceinline__ void gld16(const void* g, void* l){
  __builtin_amdgcn_global_load_lds((const __attribute__((address_space(1))) void*)g,
                                   (__attribute__((address_space(3))) void*)l, 16, 0, 0);
}

// ---- fused prep: weight transpose+casts, plus hc1/hc2 (blocks >= 832) ----
__global__ void k_prep(const float* __restrict__ W1, const float* __restrict__ W2,
                       const float* __restrict__ Wp1, const float* __restrict__ Wp2,
                       const float* __restrict__ Wfc,
                       ushort_t* __restrict__ W1t, ushort_t* __restrict__ W2t,
                       ushort_t* __restrict__ Wp1t, ushort_t* __restrict__ Wp2t,
                       ushort_t* __restrict__ Wfct,
                       const float* __restrict__ root, const float* __restrict__ Wc1,
                       const float* __restrict__ Wc2, float* __restrict__ hc1,
                       float* __restrict__ hc2){
  if (blockIdx.x >= 832){
    int b = blockIdx.x - 832;
    int f = threadIdx.x;
    if (f < 64){
      const float* r = root + (size_t)b*INF_;
      float a1 = 0.f, a2 = 0.f;
      for (int k = 0; k < INF_; ++k){
        float rv = r[k];
        a1 = fmaf(rv, Wc1[k*HIDD+f], a1);
        a2 = fmaf(rv, Wc2[k*HIDD+f], a2);
      }
      hc1[b*HIDD+f] = a1; hc2[b*HIDD+f] = a2;
    }
    return;
  }
  int idx = blockIdx.x*256 + threadIdx.x;
  if (idx < 32768){                     // W1 [128,256]
    int k = idx >> 8, c = idx & 255;
    W1t[(size_t)c*128 + k] = f2b(W1[idx]);
  } else if (idx < 163840){             // W2 [512,256]
    int j = idx - 32768; int k = j >> 8, c = j & 255;
    W2t[(size_t)c*512 + k] = f2b(W2[j]);
  } else if (idx < 196608){             // W_post1 [512,64]
    int j = idx - 163840; int k = j >> 6, c = j & 63;
    Wp1t[(size_t)c*512 + k] = f2b(Wp1[j]);
  } else if (idx < 200704){             // W_post2 [64,64]
    int j = idx - 196608; int k = j >> 6, c = j & 63;
    Wp2t[(size_t)c*64 + k] = f2b(Wp2[j]);
  } else if (idx < 212992){             // W_fc rows 64..255 [192,64]
    int j = idx - 200704; int k = j >> 6, c = j & 63;
    Wfct[(size_t)c*192 + k] = f2b(Wfc[4096 + j]);
  }
}

// ==== fused layer 1: h1 = gated(x@W_post1, hc1) [LDS] -> H = h1@W1 + att logits ====
__global__ __launch_bounds__(256) void k_l1(
    const float* __restrict__ x,        // [N,512] f32
    const ushort_t* __restrict__ Wp1t,  // [64,512] bf16
    const float* __restrict__ hc1,      // [128,64]
    const ushort_t* __restrict__ W1t,   // [256,128] bf16
    const float* __restrict__ att_s, const float* __restrict__ att_d,
    ushort_t* __restrict__ Hout,        // [N,256] bf16
    float* __restrict__ asrc, float* __restrict__ adst){
  __shared__ __align__(16) float xs[64*128];      // 32 KB f32 staging
  __shared__ __align__(16) ushort_t h1s[64*128];  // 16 KB h1 tile (swizzled)
  int tid = threadIdx.x;
  int w = tid >> 6, lane = tid & 63;
  int lr = lane & 15, lk = lane >> 4;
  int n0 = blockIdx.x * 64;
  int g = n0 >> 9;
  int sw = (lr & 7) << 4;
  // ---------- phase A: h_x rows w*16..w*16+15, cols 0..63 ----------
  f32x4 accA[4];
  #pragma unroll
  for (int ci = 0; ci < 4; ++ci) accA[ci] = (f32x4){0.f,0.f,0.f,0.f};
  const char* xg = (const char*)(x + (size_t)n0*512);
  char* Ls = (char*)xs;
  const ushort_t* BbA = Wp1t + (size_t)lr*512 + lk*8;
  int rl = w*16 + lr;
  for (int s = 0; s < 4; ++s){
    #pragma unroll
    for (int i = 0; i < 8; ++i){
      int p = i*4096 + tid*16;
      int row = p >> 9;
      int l = p ^ ((row & 7) << 4);
      gld16(xg + (size_t)row*2048 + s*512 + (l & 511), Ls + p);
    }
    __syncthreads();
    #pragma unroll
    for (int k0 = 0; k0 < 128; k0 += 32){
      int lg = rl*512 + (k0 + lk*8)*4;
      float4 fa = *(const float4*)(Ls + (lg ^ sw));
      float4 fb = *(const float4*)(Ls + ((lg + 16) ^ sw));
      bf16x8 af;
      af[0]=(short)f2b(fa.x); af[1]=(short)f2b(fa.y); af[2]=(short)f2b(fa.z); af[3]=(short)f2b(fa.w);
      af[4]=(short)f2b(fb.x); af[5]=(short)f2b(fb.y); af[6]=(short)f2b(fb.z); af[7]=(short)f2b(fb.w);
      #pragma unroll
      for (int ci = 0; ci < 4; ++ci){
        bf16x8 bfv = *(const bf16x8*)(BbA + (size_t)ci*16*512 + s*128 + k0);
        accA[ci] = __builtin_amdgcn_mfma_f32_16x16x32_bf16(af, bfv, accA[ci], 0, 0, 0);
      }
    }
    __syncthreads();
  }
  // gate + write h1 tile into LDS (XOR-swizzled rows, 256 B/row)
  char* Hc = (char*)h1s;
  #pragma unroll
  for (int ci = 0; ci < 4; ++ci){
    int col = ci*16 + lr;
    float hc = hc1[g*64 + col];
    #pragma unroll
    for (int q = 0; q < 4; ++q){
      int row = w*16 + lk*4 + q;
      int swr = (row & 7) << 4;
      float hx = accA[ci][q];
      float gg = sigmoidf_(hx + hc);
      float fo = gg*hx + (1.f-gg)*hc;
      *(ushort_t*)(Hc + ((row*256 + col*2) ^ swr))        = f2b(fo);
      *(ushort_t*)(Hc + ((row*256 + (64 + col)*2) ^ swr)) = f2b(hx);
    }
  }
  __syncthreads();
  // ---------- phase B: H = h1 @ W1 (K=128), wave = output head ----------
  int c0 = w * 64;
  f32x4 acc[4][4];
  #pragma unroll
  for (int ri = 0; ri < 4; ++ri)
    #pragma unroll
    for (int ci = 0; ci < 4; ++ci) acc[ri][ci] = (f32x4){0.f,0.f,0.f,0.f};
  #pragma unroll
  for (int k0 = 0; k0 < 128; k0 += 32){
    bf16x8 af[4], bfv[4];
    #pragma unroll
    for (int ri = 0; ri < 4; ++ri){
      int lg = (ri*16 + lr)*256 + (k0 + lk*8)*2;
      af[ri] = *(const bf16x8*)(Hc + (lg ^ sw));
    }
    #pragma unroll
    for (int ci = 0; ci < 4; ++ci)
      bfv[ci] = *(const bf16x8*)(W1t + (size_t)(c0 + ci*16 + lr)*128 + k0 + lk*8);
    #pragma unroll
    for (int ri = 0; ri < 4; ++ri)
      #pragma unroll
      for (int ci = 0; ci < 4; ++ci)
        acc[ri][ci] = __builtin_amdgcn_mfma_f32_16x16x32_bf16(af[ri], bfv[ci], acc[ri][ci], 0, 0, 0);
  }
  float as_[4], ad_[4];
  #pragma unroll
  for (int ci = 0; ci < 4; ++ci){
    as_[ci] = att_s[c0 + ci*16 + lr];
    ad_[ci] = att_d[c0 + ci*16 + lr];
  }
  #pragma unroll
  for (int ri = 0; ri < 4; ++ri){
    #pragma unroll
    for (int q = 0; q < 4; ++q){
      int row = n0 + ri*16 + lk*4 + q;
      float ps = 0.f, pd = 0.f;
      #pragma unroll
      for (int ci = 0; ci < 4; ++ci){
        float v = acc[ri][ci][q];
        Hout[(size_t)row*256 + c0 + ci*16 + lr] = f2b(v);
        ps = fmaf(v, as_[ci], ps);
        pd = fmaf(v, ad_[ci], pd);
      }
      #pragma unroll
      for (int m = 1; m < 16; m <<= 1){
        ps += __shfl_xor(ps, m);
        pd += __shfl_xor(pd, m);
      }
      if (lr == 0){
        asrc[(size_t)row*4 + w] = ps;
        adst[(size_t)row*4 + w] = pd;
      }
    }
  }
}

// ==== fused layer 2: x3 slab (per head) in LDS -> H = x3@W2 + att logits ====
__global__ __launch_bounds__(256) void k_l2(
    const ushort_t* __restrict__ xrb,   // [N,256] bf16
    const ushort_t* __restrict__ Wp2t,  // [64,64] bf16
    const float* __restrict__ hc2,      // [128,64]
    const ushort_t* __restrict__ W2t,   // [256,512] bf16
    const float* __restrict__ att_s, const float* __restrict__ att_d,
    ushort_t* __restrict__ Hout,        // [N,256] bf16
    float* __restrict__ asrc, float* __restrict__ adst){
  __shared__ __align__(16) ushort_t xs[64*256];   // 32 KB xr tile (swizzled)
  __shared__ __align__(16) ushort_t x3s[64*128];  // 16 KB x3 slab (swizzled)
  int tid = threadIdx.x;
  int w = tid >> 6, lane = tid & 63;
  int lr = lane & 15, lk = lane >> 4;
  int n0 = blockIdx.x * 64;
  int g = n0 >> 9;
  int sw = (lr & 7) << 4;
  char* Xc = (char*)xs;
  char* Sc = (char*)x3s;
  {
    const char* Ag = (const char*)(xrb + (size_t)n0*256);
    #pragma unroll
    for (int i = 0; i < 8; ++i){
      int p = i*4096 + tid*16;
      int row = p >> 9;
      int l = p ^ ((row & 7) << 4);
      gld16(Ag + (size_t)row*512 + (l & 511), Xc + p);
    }
  }
  __syncthreads();
  int c0 = w * 64;
  f32x4 acc[4][4];
  #pragma unroll
  for (int ri = 0; ri < 4; ++ri)
    #pragma unroll
    for (int ci = 0; ci < 4; ++ci) acc[ri][ci] = (f32x4){0.f,0.f,0.f,0.f};
  for (int hd = 0; hd < 4; ++hd){
    // ---- phase A: hs rows w*16..+15 for head hd (K=64) ----
    f32x4 acc2[4];
    #pragma unroll
    for (int ci = 0; ci < 4; ++ci) acc2[ci] = (f32x4){0.f,0.f,0.f,0.f};
    #pragma unroll
    for (int k0 = 0; k0 < 64; k0 += 32){
      int lg = (w*16 + lr)*512 + (hd*64 + k0 + lk*8)*2;
      bf16x8 af = *(const bf16x8*)(Xc + (lg ^ sw));
      #pragma unroll
      for (int ci = 0; ci < 4; ++ci){
        bf16x8 bfv = *(const bf16x8*)(Wp2t + (size_t)(ci*16 + lr)*64 + k0 + lk*8);
        acc2[ci] = __builtin_amdgcn_mfma_f32_16x16x32_bf16(af, bfv, acc2[ci], 0, 0, 0);
      }
    }
    #pragma unroll
    for (int ci = 0; ci < 4; ++ci){
      int col = ci*16 + lr;
      float hc = hc2[g*64 + col];
      #pragma unroll
      for (int q = 0; q < 4; ++q){
        int row = w*16 + lk*4 + q;
        int swr = (row & 7) << 4;
        float a = acc2[ci][q];
        float gg = sigmoidf_(a + hc);
        *(ushort_t*)(Sc + ((row*256 + col*2) ^ swr))        = f2b(gg*a + (1.f-gg)*hc);
        *(ushort_t*)(Sc + ((row*256 + (64 + col)*2) ^ swr)) = f2b(a);
      }
    }
    __syncthreads();
    // ---- phase B: K-slab 128 of the GAT GEMM, wave = output head ----
    #pragma unroll
    for (int k0 = 0; k0 < 128; k0 += 32){
      bf16x8 af[4], bfv[4];
      #pragma unroll
      for (int ri = 0; ri < 4; ++ri){
        int lg = (ri*16 + lr)*256 + (k0 + lk*8)*2;
        af[ri] = *(const bf16x8*)(Sc + (lg ^ sw));
      }
      #pragma unroll
      for (int ci = 0; ci < 4; ++ci)
        bfv[ci] = *(const bf16x8*)(W2t + (size_t)(c0 + ci*16 + lr)*512 + hd*128 + k0 + lk*8);
      #pragma unroll
      for (int ri = 0; ri < 4; ++ri)
        #pragma unroll
        for (int ci = 0; ci < 4; ++ci)
          acc[ri][ci] = __builtin_amdgcn_mfma_f32_16x16x32_bf16(af[ri], bfv[ci], acc[ri][ci], 0, 0, 0);
    }
    if (hd < 3) __syncthreads();
  }
  float as_[4], ad_[4];
  #pragma unroll
  for (int ci = 0; ci < 4; ++ci){
    as_[ci] = att_s[c0 + ci*16 + lr];
    ad_[ci] = att_d[c0 + ci*16 + lr];
  }
  #pragma unroll
  for (int ri = 0; ri < 4; ++ri){
    #pragma unroll
    for (int q = 0; q < 4; ++q){
      int row = n0 + ri*16 + lk*4 + q;
      float ps = 0.f, pd = 0.f;
      #pragma unroll
      for (int ci = 0; ci < 4; ++ci){
        float v = acc[ri][ci][q];
        Hout[(size_t)row*256 + c0 + ci*16 + lr] = f2b(v);
        ps = fmaf(v, as_[ci], ps);
        pd = fmaf(v, ad_[ci], pd);
      }
      #pragma unroll
      for (int m = 1; m < 16; m <<= 1){
        ps += __shfl_xor(ps, m);
        pd += __shfl_xor(pd, m);
      }
      if (lr == 0){
        asrc[(size_t)row*4 + w] = ps;
        adst[(size_t)row*4 + w] = pd;
      }
    }
  }
}

// ---------------- CSR build ----------------
__global__ void k_count(const int* __restrict__ ei, int* __restrict__ deg){
  int t = blockIdx.x*256 + threadIdx.x;
  int s = ei[t], d = ei[EE + t];
  atomicAdd(&deg[d], 1);
  atomicAdd(&deg[s], 1);
}

__global__ void k_scan1(const int* __restrict__ deg, int* __restrict__ offa,
                        int* __restrict__ bsum){
  __shared__ int sm[256];
  int tid = threadIdx.x, idx = blockIdx.x*256 + tid;
  int v = deg[idx] + 1;                 // +1 self-loop
  sm[tid] = v; __syncthreads();
  for (int o = 1; o < 256; o <<= 1){
    int t = (tid >= o) ? sm[tid-o] : 0;
    __syncthreads();
    sm[tid] += t;
    __syncthreads();
  }
  offa[idx] = sm[tid] - v;
  if (tid == 255) bsum[blockIdx.x] = sm[255];
}

__global__ void k_scan2(int* __restrict__ bsum){
  __shared__ int sm[256];
  int tid = threadIdx.x;
  int v = bsum[tid];
  sm[tid] = v; __syncthreads();
  for (int o = 1; o < 256; o <<= 1){
    int t = (tid >= o) ? sm[tid-o] : 0;
    __syncthreads();
    sm[tid] += t;
    __syncthreads();
  }
  bsum[tid] = sm[tid] - v;
}

__global__ void k_scan3(int* __restrict__ offa, const int* __restrict__ bsum){
  int idx = blockIdx.x*256 + threadIdx.x;
  offa[idx] += bsum[idx >> 8];
}

__global__ void k_fill(const int* __restrict__ ei, const int* __restrict__ offa,
                       int* __restrict__ cur, int* __restrict__ elist){
  int t = blockIdx.x*256 + threadIdx.x;
  int s = ei[t], d = ei[EE + t];
  int p = atomicAdd(&cur[d], 1); elist[offa[d] + p] = s;   // TD edge
  p = atomicAdd(&cur[s], 1);     elist[offa[s] + p] = d;   // BU (flipped) edge
  p = atomicAdd(&cur[t], 1);     elist[offa[t] + p] = t;   // self-loop (E==N)
}

// ------ GAT softmax-aggregate (h bf16); XCD-swizzled; e-values cached in LDS ------
template<int LAYER>
__global__ __launch_bounds__(256) void k_agg(const int* __restrict__ offa,
                                             const int* __restrict__ deg,
                                             const int* __restrict__ elist,
                                             const ushort_t* __restrict__ h,  // [N,256] bf16
                                             const float* __restrict__ asrc,
                                             const float* __restrict__ adst,
                                             const float* __restrict__ bias,
                                             ushort_t* __restrict__ outb,
                                             float* __restrict__ outf){
  __shared__ float eS[4][4][17][4];     // [wave][grp][edge(pad17)][head]
  __shared__ int   sS[4][4][17];
  int bid = blockIdx.x;
  int swz = (bid & 7) * (4096/8) + (bid >> 3);   // XCD-contiguous graphs
  int tid = threadIdx.x;
  int wave = tid >> 6, lane = tid & 63;
  int grp = lane >> 4, l = lane & 15;
  int n = swz*16 + wave*4 + grp;
  int o0 = offa[n], cnt = deg[n] + 1;
  float4 adv = *(const float4*)&adst[(size_t)n*4];
  float ad[4] = {adv.x, adv.y, adv.z, adv.w};
  int lim = (cnt < 16) ? cnt : 16;
  int s_l = elist[o0 + ((l < cnt) ? l : 0)];
  float4 asv = *(const float4*)&asrc[(size_t)s_l*4];
  float e_l[4];
  e_l[0] = lrelu_(asv.x + ad[0]); e_l[1] = lrelu_(asv.y + ad[1]);
  e_l[2] = lrelu_(asv.z + ad[2]); e_l[3] = lrelu_(asv.w + ad[3]);
  if (l < lim){
    sS[wave][grp][l] = s_l;
    *(float4*)&eS[wave][grp][l][0] = make_float4(e_l[0], e_l[1], e_l[2], e_l[3]);
  }
  float m[4];
  #pragma unroll
  for (int hh = 0; hh < 4; ++hh) m[hh] = (l < cnt) ? e_l[hh] : -1e30f;
  for (int i = 16 + l; i < cnt; i += 16){
    int s = elist[o0 + i];
    float4 a2 = *(const float4*)&asrc[(size_t)s*4];
    m[0] = fmaxf(m[0], lrelu_(a2.x + ad[0]));
    m[1] = fmaxf(m[1], lrelu_(a2.y + ad[1]));
    m[2] = fmaxf(m[2], lrelu_(a2.z + ad[2]));
    m[3] = fmaxf(m[3], lrelu_(a2.w + ad[3]));
  }
  #pragma unroll
  for (int mask = 1; mask < 16; mask <<= 1)
    #pragma unroll
    for (int hh = 0; hh < 4; ++hh) m[hh] = fmaxf(m[hh], __shfl_xor(m[hh], mask));
  int myh = l >> 2;
  float mm = m[myh];
  float den = 0.f;
  float accv[16] = {};
  for (int i = 0; i < lim; ++i){
    int s = sS[wave][grp][i];
    float e = eS[wave][grp][i][myh];
    float ex = __expf(e - mm);
    den += ex;
    const uint4* hp = (const uint4*)(h + (size_t)s*256 + l*16);
    uint4 h0 = hp[0], h1v = hp[1];
    uint_t uu[8] = {h0.x, h0.y, h0.z, h0.w, h1v.x, h1v.y, h1v.z, h1v.w};
    #pragma unroll
    for (int r = 0; r < 8; ++r){
      accv[2*r+0] = fmaf(ex, b2f(uu[r] & 0xffffu), accv[2*r+0]);
      accv[2*r+1] = fmaf(ex, b2f(uu[r] >> 16),     accv[2*r+1]);
    }
  }
  for (int i = 16; i < cnt; ++i){
    int s = elist[o0 + i];
    float4 a2 = *(const float4*)&asrc[(size_t)s*4];
    float e = lrelu_(((const float*)&a2)[myh] + ad[myh]);
    float ex = __expf(e - mm);
    den += ex;
    const uint4* hp = (const uint4*)(h + (size_t)s*256 + l*16);
    uint4 h0 = hp[0], h1v = hp[1];
    uint_t uu[8] = {h0.x, h0.y, h0.z, h0.w, h1v.x, h1v.y, h1v.z, h1v.w};
    #pragma unroll
    for (int r = 0; r < 8; ++r){
      accv[2*r+0] = fmaf(ex, b2f(uu[r] & 0xffffu), accv[2*r+0]);
      accv[2*r+1] = fmaf(ex, b2f(uu[r] >> 16),     accv[2*r+1]);
    }
  }
  float inv = 1.0f / den;
  if (LAYER == 1){
    #pragma unroll
    for (int r = 0; r < 4; ++r){
      int c = l*16 + r*4;
      float4 bv = *(const float4*)&bias[c];
      float o0v = fmaxf(accv[r*4+0]*inv + bv.x, 0.f);
      float o1v = fmaxf(accv[r*4+1]*inv + bv.y, 0.f);
      float o2v = fmaxf(accv[r*4+2]*inv + bv.z, 0.f);
      float o3v = fmaxf(accv[r*4+3]*inv + bv.w, 0.f);
      uint2 pk;
      pk.x = (uint_t)f2b(o0v) | ((uint_t)f2b(o1v) << 16);
      pk.y = (uint_t)f2b(o2v) | ((uint_t)f2b(o3v) << 16);
      *(uint2*)&outb[(size_t)n*256 + c] = pk;
    }
  } else {
    #pragma unroll
    for (int r = 0; r < 16; ++r) accv[r] *= inv;
    #pragma unroll
    for (int r = 0; r < 16; ++r){
      accv[r] += __shfl_xor(accv[r], 4);
      accv[r] += __shfl_xor(accv[r], 8);
    }
    if (l < 4){
      #pragma unroll
      for (int r = 0; r < 4; ++r){
        int c = l*16 + r*4;
        float4 bv = *(const float4*)&bias[c];
        float4 o;
        o.x = fmaxf(accv[r*4+0]*0.25f + bv.x, 0.f);
        o.y = fmaxf(accv[r*4+1]*0.25f + bv.y, 0.f);
        o.z = fmaxf(accv[r*4+2]*0.25f + bv.z, 0.f);
        o.w = fmaxf(accv[r*4+3]*0.25f + bv.w, 0.f);
        *(float4*)&outf[(size_t)n*64 + c] = o;
      }
    }
  }
}

// ---- pool via MFMA (k_base fused): block = 64 nodes x 64 outputs, K=192 ----
__global__ __launch_bounds__(256) void k_pool_mfma(
    const float* __restrict__ xr2,      // [N,64] f32
    const ushort_t* __restrict__ Wfct,  // [64,192] bf16 (W_fc[64:256]^T)
    const float* __restrict__ Wfc,      // [256,64] f32 (rows 0..63 used)
    const float* __restrict__ bfc,
    float* __restrict__ shat,
    float* __restrict__ ssum){
  __shared__ __align__(16) float xs[64][68];
  __shared__ float rls[64];
  __shared__ float bs[64];
  __shared__ float ls_sh[64];
  __shared__ float ls_s[64];
  int tid = threadIdx.x;
  int n0 = blockIdx.x * 64;
  int g = n0 >> 9;
  {
    int row = tid >> 4, col4 = (tid & 15) * 4;
    #pragma unroll
    for (int i = 0; i < 4; ++i){
      float4 v = *(const float4*)&xr2[(size_t)(n0 + row + i*16)*64 + col4];
      *(float4*)&xs[row + i*16][col4] = v;
    }
    if (tid < 16){
      float4 v = *(const float4*)&xr2[(size_t)((size_t)g*GGR)*64 + tid*4];
      *(float4*)&rls[tid*4] = v;
    }
    if (tid >= 128 && tid < 192){ ls_sh[tid-128] = 0.f; ls_s[tid-128] = 0.f; }
  }
  __syncthreads();
  if (tid < 64){
    float b = bfc[tid];
    for (int j = 0; j < 64; ++j) b = fmaf(rls[j], Wfc[j*64 + tid], b);
    bs[tid] = b;
  }
  __syncthreads();
  int w = tid >> 6, lane = tid & 63;
  int lr = lane & 15, lk = lane >> 4;
  f32x4 acc[4];
  #pragma unroll
  for (int ci = 0; ci < 4; ++ci) acc[ci] = (f32x4){0.f,0.f,0.f,0.f};
  int arow = w*16 + lr;
  #pragma unroll
  for (int k0 = 0; k0 < 192; k0 += 32){
    int seg = k0 >> 6;
    int cb = (k0 & 63) + lk*8;
    bf16x8 af;
    #pragma unroll
    for (int j = 0; j < 8; ++j){
      float xv = xs[arow][cb + j];
      float rv = rls[cb + j];
      float v = (seg == 0) ? xv : (seg == 1 ? xv*rv : fabsf(rv - xv));
      af[j] = (short)f2b(v);
    }
    #pragma unroll
    for (int ci = 0; ci < 4; ++ci){
      bf16x8 bfv = *(const bf16x8*)(Wfct + (size_t)(ci*16+lr)*192 + k0 + lk*8);
      acc[ci] = __builtin_amdgcn_mfma_f32_16x16x32_bf16(af, bfv, acc[ci], 0, 0, 0);
    }
  }
  float bsv[4];
  #pragma unroll
  for (int ci = 0; ci < 4; ++ci) bsv[ci] = bs[ci*16 + lr];
  float c_sh[4] = {0.f,0.f,0.f,0.f}, c_s[4] = {0.f,0.f,0.f,0.f};
  #pragma unroll
  for (int q = 0; q < 4; ++q){
    int rrow = w*16 + lk*4 + q;
    float t[4];
    float mx = -1e30f;
    #pragma unroll
    for (int ci = 0; ci < 4; ++ci){
      t[ci] = tanhf_(acc[ci][q] + bsv[ci]);
      mx = fmaxf(mx, t[ci]);
    }
    #pragma unroll
    for (int mask = 1; mask < 16; mask <<= 1) mx = fmaxf(mx, __shfl_xor(mx, mask));
    float e[4], s = 0.f;
    #pragma unroll
    for (int ci = 0; ci < 4; ++ci){ e[ci] = __expf(t[ci] - mx); s += e[ci]; }
    #pragma unroll
    for (int mask = 1; mask < 16; mask <<= 1) s += __shfl_xor(s, mask);
    float invs = 1.0f / s;
    #pragma unroll
    for (int ci = 0; ci < 4; ++ci){
      float xv = xs[rrow][ci*16 + lr];
      c_sh[ci] = fmaf(e[ci]*invs, xv, c_sh[ci]);
      c_s[ci] += xv;
    }
  }
  #pragma unroll
  for (int ci = 0; ci < 4; ++ci){
    c_sh[ci] += __shfl_xor(c_sh[ci], 16); c_sh[ci] += __shfl_xor(c_sh[ci], 32);
    c_s[ci]  += __shfl_xor(c_s[ci], 16);  c_s[ci]  += __shfl_xor(c_s[ci], 32);
  }
  if (lk == 0){
    #pragma unroll
    for (int ci = 0; ci < 4; ++ci){
      atomicAdd(&ls_sh[ci*16 + lr], c_sh[ci]);
      atomicAdd(&ls_s[ci*16 + lr], c_s[ci]);
    }
  }
  __syncthreads();
  if (tid < 64){
    atomicAdd(&shat[g*64 + tid], ls_sh[tid]);
    atomicAdd(&ssum[g*64 + tid], ls_s[tid]);
  }
}

// ------------- final logits + log_softmax -------------
__global__ void k_final(const float* __restrict__ shat, const float* __restrict__ ssum,
                        const float* __restrict__ Wc, const float* __restrict__ bc,
                        float* __restrict__ outp){
  int g = threadIdx.x;   // 128 graphs
  float l0 = bc[0], l1 = bc[1], l2 = bc[2], l3 = bc[3];
  const float s512 = 1.0f/512.0f;
  for (int j = 0; j < 64; ++j){
    float sh = shat[g*64 + j]*s512;
    float ss = ssum[g*64 + j]*s512;
    float4 w1 = *(const float4*)&Wc[j*4];
    float4 w2 = *(const float4*)&Wc[(64+j)*4];
    l0 = fmaf(sh, w1.x, fmaf(ss, w2.x, l0));
    l1 = fmaf(sh, w1.y, fmaf(ss, w2.y, l1));
    l2 = fmaf(sh, w1.z, fmaf(ss, w2.z, l2));
    l3 = fmaf(sh, w1.w, fmaf(ss, w2.w, l3));
  }
  float mx = fmaxf(fmaxf(l0,l1), fmaxf(l2,l3));
  float s = __expf(l0-mx)+__expf(l1-mx)+__expf(l2-mx)+__expf(l3-mx);
  float lse = mx + logf(s);
  outp[g*4+0] = l0 - lse;
  outp[g*4+1] = l1 - lse;
  outp[g*4+2] = l2 - lse;
  outp[g*4+3] = l3 - lse;
}

extern "C" void kernel_launch(void* const* d_in, const int* in_sizes, int n_in,
                              void* d_out, int out_size, void* d_ws, size_t ws_size,
                              hipStream_t stream){
  const float* x        = (const float*)d_in[0];
  const float* root     = (const float*)d_in[1];
  const int*   ei       = (const int*)d_in[2];
  const float* W_post1  = (const float*)d_in[5];
  const float* W_claim1 = (const float*)d_in[6];
  const float* W1       = (const float*)d_in[7];
  const float* att_src1 = (const float*)d_in[8];
  const float* att_dst1 = (const float*)d_in[9];
  const float* b1       = (const float*)d_in[10];
  const float* W_post2  = (const float*)d_in[11];
  const float* W_claim2 = (const float*)d_in[12];
  const float* W2       = (const float*)d_in[13];
  const float* att_src2 = (const float*)d_in[14];
  const float* att_dst2 = (const float*)d_in[15];
  const float* b2       = (const float*)d_in[16];
  const float* W_fc     = (const float*)d_in[17];
  const float* b_fc     = (const float*)d_in[18];
  const float* W_clf    = (const float*)d_in[19];
  const float* b_clf    = (const float*)d_in[20];
  float* out = (float*)d_out;

  char* w = (char*)d_ws;
  size_t o = 0;
  auto alloc = [&](size_t bytes)->char*{ char* p = w + o; o += (bytes + 255) & ~(size_t)255; return p; };
  ushort_t* RB   = (ushort_t*)alloc((size_t)NN*256*2);   // h2b then h3b
  ushort_t* xrb  = (ushort_t*)alloc((size_t)NN*256*2);
  float* xr2  = (float*)alloc((size_t)NN*64*4);
  float* asrc = (float*)alloc((size_t)NN*4*4);
  float* adst = (float*)alloc((size_t)NN*4*4);
  float* hc1  = (float*)alloc(128*64*4);
  float* hc2  = (float*)alloc(128*64*4);
  ushort_t* W1t  = (ushort_t*)alloc((size_t)256*128*2);
  ushort_t* W2t  = (ushort_t*)alloc((size_t)256*512*2);
  ushort_t* Wp1t = (ushort_t*)alloc((size_t)64*512*2);
  ushort_t* Wp2t = (ushort_t*)alloc((size_t)64*64*2);
  ushort_t* Wfct = (ushort_t*)alloc((size_t)64*192*2);
  int*   deg  = (int*)alloc((size_t)NN*4);
  int*   cur  = (int*)alloc((size_t)NN*4);      // adjacent to deg: one memset
  int*   offa = (int*)alloc((size_t)NN*4);
  int*   bsum = (int*)alloc(256*4);
  int*   elist= (int*)alloc((size_t)(2*EE+NN)*4);
  float* shat = (float*)alloc(128*64*4);
  float* ssumv= (float*)alloc(128*64*4);        // adjacent to shat: one memset

  ushort_t* h2b = RB;    // [N,256] bf16
  ushort_t* h3b = RB;    // [N,256] bf16 (h2b dead by then)

  hipMemsetAsync(deg,  0, (size_t)NN*8, stream);     // deg + cur
  hipMemsetAsync(shat, 0, 2*128*64*4, stream);       // shat + ssumv

  k_prep<<<960, 256, 0, stream>>>(W1, W2, W_post1, W_post2, W_fc,
                                  W1t, W2t, Wp1t, Wp2t, Wfct,
                                  root, W_claim1, W_claim2, hc1, hc2);
  k_count<<<256, 256, 0, stream>>>(ei, deg);
  k_scan1<<<256, 256, 0, stream>>>(deg, offa, bsum);
  k_scan2<<<1, 256, 0, stream>>>(bsum);
  k_scan3<<<256, 256, 0, stream>>>(offa, bsum);
  k_fill<<<256, 256, 0, stream>>>(ei, offa, cur, elist);
  k_l1<<<1024, 256, 0, stream>>>(x, Wp1t, hc1, W1t, att_src1, att_dst1, h2b, asrc, adst);
  k_agg<1><<<4096, 256, 0, stream>>>(offa, deg, elist, h2b, asrc, adst, b1, xrb, nullptr);
  k_l2<<<1024, 256, 0, stream>>>(xrb, Wp2t, hc2, W2t, att_src2, att_dst2, h3b, asrc, adst);
  k_agg<2><<<4096, 256, 0, stream>>>(offa, deg, elist, h3b, asrc, adst, b2, nullptr, xr2);
  k_pool_mfma<<<1024, 256, 0, stream>>>(xr2, Wfct, W_fc, b_fc, shat, ssumv);
  k_final<<<1, 128, 0, stream>>>(shat, ssumv, W_clf, b_clf, out);
  (void)in_sizes; (void)n_in; (void)out_size; (void)ws_size;
}

// Round 7
// 261.237 us; speedup vs baseline: 2.9460x; 1.0097x over previous
//
#include <hip/hip_runtime.h>
#include <math.h>

#define NN   65536
#define BB   128
#define GGR  512
#define EE   65536
#define INF_ 512
#define HIDD 64

typedef __attribute__((ext_vector_type(8))) short bf16x8;
typedef __attribute__((ext_vector_type(4))) float f32x4;
typedef unsigned short ushort_t;
typedef unsigned int uint_t;

static __device__ __forceinline__ float sigmoidf_(float x){ return 1.0f/(1.0f+__expf(-x)); }
static __device__ __forceinline__ float lrelu_(float x){ return x>=0.0f ? x : 0.2f*x; }
static __device__ __forceinline__ float tanhf_(float x){
  float e = __expf(2.f*x);
  return 1.f - 2.f/(e + 1.f);
}

// f32 -> bf16 bits, round-to-nearest-even
static __device__ __forceinline__ ushort_t f2b(float f){
  union { float f; uint_t u; } v; v.f = f;
  uint_t u = v.u;
  uint_t r = (u + 0x7fffu + ((u >> 16) & 1u)) >> 16;
  return (ushort_t)r;
}
// bf16 bits -> f32 (exact)
static __device__ __forceinline__ float b2f(uint_t u16){
  union { uint_t u; float f; } v; v.u = u16 << 16; return v.f;
}

// async global->LDS, 16 bytes per lane
static __device__ __forceinline__ void gld16(const void* g, void* l){
  __builtin_amdgcn_global_load_lds((const __attribute__((address_space(1))) void*)g,
                                   (__attribute__((address_space(3))) void*)l, 16, 0, 0);
}

// ---- fused prep: weight transpose+casts, plus hc1/hc2 (blocks >= 832) ----
__global__ void k_prep(const float* __restrict__ W1, const float* __restrict__ W2,
                       const float* __restrict__ Wp1, const float* __restrict__ Wp2,
                       const float* __restrict__ Wfc,
                       ushort_t* __restrict__ W1t, ushort_t* __restrict__ W2t,
                       ushort_t* __restrict__ Wp1t, ushort_t* __restrict__ Wp2t,
                       ushort_t* __restrict__ Wfct,
                       const float* __restrict__ root, const float* __restrict__ Wc1,
                       const float* __restrict__ Wc2, float* __restrict__ hc1,
                       float* __restrict__ hc2){
  if (blockIdx.x >= 832){
    int b = blockIdx.x - 832;
    int f = threadIdx.x;
    if (f < 64){
      const float* r = root + (size_t)b*INF_;
      float a1 = 0.f, a2 = 0.f;
      for (int k = 0; k < INF_; ++k){
        float rv = r[k];
        a1 = fmaf(rv, Wc1[k*HIDD+f], a1);
        a2 = fmaf(rv, Wc2[k*HIDD+f], a2);
      }
      hc1[b*HIDD+f] = a1; hc2[b*HIDD+f] = a2;
    }
    return;
  }
  int idx = blockIdx.x*256 + threadIdx.x;
  if (idx < 32768){                     // W1 [128,256]
    int k = idx >> 8, c = idx & 255;
    W1t[(size_t)c*128 + k] = f2b(W1[idx]);
  } else if (idx < 163840){             // W2 [512,256]
    int j = idx - 32768; int k = j >> 8, c = j & 255;
    W2t[(size_t)c*512 + k] = f2b(W2[j]);
  } else if (idx < 196608){             // W_post1 [512,64]
    int j = idx - 163840; int k = j >> 6, c = j & 63;
    Wp1t[(size_t)c*512 + k] = f2b(Wp1[j]);
  } else if (idx < 200704){             // W_post2 [64,64]
    int j = idx - 196608; int k = j >> 6, c = j & 63;
    Wp2t[(size_t)c*64 + k] = f2b(Wp2[j]);
  } else if (idx < 212992){             // W_fc rows 64..255 [192,64]
    int j = idx - 200704; int k = j >> 6, c = j & 63;
    Wfct[(size_t)c*192 + k] = f2b(Wfc[4096 + j]);
  }
}

// ==== fused layer 1 (pipelined): h1 = gated(x@W_post1, hc1) [LDS] -> H = h1@W1 + att logits ====
// LDS: 2 x 16 KB ping-pong stage buffers (BK=64 f32); h1 tile aliases buf0. Total 32 KB.
__global__ __launch_bounds__(256) void k_l1(
    const float* __restrict__ x,        // [N,512] f32
    const ushort_t* __restrict__ Wp1t,  // [64,512] bf16
    const float* __restrict__ hc1,      // [128,64]
    const ushort_t* __restrict__ W1t,   // [256,128] bf16
    const float* __restrict__ att_s, const float* __restrict__ att_d,
    ushort_t* __restrict__ Hout,        // [N,256] bf16
    float* __restrict__ asrc, float* __restrict__ adst){
  __shared__ __align__(16) char Lds[32768];
  int tid = threadIdx.x;
  int w = tid >> 6, lane = tid & 63;
  int lr = lane & 15, lk = lane >> 4;
  int n0 = blockIdx.x * 64;
  int g = n0 >> 9;
  int sw = (lr & 7) << 4;
  const char* xg = (const char*)(x + (size_t)n0*512);
  char* buf0 = Lds;
  char* buf1 = Lds + 16384;
  // stage: 64 rows x 64 f32 (256 B/row), XOR-swizzled source, linear dest
  auto STAGE = [&](char* dst, int s){
    #pragma unroll
    for (int i = 0; i < 4; ++i){
      int p = i*4096 + tid*16;
      int row = p >> 8;
      int l = p ^ ((row & 7) << 4);
      gld16(xg + (size_t)row*2048 + s*256 + (l & 255), dst + p);
    }
  };
  // ---------- phase A: pipelined K=512 in 8 stages of 64 ----------
  f32x4 accA[4];
  #pragma unroll
  for (int ci = 0; ci < 4; ++ci) accA[ci] = (f32x4){0.f,0.f,0.f,0.f};
  const ushort_t* BbA = Wp1t + (size_t)lr*512 + lk*8;
  int rl = w*16 + lr;
  STAGE(buf0, 0);
  #pragma unroll
  for (int s = 0; s < 8; ++s){
    char* cur = (s & 1) ? buf1 : buf0;
    if (s < 7){
      char* nxt = (s & 1) ? buf0 : buf1;
      STAGE(nxt, s + 1);
      asm volatile("s_waitcnt vmcnt(4)" ::: "memory");
    } else {
      asm volatile("s_waitcnt vmcnt(0)" ::: "memory");
    }
    __builtin_amdgcn_s_barrier();
    asm volatile("" ::: "memory");
    #pragma unroll
    for (int k0 = 0; k0 < 64; k0 += 32){
      int lg = rl*256 + (k0 + lk*8)*4;
      float4 fa = *(const float4*)(cur + (lg ^ sw));
      float4 fb = *(const float4*)(cur + ((lg + 16) ^ sw));
      bf16x8 af;
      af[0]=(short)f2b(fa.x); af[1]=(short)f2b(fa.y); af[2]=(short)f2b(fa.z); af[3]=(short)f2b(fa.w);
      af[4]=(short)f2b(fb.x); af[5]=(short)f2b(fb.y); af[6]=(short)f2b(fb.z); af[7]=(short)f2b(fb.w);
      #pragma unroll
      for (int ci = 0; ci < 4; ++ci){
        bf16x8 bfv = *(const bf16x8*)(BbA + (size_t)ci*16*512 + s*64 + k0);
        accA[ci] = __builtin_amdgcn_mfma_f32_16x16x32_bf16(af, bfv, accA[ci], 0, 0, 0);
      }
    }
    asm volatile("" ::: "memory");
    __builtin_amdgcn_s_barrier();
  }
  // gate + write h1 tile into buf0 (dead; XOR-swizzled rows, 256 B/row)
  char* Hc = buf0;
  #pragma unroll
  for (int ci = 0; ci < 4; ++ci){
    int col = ci*16 + lr;
    float hc = hc1[g*64 + col];
    #pragma unroll
    for (int q = 0; q < 4; ++q){
      int row = w*16 + lk*4 + q;
      int swr = (row & 7) << 4;
      float hx = accA[ci][q];
      float gg = sigmoidf_(hx + hc);
      float fo = gg*hx + (1.f-gg)*hc;
      *(ushort_t*)(Hc + ((row*256 + col*2) ^ swr))        = f2b(fo);
      *(ushort_t*)(Hc + ((row*256 + (64 + col)*2) ^ swr)) = f2b(hx);
    }
  }
  __syncthreads();
  // ---------- phase B: H = h1 @ W1 (K=128), wave = output head ----------
  int c0 = w * 64;
  f32x4 acc[4][4];
  #pragma unroll
  for (int ri = 0; ri < 4; ++ri)
    #pragma unroll
    for (int ci = 0; ci < 4; ++ci) acc[ri][ci] = (f32x4){0.f,0.f,0.f,0.f};
  #pragma unroll
  for (int k0 = 0; k0 < 128; k0 += 32){
    bf16x8 af[4], bfv[4];
    #pragma unroll
    for (int ri = 0; ri < 4; ++ri){
      int lg = (ri*16 + lr)*256 + (k0 + lk*8)*2;
      af[ri] = *(const bf16x8*)(Hc + (lg ^ sw));
    }
    #pragma unroll
    for (int ci = 0; ci < 4; ++ci)
      bfv[ci] = *(const bf16x8*)(W1t + (size_t)(c0 + ci*16 + lr)*128 + k0 + lk*8);
    #pragma unroll
    for (int ri = 0; ri < 4; ++ri)
      #pragma unroll
      for (int ci = 0; ci < 4; ++ci)
        acc[ri][ci] = __builtin_amdgcn_mfma_f32_16x16x32_bf16(af[ri], bfv[ci], acc[ri][ci], 0, 0, 0);
  }
  float as_[4], ad_[4];
  #pragma unroll
  for (int ci = 0; ci < 4; ++ci){
    as_[ci] = att_s[c0 + ci*16 + lr];
    ad_[ci] = att_d[c0 + ci*16 + lr];
  }
  #pragma unroll
  for (int ri = 0; ri < 4; ++ri){
    #pragma unroll
    for (int q = 0; q < 4; ++q){
      int row = n0 + ri*16 + lk*4 + q;
      float ps = 0.f, pd = 0.f;
      #pragma unroll
      for (int ci = 0; ci < 4; ++ci){
        float v = acc[ri][ci][q];
        Hout[(size_t)row*256 + c0 + ci*16 + lr] = f2b(v);
        ps = fmaf(v, as_[ci], ps);
        pd = fmaf(v, ad_[ci], pd);
      }
      #pragma unroll
      for (int m = 1; m < 16; m <<= 1){
        ps += __shfl_xor(ps, m);
        pd += __shfl_xor(pd, m);
      }
      if (lr == 0){
        asrc[(size_t)row*4 + w] = ps;
        adst[(size_t)row*4 + w] = pd;
      }
    }
  }
}

// ==== fused layer 2: x3 slab (per head) in LDS -> H = x3@W2 + att logits ====
__global__ __launch_bounds__(256) void k_l2(
    const ushort_t* __restrict__ xrb,   // [N,256] bf16
    const ushort_t* __restrict__ Wp2t,  // [64,64] bf16
    const float* __restrict__ hc2,      // [128,64]
    const ushort_t* __restrict__ W2t,   // [256,512] bf16
    const float* __restrict__ att_s, const float* __restrict__ att_d,
    ushort_t* __restrict__ Hout,        // [N,256] bf16
    float* __restrict__ asrc, float* __restrict__ adst){
  __shared__ __align__(16) ushort_t xs[64*256];   // 32 KB xr tile (swizzled)
  __shared__ __align__(16) ushort_t x3s[64*128];  // 16 KB x3 slab (swizzled)
  int tid = threadIdx.x;
  int w = tid >> 6, lane = tid & 63;
  int lr = lane & 15, lk = lane >> 4;
  int n0 = blockIdx.x * 64;
  int g = n0 >> 9;
  int sw = (lr & 7) << 4;
  char* Xc = (char*)xs;
  char* Sc = (char*)x3s;
  {
    const char* Ag = (const char*)(xrb + (size_t)n0*256);
    #pragma unroll
    for (int i = 0; i < 8; ++i){
      int p = i*4096 + tid*16;
      int row = p >> 9;
      int l = p ^ ((row & 7) << 4);
      gld16(Ag + (size_t)row*512 + (l & 511), Xc + p);
    }
  }
  __syncthreads();
  int c0 = w * 64;
  f32x4 acc[4][4];
  #pragma unroll
  for (int ri = 0; ri < 4; ++ri)
    #pragma unroll
    for (int ci = 0; ci < 4; ++ci) acc[ri][ci] = (f32x4){0.f,0.f,0.f,0.f};
  for (int hd = 0; hd < 4; ++hd){
    // ---- phase A: hs rows w*16..+15 for head hd (K=64) ----
    f32x4 acc2[4];
    #pragma unroll
    for (int ci = 0; ci < 4; ++ci) acc2[ci] = (f32x4){0.f,0.f,0.f,0.f};
    #pragma unroll
    for (int k0 = 0; k0 < 64; k0 += 32){
      int lg = (w*16 + lr)*512 + (hd*64 + k0 + lk*8)*2;
      bf16x8 af = *(const bf16x8*)(Xc + (lg ^ sw));
      #pragma unroll
      for (int ci = 0; ci < 4; ++ci){
        bf16x8 bfv = *(const bf16x8*)(Wp2t + (size_t)(ci*16 + lr)*64 + k0 + lk*8);
        acc2[ci] = __builtin_amdgcn_mfma_f32_16x16x32_bf16(af, bfv, acc2[ci], 0, 0, 0);
      }
    }
    #pragma unroll
    for (int ci = 0; ci < 4; ++ci){
      int col = ci*16 + lr;
      float hc = hc2[g*64 + col];
      #pragma unroll
      for (int q = 0; q < 4; ++q){
        int row = w*16 + lk*4 + q;
        int swr = (row & 7) << 4;
        float a = acc2[ci][q];
        float gg = sigmoidf_(a + hc);
        *(ushort_t*)(Sc + ((row*256 + col*2) ^ swr))        = f2b(gg*a + (1.f-gg)*hc);
        *(ushort_t*)(Sc + ((row*256 + (64 + col)*2) ^ swr)) = f2b(a);
      }
    }
    __syncthreads();
    // ---- phase B: K-slab 128 of the GAT GEMM, wave = output head ----
    #pragma unroll
    for (int k0 = 0; k0 < 128; k0 += 32){
      bf16x8 af[4], bfv[4];
      #pragma unroll
      for (int ri = 0; ri < 4; ++ri){
        int lg = (ri*16 + lr)*256 + (k0 + lk*8)*2;
        af[ri] = *(const bf16x8*)(Sc + (lg ^ sw));
      }
      #pragma unroll
      for (int ci = 0; ci < 4; ++ci)
        bfv[ci] = *(const bf16x8*)(W2t + (size_t)(c0 + ci*16 + lr)*512 + hd*128 + k0 + lk*8);
      #pragma unroll
      for (int ri = 0; ri < 4; ++ri)
        #pragma unroll
        for (int ci = 0; ci < 4; ++ci)
          acc[ri][ci] = __builtin_amdgcn_mfma_f32_16x16x32_bf16(af[ri], bfv[ci], acc[ri][ci], 0, 0, 0);
    }
    if (hd < 3) __syncthreads();
  }
  float as_[4], ad_[4];
  #pragma unroll
  for (int ci = 0; ci < 4; ++ci){
    as_[ci] = att_s[c0 + ci*16 + lr];
    ad_[ci] = att_d[c0 + ci*16 + lr];
  }
  #pragma unroll
  for (int ri = 0; ri < 4; ++ri){
    #pragma unroll
    for (int q = 0; q < 4; ++q){
      int row = n0 + ri*16 + lk*4 + q;
      float ps = 0.f, pd = 0.f;
      #pragma unroll
      for (int ci = 0; ci < 4; ++ci){
        float v = acc[ri][ci][q];
        Hout[(size_t)row*256 + c0 + ci*16 + lr] = f2b(v);
        ps = fmaf(v, as_[ci], ps);
        pd = fmaf(v, ad_[ci], pd);
      }
      #pragma unroll
      for (int m = 1; m < 16; m <<= 1){
        ps += __shfl_xor(ps, m);
        pd += __shfl_xor(pd, m);
      }
      if (lr == 0){
        asrc[(size_t)row*4 + w] = ps;
        adst[(size_t)row*4 + w] = pd;
      }
    }
  }
}

// ---------------- CSR build ----------------
__global__ void k_count(const int* __restrict__ ei, int* __restrict__ deg){
  int t = blockIdx.x*256 + threadIdx.x;
  int s = ei[t], d = ei[EE + t];
  atomicAdd(&deg[d], 1);
  atomicAdd(&deg[s], 1);
}

__global__ void k_scan1(const int* __restrict__ deg, int* __restrict__ offa,
                        int* __restrict__ bsum){
  __shared__ int sm[256];
  int tid = threadIdx.x, idx = blockIdx.x*256 + tid;
  int v = deg[idx] + 1;                 // +1 self-loop
  sm[tid] = v; __syncthreads();
  for (int o = 1; o < 256; o <<= 1){
    int t = (tid >= o) ? sm[tid-o] : 0;
    __syncthreads();
    sm[tid] += t;
    __syncthreads();
  }
  offa[idx] = sm[tid] - v;
  if (tid == 255) bsum[blockIdx.x] = sm[255];
}

__global__ void k_scan2(int* __restrict__ bsum){
  __shared__ int sm[256];
  int tid = threadIdx.x;
  int v = bsum[tid];
  sm[tid] = v; __syncthreads();
  for (int o = 1; o < 256; o <<= 1){
    int t = (tid >= o) ? sm[tid-o] : 0;
    __syncthreads();
    sm[tid] += t;
    __syncthreads();
  }
  bsum[tid] = sm[tid] - v;
}

__global__ void k_scan3(int* __restrict__ offa, const int* __restrict__ bsum){
  int idx = blockIdx.x*256 + threadIdx.x;
  offa[idx] += bsum[idx >> 8];
}

__global__ void k_fill(const int* __restrict__ ei, const int* __restrict__ offa,
                       int* __restrict__ cur, int* __restrict__ elist){
  int t = blockIdx.x*256 + threadIdx.x;
  int s = ei[t], d = ei[EE + t];
  int p = atomicAdd(&cur[d], 1); elist[offa[d] + p] = s;   // TD edge
  p = atomicAdd(&cur[s], 1);     elist[offa[s] + p] = d;   // BU (flipped) edge
  p = atomicAdd(&cur[t], 1);     elist[offa[t] + p] = t;   // self-loop (E==N)
}

// ------ GAT softmax-aggregate (h bf16); XCD-swizzled; e-values cached in LDS ------
template<int LAYER>
__global__ __launch_bounds__(256) void k_agg(const int* __restrict__ offa,
                                             const int* __restrict__ deg,
                                             const int* __restrict__ elist,
                                             const ushort_t* __restrict__ h,  // [N,256] bf16
                                             const float* __restrict__ asrc,
                                             const float* __restrict__ adst,
                                             const float* __restrict__ bias,
                                             ushort_t* __restrict__ outb,
                                             float* __restrict__ outf){
  __shared__ float eS[4][4][17][4];     // [wave][grp][edge(pad17)][head]
  __shared__ int   sS[4][4][17];
  int bid = blockIdx.x;
  int swz = (bid & 7) * (4096/8) + (bid >> 3);   // XCD-contiguous graphs
  int tid = threadIdx.x;
  int wave = tid >> 6, lane = tid & 63;
  int grp = lane >> 4, l = lane & 15;
  int n = swz*16 + wave*4 + grp;
  int o0 = offa[n], cnt = deg[n] + 1;
  float4 adv = *(const float4*)&adst[(size_t)n*4];
  float ad[4] = {adv.x, adv.y, adv.z, adv.w};
  int lim = (cnt < 16) ? cnt : 16;
  int s_l = elist[o0 + ((l < cnt) ? l : 0)];
  float4 asv = *(const float4*)&asrc[(size_t)s_l*4];
  float e_l[4];
  e_l[0] = lrelu_(asv.x + ad[0]); e_l[1] = lrelu_(asv.y + ad[1]);
  e_l[2] = lrelu_(asv.z + ad[2]); e_l[3] = lrelu_(asv.w + ad[3]);
  if (l < lim){
    sS[wave][grp][l] = s_l;
    *(float4*)&eS[wave][grp][l][0] = make_float4(e_l[0], e_l[1], e_l[2], e_l[3]);
  }
  float m[4];
  #pragma unroll
  for (int hh = 0; hh < 4; ++hh) m[hh] = (l < cnt) ? e_l[hh] : -1e30f;
  for (int i = 16 + l; i < cnt; i += 16){
    int s = elist[o0 + i];
    float4 a2 = *(const float4*)&asrc[(size_t)s*4];
    m[0] = fmaxf(m[0], lrelu_(a2.x + ad[0]));
    m[1] = fmaxf(m[1], lrelu_(a2.y + ad[1]));
    m[2] = fmaxf(m[2], lrelu_(a2.z + ad[2]));
    m[3] = fmaxf(m[3], lrelu_(a2.w + ad[3]));
  }
  #pragma unroll
  for (int mask = 1; mask < 16; mask <<= 1)
    #pragma unroll
    for (int hh = 0; hh < 4; ++hh) m[hh] = fmaxf(m[hh], __shfl_xor(m[hh], mask));
  int myh = l >> 2;
  float mm = m[myh];
  float den = 0.f;
  float accv[16] = {};
  for (int i = 0; i < lim; ++i){
    int s = sS[wave][grp][i];
    float e = eS[wave][grp][i][myh];
    float ex = __expf(e - mm);
    den += ex;
    const uint4* hp = (const uint4*)(h + (size_t)s*256 + l*16);
    uint4 h0 = hp[0], h1v = hp[1];
    uint_t uu[8] = {h0.x, h0.y, h0.z, h0.w, h1v.x, h1v.y, h1v.z, h1v.w};
    #pragma unroll
    for (int r = 0; r < 8; ++r){
      accv[2*r+0] = fmaf(ex, b2f(uu[r] & 0xffffu), accv[2*r+0]);
      accv[2*r+1] = fmaf(ex, b2f(uu[r] >> 16),     accv[2*r+1]);
    }
  }
  for (int i = 16; i < cnt; ++i){
    int s = elist[o0 + i];
    float4 a2 = *(const float4*)&asrc[(size_t)s*4];
    float e = lrelu_(((const float*)&a2)[myh] + ad[myh]);
    float ex = __expf(e - mm);
    den += ex;
    const uint4* hp = (const uint4*)(h + (size_t)s*256 + l*16);
    uint4 h0 = hp[0], h1v = hp[1];
    uint_t uu[8] = {h0.x, h0.y, h0.z, h0.w, h1v.x, h1v.y, h1v.z, h1v.w};
    #pragma unroll
    for (int r = 0; r < 8; ++r){
      accv[2*r+0] = fmaf(ex, b2f(uu[r] & 0xffffu), accv[2*r+0]);
      accv[2*r+1] = fmaf(ex, b2f(uu[r] >> 16),     accv[2*r+1]);
    }
  }
  float inv = 1.0f / den;
  if (LAYER == 1){
    #pragma unroll
    for (int r = 0; r < 4; ++r){
      int c = l*16 + r*4;
      float4 bv = *(const float4*)&bias[c];
      float o0v = fmaxf(accv[r*4+0]*inv + bv.x, 0.f);
      float o1v = fmaxf(accv[r*4+1]*inv + bv.y, 0.f);
      float o2v = fmaxf(accv[r*4+2]*inv + bv.z, 0.f);
      float o3v = fmaxf(accv[r*4+3]*inv + bv.w, 0.f);
      uint2 pk;
      pk.x = (uint_t)f2b(o0v) | ((uint_t)f2b(o1v) << 16);
      pk.y = (uint_t)f2b(o2v) | ((uint_t)f2b(o3v) << 16);
      *(uint2*)&outb[(size_t)n*256 + c] = pk;
    }
  } else {
    #pragma unroll
    for (int r = 0; r < 16; ++r) accv[r] *= inv;
    #pragma unroll
    for (int r = 0; r < 16; ++r){
      accv[r] += __shfl_xor(accv[r], 4);
      accv[r] += __shfl_xor(accv[r], 8);
    }
    if (l < 4){
      #pragma unroll
      for (int r = 0; r < 4; ++r){
        int c = l*16 + r*4;
        float4 bv = *(const float4*)&bias[c];
        float4 o;
        o.x = fmaxf(accv[r*4+0]*0.25f + bv.x, 0.f);
        o.y = fmaxf(accv[r*4+1]*0.25f + bv.y, 0.f);
        o.z = fmaxf(accv[r*4+2]*0.25f + bv.z, 0.f);
        o.w = fmaxf(accv[r*4+3]*0.25f + bv.w, 0.f);
        *(float4*)&outf[(size_t)n*64 + c] = o;
      }
    }
  }
}

// ---- pool via MFMA (k_base fused): block = 64 nodes x 64 outputs, K=192 ----
__global__ __launch_bounds__(256) void k_pool_mfma(
    const float* __restrict__ xr2,      // [N,64] f32
    const ushort_t* __restrict__ Wfct,  // [64,192] bf16 (W_fc[64:256]^T)
    const float* __restrict__ Wfc,      // [256,64] f32 (rows 0..63 used)
    const float* __restrict__ bfc,
    float* __restrict__ shat,
    float* __restrict__ ssum){
  __shared__ __align__(16) float xs[64][68];
  __shared__ float rls[64];
  __shared__ float bs[64];
  __shared__ float ls_sh[64];
  __shared__ float ls_s[64];
  int tid = threadIdx.x;
  int n0 = blockIdx.x * 64;
  int g = n0 >> 9;
  {
    int row = tid >> 4, col4 = (tid & 15) * 4;
    #pragma unroll
    for (int i = 0; i < 4; ++i){
      float4 v = *(const float4*)&xr2[(size_t)(n0 + row + i*16)*64 + col4];
      *(float4*)&xs[row + i*16][col4] = v;
    }
    if (tid < 16){
      float4 v = *(const float4*)&xr2[(size_t)((size_t)g*GGR)*64 + tid*4];
      *(float4*)&rls[tid*4] = v;
    }
    if (tid >= 128 && tid < 192){ ls_sh[tid-128] = 0.f; ls_s[tid-128] = 0.f; }
  }
  __syncthreads();
  if (tid < 64){
    float b = bfc[tid];
    for (int j = 0; j < 64; ++j) b = fmaf(rls[j], Wfc[j*64 + tid], b);
    bs[tid] = b;
  }
  __syncthreads();
  int w = tid >> 6, lane = tid & 63;
  int lr = lane & 15, lk = lane >> 4;
  f32x4 acc[4];
  #pragma unroll
  for (int ci = 0; ci < 4; ++ci) acc[ci] = (f32x4){0.f,0.f,0.f,0.f};
  int arow = w*16 + lr;
  #pragma unroll
  for (int k0 = 0; k0 < 192; k0 += 32){
    int seg = k0 >> 6;
    int cb = (k0 & 63) + lk*8;
    bf16x8 af;
    #pragma unroll
    for (int j = 0; j < 8; ++j){
      float xv = xs[arow][cb + j];
      float rv = rls[cb + j];
      float v = (seg == 0) ? xv : (seg == 1 ? xv*rv : fabsf(rv - xv));
      af[j] = (short)f2b(v);
    }
    #pragma unroll
    for (int ci = 0; ci < 4; ++ci){
      bf16x8 bfv = *(const bf16x8*)(Wfct + (size_t)(ci*16+lr)*192 + k0 + lk*8);
      acc[ci] = __builtin_amdgcn_mfma_f32_16x16x32_bf16(af, bfv, acc[ci], 0, 0, 0);
    }
  }
  float bsv[4];
  #pragma unroll
  for (int ci = 0; ci < 4; ++ci) bsv[ci] = bs[ci*16 + lr];
  float c_sh[4] = {0.f,0.f,0.f,0.f}, c_s[4] = {0.f,0.f,0.f,0.f};
  #pragma unroll
  for (int q = 0; q < 4; ++q){
    int rrow = w*16 + lk*4 + q;
    float t[4];
    float mx = -1e30f;
    #pragma unroll
    for (int ci = 0; ci < 4; ++ci){
      t[ci] = tanhf_(acc[ci][q] + bsv[ci]);
      mx = fmaxf(mx, t[ci]);
    }
    #pragma unroll
    for (int mask = 1; mask < 16; mask <<= 1) mx = fmaxf(mx, __shfl_xor(mx, mask));
    float e[4], s = 0.f;
    #pragma unroll
    for (int ci = 0; ci < 4; ++ci){ e[ci] = __expf(t[ci] - mx); s += e[ci]; }
    #pragma unroll
    for (int mask = 1; mask < 16; mask <<= 1) s += __shfl_xor(s, mask);
    float invs = 1.0f / s;
    #pragma unroll
    for (int ci = 0; ci < 4; ++ci){
      float xv = xs[rrow][ci*16 + lr];
      c_sh[ci] = fmaf(e[ci]*invs, xv, c_sh[ci]);
      c_s[ci] += xv;
    }
  }
  #pragma unroll
  for (int ci = 0; ci < 4; ++ci){
    c_sh[ci] += __shfl_xor(c_sh[ci], 16); c_sh[ci] += __shfl_xor(c_sh[ci], 32);
    c_s[ci]  += __shfl_xor(c_s[ci], 16);  c_s[ci]  += __shfl_xor(c_s[ci], 32);
  }
  if (lk == 0){
    #pragma unroll
    for (int ci = 0; ci < 4; ++ci){
      atomicAdd(&ls_sh[ci*16 + lr], c_sh[ci]);
      atomicAdd(&ls_s[ci*16 + lr], c_s[ci]);
    }
  }
  __syncthreads();
  if (tid < 64){
    atomicAdd(&shat[g*64 + tid], ls_sh[tid]);
    atomicAdd(&ssum[g*64 + tid], ls_s[tid]);
  }
}

// ------------- final logits + log_softmax -------------
__global__ void k_final(const float* __restrict__ shat, const float* __restrict__ ssum,
                        const float* __restrict__ Wc, const float* __restrict__ bc,
                        float* __restrict__ outp){
  int g = threadIdx.x;   // 128 graphs
  float l0 = bc[0], l1 = bc[1], l2 = bc[2], l3 = bc[3];
  const float s512 = 1.0f/512.0f;
  for (int j = 0; j < 64; ++j){
    float sh = shat[g*64 + j]*s512;
    float ss = ssum[g*64 + j]*s512;
    float4 w1 = *(const float4*)&Wc[j*4];
    float4 w2 = *(const float4*)&Wc[(64+j)*4];
    l0 = fmaf(sh, w1.x, fmaf(ss, w2.x, l0));
    l1 = fmaf(sh, w1.y, fmaf(ss, w2.y, l1));
    l2 = fmaf(sh, w1.z, fmaf(ss, w2.z, l2));
    l3 = fmaf(sh, w1.w, fmaf(ss, w2.w, l3));
  }
  float mx = fmaxf(fmaxf(l0,l1), fmaxf(l2,l3));
  float s = __expf(l0-mx)+__expf(l1-mx)+__expf(l2-mx)+__expf(l3-mx);
  float lse = mx + logf(s);
  outp[g*4+0] = l0 - lse;
  outp[g*4+1] = l1 - lse;
  outp[g*4+2] = l2 - lse;
  outp[g*4+3] = l3 - lse;
}

extern "C" void kernel_launch(void* const* d_in, const int* in_sizes, int n_in,
                              void* d_out, int out_size, void* d_ws, size_t ws_size,
                              hipStream_t stream){
  const float* x        = (const float*)d_in[0];
  const float* root     = (const float*)d_in[1];
  const int*   ei       = (const int*)d_in[2];
  const float* W_post1  = (const float*)d_in[5];
  const float* W_claim1 = (const float*)d_in[6];
  const float* W1       = (const float*)d_in[7];
  const float* att_src1 = (const float*)d_in[8];
  const float* att_dst1 = (const float*)d_in[9];
  const float* b1       = (const float*)d_in[10];
  const float* W_post2  = (const float*)d_in[11];
  const float* W_claim2 = (const float*)d_in[12];
  const float* W2       = (const float*)d_in[13];
  const float* att_src2 = (const float*)d_in[14];
  const float* att_dst2 = (const float*)d_in[15];
  const float* b2       = (const float*)d_in[16];
  const float* W_fc     = (const float*)d_in[17];
  const float* b_fc     = (const float*)d_in[18];
  const float* W_clf    = (const float*)d_in[19];
  const float* b_clf    = (const float*)d_in[20];
  float* out = (float*)d_out;

  char* w = (char*)d_ws;
  size_t o = 0;
  auto alloc = [&](size_t bytes)->char*{ char* p = w + o; o += (bytes + 255) & ~(size_t)255; return p; };
  ushort_t* RB   = (ushort_t*)alloc((size_t)NN*256*2);   // h2b then h3b
  ushort_t* xrb  = (ushort_t*)alloc((size_t)NN*256*2);
  float* xr2  = (float*)alloc((size_t)NN*64*4);
  float* asrc = (float*)alloc((size_t)NN*4*4);
  float* adst = (float*)alloc((size_t)NN*4*4);
  float* hc1  = (float*)alloc(128*64*4);
  float* hc2  = (float*)alloc(128*64*4);
  ushort_t* W1t  = (ushort_t*)alloc((size_t)256*128*2);
  ushort_t* W2t  = (ushort_t*)alloc((size_t)256*512*2);
  ushort_t* Wp1t = (ushort_t*)alloc((size_t)64*512*2);
  ushort_t* Wp2t = (ushort_t*)alloc((size_t)64*64*2);
  ushort_t* Wfct = (ushort_t*)alloc((size_t)64*192*2);
  int*   deg  = (int*)alloc((size_t)NN*4);
  int*   cur  = (int*)alloc((size_t)NN*4);      // adjacent to deg: one memset
  int*   offa = (int*)alloc((size_t)NN*4);
  int*   bsum = (int*)alloc(256*4);
  int*   elist= (int*)alloc((size_t)(2*EE+NN)*4);
  float* shat = (float*)alloc(128*64*4);
  float* ssumv= (float*)alloc(128*64*4);        // adjacent to shat: one memset

  ushort_t* h2b = RB;    // [N,256] bf16
  ushort_t* h3b = RB;    // [N,256] bf16 (h2b dead by then)

  hipMemsetAsync(deg,  0, (size_t)NN*8, stream);     // deg + cur
  hipMemsetAsync(shat, 0, 2*128*64*4, stream);       // shat + ssumv

  k_prep<<<960, 256, 0, stream>>>(W1, W2, W_post1, W_post2, W_fc,
                                  W1t, W2t, Wp1t, Wp2t, Wfct,
                                  root, W_claim1, W_claim2, hc1, hc2);
  k_count<<<256, 256, 0, stream>>>(ei, deg);
  k_scan1<<<256, 256, 0, stream>>>(deg, offa, bsum);
  k_scan2<<<1, 256, 0, stream>>>(bsum);
  k_scan3<<<256, 256, 0, stream>>>(offa, bsum);
  k_fill<<<256, 256, 0, stream>>>(ei, offa, cur, elist);
  k_l1<<<1024, 256, 0, stream>>>(x, Wp1t, hc1, W1t, att_src1, att_dst1, h2b, asrc, adst);
  k_agg<1><<<4096, 256, 0, stream>>>(offa, deg, elist, h2b, asrc, adst, b1, xrb, nullptr);
  k_l2<<<1024, 256, 0, stream>>>(xrb, Wp2t, hc2, W2t, att_src2, att_dst2, h3b, asrc, adst);
  k_agg<2><<<4096, 256, 0, stream>>>(offa, deg, elist, h3b, asrc, adst, b2, nullptr, xr2);
  k_pool_mfma<<<1024, 256, 0, stream>>>(xr2, Wfct, W_fc, b_fc, shat, ssumv);
  k_final<<<1, 128, 0, stream>>>(shat, ssumv, W_clf, b_clf, out);
  (void)in_sizes; (void)n_in; (void)out_size; (void)ws_size;
}

// Round 8
// 256.799 us; speedup vs baseline: 2.9969x; 1.0173x over previous
//
#include <hip/hip_runtime.h>
#include <math.h>

#define NN   65536
#define BB   128
#define GGR  512
#define EE   65536
#define INF_ 512
#define HIDD 64

typedef __attribute__((ext_vector_type(8))) short bf16x8;
typedef __attribute__((ext_vector_type(4))) float f32x4;
typedef unsigned short ushort_t;
typedef unsigned int uint_t;

static __device__ __forceinline__ float sigmoidf_(float x){ return 1.0f/(1.0f+__expf(-x)); }
static __device__ __forceinline__ float lrelu_(float x){ return x>=0.0f ? x : 0.2f*x; }
static __device__ __forceinline__ float tanhf_(float x){
  float e = __expf(2.f*x);
  return 1.f - 2.f/(e + 1.f);
}

// f32 -> bf16 bits, round-to-nearest-even
static __device__ __forceinline__ ushort_t f2b(float f){
  union { float f; uint_t u; } v; v.f = f;
  uint_t u = v.u;
  uint_t r = (u + 0x7fffu + ((u >> 16) & 1u)) >> 16;
  return (ushort_t)r;
}
// bf16 bits -> f32 (exact)
static __device__ __forceinline__ float b2f(uint_t u16){
  union { uint_t u; float f; } v; v.u = u16 << 16; return v.f;
}

// async global->LDS, 16 bytes per lane
static __device__ __forceinline__ void gld16(const void* g, void* l){
  __builtin_amdgcn_global_load_lds((const __attribute__((address_space(1))) void*)g,
                                   (__attribute__((address_space(3))) void*)l, 16, 0, 0);
}

// ---- fused prep: weight transpose+casts, plus hc1/hc2 (blocks >= 832) ----
__global__ void k_prep(const float* __restrict__ W1, const float* __restrict__ W2,
                       const float* __restrict__ Wp1, const float* __restrict__ Wp2,
                       const float* __restrict__ Wfc,
                       ushort_t* __restrict__ W1t, ushort_t* __restrict__ W2t,
                       ushort_t* __restrict__ Wp1t, ushort_t* __restrict__ Wp2t,
                       ushort_t* __restrict__ Wfct,
                       const float* __restrict__ root, const float* __restrict__ Wc1,
                       const float* __restrict__ Wc2, float* __restrict__ hc1,
                       float* __restrict__ hc2){
  if (blockIdx.x >= 832){
    int b = blockIdx.x - 832;
    int f = threadIdx.x;
    if (f < 64){
      const float* r = root + (size_t)b*INF_;
      float a1 = 0.f, a2 = 0.f;
      for (int k = 0; k < INF_; ++k){
        float rv = r[k];
        a1 = fmaf(rv, Wc1[k*HIDD+f], a1);
        a2 = fmaf(rv, Wc2[k*HIDD+f], a2);
      }
      hc1[b*HIDD+f] = a1; hc2[b*HIDD+f] = a2;
    }
    return;
  }
  int idx = blockIdx.x*256 + threadIdx.x;
  if (idx < 32768){                     // W1 [128,256]
    int k = idx >> 8, c = idx & 255;
    W1t[(size_t)c*128 + k] = f2b(W1[idx]);
  } else if (idx < 163840){             // W2 [512,256]
    int j = idx - 32768; int k = j >> 8, c = j & 255;
    W2t[(size_t)c*512 + k] = f2b(W2[j]);
  } else if (idx < 196608){             // W_post1 [512,64]
    int j = idx - 163840; int k = j >> 6, c = j & 63;
    Wp1t[(size_t)c*512 + k] = f2b(Wp1[j]);
  } else if (idx < 200704){             // W_post2 [64,64]
    int j = idx - 196608; int k = j >> 6, c = j & 63;
    Wp2t[(size_t)c*64 + k] = f2b(Wp2[j]);
  } else if (idx < 212992){             // W_fc rows 64..255 [192,64]
    int j = idx - 200704; int k = j >> 6, c = j & 63;
    Wfct[(size_t)c*192 + k] = f2b(Wfc[4096 + j]);
  }
}

// ==== fused layer 1 (linear-read stage): h1 = gated(x@W_post1, hc1) -> H = h1@W1 + att logits ====
// Each wave stages its OWN 16 rows (contiguous 32 KB of x) via coalesced float4 reads,
// casts to bf16, ds_writes into a per-wave XOR-swizzled LDS chunk. No cross-wave sync
// until the h1 handoff. LDS = 4 x 16 KB chunks; h1 tile aliases chunk 0. Total 64 KB.
__global__ __launch_bounds__(256) void k_l1(
    const float* __restrict__ x,        // [N,512] f32
    const ushort_t* __restrict__ Wp1t,  // [64,512] bf16
    const float* __restrict__ hc1,      // [128,64]
    const ushort_t* __restrict__ W1t,   // [256,128] bf16
    const float* __restrict__ att_s, const float* __restrict__ att_d,
    ushort_t* __restrict__ Hout,        // [N,256] bf16
    float* __restrict__ asrc, float* __restrict__ adst){
  __shared__ __align__(16) char Lds[65536];
  int tid = threadIdx.x;
  int w = tid >> 6, lane = tid & 63;
  int lr = lane & 15, lk = lane >> 4;
  int n0 = blockIdx.x * 64;
  int g = n0 >> 9;
  int sw = (lr & 7) << 4;
  char* chunk = Lds + w*16384;
  // ---- linear stage: 32 KB contiguous f32 per wave -> bf16 LDS chunk (swizzled) ----
  const char* xg = (const char*)(x + (size_t)(n0 + w*16)*512);
  #pragma unroll
  for (int it = 0; it < 32; ++it){
    int b = it*1024 + lane*16;          // f32 byte offset within the wave's 32 KB
    float4 v = *(const float4*)(xg + b);
    int row = b >> 11;                  // 0..15
    int off = (b & 2047) >> 1;          // bf16 byte offset within 1024-B row
    uint2 pk;
    pk.x = (uint_t)f2b(v.x) | ((uint_t)f2b(v.y) << 16);
    pk.y = (uint_t)f2b(v.z) | ((uint_t)f2b(v.w) << 16);
    *(uint2*)(chunk + ((row*1024 + off) ^ ((row & 7) << 4))) = pk;
  }
  // ---- phase A: rows w*16..w*16+15, cols 0..63, K=512 (reads own chunk only) ----
  f32x4 accA[4];
  #pragma unroll
  for (int ci = 0; ci < 4; ++ci) accA[ci] = (f32x4){0.f,0.f,0.f,0.f};
  const ushort_t* BbA = Wp1t + (size_t)lr*512 + lk*8;
  #pragma unroll
  for (int k0 = 0; k0 < 512; k0 += 32){
    bf16x8 af = *(const bf16x8*)(chunk + ((lr*1024 + (k0 + lk*8)*2) ^ sw));
    #pragma unroll
    for (int ci = 0; ci < 4; ++ci){
      bf16x8 bfv = *(const bf16x8*)(BbA + (size_t)ci*16*512 + k0);
      accA[ci] = __builtin_amdgcn_mfma_f32_16x16x32_bf16(af, bfv, accA[ci], 0, 0, 0);
    }
  }
  __syncthreads();                      // all waves done with their chunks
  // gate + write h1 tile into Lds[0,16K) (XOR-swizzled rows, 256 B/row)
  char* Hc = Lds;
  #pragma unroll
  for (int ci = 0; ci < 4; ++ci){
    int col = ci*16 + lr;
    float hc = hc1[g*64 + col];
    #pragma unroll
    for (int q = 0; q < 4; ++q){
      int row = w*16 + lk*4 + q;
      int swr = (row & 7) << 4;
      float hx = accA[ci][q];
      float gg = sigmoidf_(hx + hc);
      float fo = gg*hx + (1.f-gg)*hc;
      *(ushort_t*)(Hc + ((row*256 + col*2) ^ swr))        = f2b(fo);
      *(ushort_t*)(Hc + ((row*256 + (64 + col)*2) ^ swr)) = f2b(hx);
    }
  }
  __syncthreads();
  // ---------- phase B: H = h1 @ W1 (K=128), wave = output head ----------
  int c0 = w * 64;
  f32x4 acc[4][4];
  #pragma unroll
  for (int ri = 0; ri < 4; ++ri)
    #pragma unroll
    for (int ci = 0; ci < 4; ++ci) acc[ri][ci] = (f32x4){0.f,0.f,0.f,0.f};
  #pragma unroll
  for (int k0 = 0; k0 < 128; k0 += 32){
    bf16x8 af[4], bfv[4];
    #pragma unroll
    for (int ri = 0; ri < 4; ++ri){
      int lg = (ri*16 + lr)*256 + (k0 + lk*8)*2;
      af[ri] = *(const bf16x8*)(Hc + (lg ^ sw));
    }
    #pragma unroll
    for (int ci = 0; ci < 4; ++ci)
      bfv[ci] = *(const bf16x8*)(W1t + (size_t)(c0 + ci*16 + lr)*128 + k0 + lk*8);
    #pragma unroll
    for (int ri = 0; ri < 4; ++ri)
      #pragma unroll
      for (int ci = 0; ci < 4; ++ci)
        acc[ri][ci] = __builtin_amdgcn_mfma_f32_16x16x32_bf16(af[ri], bfv[ci], acc[ri][ci], 0, 0, 0);
  }
  float as_[4], ad_[4];
  #pragma unroll
  for (int ci = 0; ci < 4; ++ci){
    as_[ci] = att_s[c0 + ci*16 + lr];
    ad_[ci] = att_d[c0 + ci*16 + lr];
  }
  #pragma unroll
  for (int ri = 0; ri < 4; ++ri){
    #pragma unroll
    for (int q = 0; q < 4; ++q){
      int row = n0 + ri*16 + lk*4 + q;
      float ps = 0.f, pd = 0.f;
      #pragma unroll
      for (int ci = 0; ci < 4; ++ci){
        float v = acc[ri][ci][q];
        Hout[(size_t)row*256 + c0 + ci*16 + lr] = f2b(v);
        ps = fmaf(v, as_[ci], ps);
        pd = fmaf(v, ad_[ci], pd);
      }
      #pragma unroll
      for (int m = 1; m < 16; m <<= 1){
        ps += __shfl_xor(ps, m);
        pd += __shfl_xor(pd, m);
      }
      if (lr == 0){
        asrc[(size_t)row*4 + w] = ps;
        adst[(size_t)row*4 + w] = pd;
      }
    }
  }
}

// ==== fused layer 2: x3 slab (per head) in LDS -> H = x3@W2 + att logits ====
__global__ __launch_bounds__(256) void k_l2(
    const ushort_t* __restrict__ xrb,   // [N,256] bf16
    const ushort_t* __restrict__ Wp2t,  // [64,64] bf16
    const float* __restrict__ hc2,      // [128,64]
    const ushort_t* __restrict__ W2t,   // [256,512] bf16
    const float* __restrict__ att_s, const float* __restrict__ att_d,
    ushort_t* __restrict__ Hout,        // [N,256] bf16
    float* __restrict__ asrc, float* __restrict__ adst){
  __shared__ __align__(16) ushort_t xs[64*256];   // 32 KB xr tile (swizzled)
  __shared__ __align__(16) ushort_t x3s[64*128];  // 16 KB x3 slab (swizzled)
  int tid = threadIdx.x;
  int w = tid >> 6, lane = tid & 63;
  int lr = lane & 15, lk = lane >> 4;
  int n0 = blockIdx.x * 64;
  int g = n0 >> 9;
  int sw = (lr & 7) << 4;
  char* Xc = (char*)xs;
  char* Sc = (char*)x3s;
  {
    const char* Ag = (const char*)(xrb + (size_t)n0*256);
    #pragma unroll
    for (int i = 0; i < 8; ++i){
      int p = i*4096 + tid*16;
      int row = p >> 9;
      int l = p ^ ((row & 7) << 4);
      gld16(Ag + (size_t)row*512 + (l & 511), Xc + p);
    }
  }
  __syncthreads();
  int c0 = w * 64;
  f32x4 acc[4][4];
  #pragma unroll
  for (int ri = 0; ri < 4; ++ri)
    #pragma unroll
    for (int ci = 0; ci < 4; ++ci) acc[ri][ci] = (f32x4){0.f,0.f,0.f,0.f};
  for (int hd = 0; hd < 4; ++hd){
    // ---- phase A: hs rows w*16..+15 for head hd (K=64) ----
    f32x4 acc2[4];
    #pragma unroll
    for (int ci = 0; ci < 4; ++ci) acc2[ci] = (f32x4){0.f,0.f,0.f,0.f};
    #pragma unroll
    for (int k0 = 0; k0 < 64; k0 += 32){
      int lg = (w*16 + lr)*512 + (hd*64 + k0 + lk*8)*2;
      bf16x8 af = *(const bf16x8*)(Xc + (lg ^ sw));
      #pragma unroll
      for (int ci = 0; ci < 4; ++ci){
        bf16x8 bfv = *(const bf16x8*)(Wp2t + (size_t)(ci*16 + lr)*64 + k0 + lk*8);
        acc2[ci] = __builtin_amdgcn_mfma_f32_16x16x32_bf16(af, bfv, acc2[ci], 0, 0, 0);
      }
    }
    #pragma unroll
    for (int ci = 0; ci < 4; ++ci){
      int col = ci*16 + lr;
      float hc = hc2[g*64 + col];
      #pragma unroll
      for (int q = 0; q < 4; ++q){
        int row = w*16 + lk*4 + q;
        int swr = (row & 7) << 4;
        float a = acc2[ci][q];
        float gg = sigmoidf_(a + hc);
        *(ushort_t*)(Sc + ((row*256 + col*2) ^ swr))        = f2b(gg*a + (1.f-gg)*hc);
        *(ushort_t*)(Sc + ((row*256 + (64 + col)*2) ^ swr)) = f2b(a);
      }
    }
    __syncthreads();
    // ---- phase B: K-slab 128 of the GAT GEMM, wave = output head ----
    #pragma unroll
    for (int k0 = 0; k0 < 128; k0 += 32){
      bf16x8 af[4], bfv[4];
      #pragma unroll
      for (int ri = 0; ri < 4; ++ri){
        int lg = (ri*16 + lr)*256 + (k0 + lk*8)*2;
        af[ri] = *(const bf16x8*)(Sc + (lg ^ sw));
      }
      #pragma unroll
      for (int ci = 0; ci < 4; ++ci)
        bfv[ci] = *(const bf16x8*)(W2t + (size_t)(c0 + ci*16 + lr)*512 + hd*128 + k0 + lk*8);
      #pragma unroll
      for (int ri = 0; ri < 4; ++ri)
        #pragma unroll
        for (int ci = 0; ci < 4; ++ci)
          acc[ri][ci] = __builtin_amdgcn_mfma_f32_16x16x32_bf16(af[ri], bfv[ci], acc[ri][ci], 0, 0, 0);
    }
    if (hd < 3) __syncthreads();
  }
  float as_[4], ad_[4];
  #pragma unroll
  for (int ci = 0; ci < 4; ++ci){
    as_[ci] = att_s[c0 + ci*16 + lr];
    ad_[ci] = att_d[c0 + ci*16 + lr];
  }
  #pragma unroll
  for (int ri = 0; ri < 4; ++ri){
    #pragma unroll
    for (int q = 0; q < 4; ++q){
      int row = n0 + ri*16 + lk*4 + q;
      float ps = 0.f, pd = 0.f;
      #pragma unroll
      for (int ci = 0; ci < 4; ++ci){
        float v = acc[ri][ci][q];
        Hout[(size_t)row*256 + c0 + ci*16 + lr] = f2b(v);
        ps = fmaf(v, as_[ci], ps);
        pd = fmaf(v, ad_[ci], pd);
      }
      #pragma unroll
      for (int m = 1; m < 16; m <<= 1){
        ps += __shfl_xor(ps, m);
        pd += __shfl_xor(pd, m);
      }
      if (lr == 0){
        asrc[(size_t)row*4 + w] = ps;
        adst[(size_t)row*4 + w] = pd;
      }
    }
  }
}

// ---------------- CSR build ----------------
__global__ void k_count(const int* __restrict__ ei, int* __restrict__ deg){
  int t = blockIdx.x*256 + threadIdx.x;
  int s = ei[t], d = ei[EE + t];
  atomicAdd(&deg[d], 1);
  atomicAdd(&deg[s], 1);
}

__global__ void k_scan1(const int* __restrict__ deg, int* __restrict__ offa,
                        int* __restrict__ bsum){
  __shared__ int sm[256];
  int tid = threadIdx.x, idx = blockIdx.x*256 + tid;
  int v = deg[idx] + 1;                 // +1 self-loop
  sm[tid] = v; __syncthreads();
  for (int o = 1; o < 256; o <<= 1){
    int t = (tid >= o) ? sm[tid-o] : 0;
    __syncthreads();
    sm[tid] += t;
    __syncthreads();
  }
  offa[idx] = sm[tid] - v;
  if (tid == 255) bsum[blockIdx.x] = sm[255];
}

__global__ void k_scan2(int* __restrict__ bsum){
  __shared__ int sm[256];
  int tid = threadIdx.x;
  int v = bsum[tid];
  sm[tid] = v; __syncthreads();
  for (int o = 1; o < 256; o <<= 1){
    int t = (tid >= o) ? sm[tid-o] : 0;
    __syncthreads();
    sm[tid] += t;
    __syncthreads();
  }
  bsum[tid] = sm[tid] - v;
}

__global__ void k_scan3(int* __restrict__ offa, const int* __restrict__ bsum){
  int idx = blockIdx.x*256 + threadIdx.x;
  offa[idx] += bsum[idx >> 8];
}

__global__ void k_fill(const int* __restrict__ ei, const int* __restrict__ offa,
                       int* __restrict__ cur, int* __restrict__ elist){
  int t = blockIdx.x*256 + threadIdx.x;
  int s = ei[t], d = ei[EE + t];
  int p = atomicAdd(&cur[d], 1); elist[offa[d] + p] = s;   // TD edge
  p = atomicAdd(&cur[s], 1);     elist[offa[s] + p] = d;   // BU (flipped) edge
  p = atomicAdd(&cur[t], 1);     elist[offa[t] + p] = t;   // self-loop (E==N)
}

// ------ GAT softmax-aggregate (h bf16); XCD-swizzled; e-values cached in LDS ------
template<int LAYER>
__global__ __launch_bounds__(256) void k_agg(const int* __restrict__ offa,
                                             const int* __restrict__ deg,
                                             const int* __restrict__ elist,
                                             const ushort_t* __restrict__ h,  // [N,256] bf16
                                             const float* __restrict__ asrc,
                                             const float* __restrict__ adst,
                                             const float* __restrict__ bias,
                                             ushort_t* __restrict__ outb,
                                             float* __restrict__ outf){
  __shared__ float eS[4][4][17][4];     // [wave][grp][edge(pad17)][head]
  __shared__ int   sS[4][4][17];
  int bid = blockIdx.x;
  int swz = (bid & 7) * (4096/8) + (bid >> 3);   // XCD-contiguous graphs
  int tid = threadIdx.x;
  int wave = tid >> 6, lane = tid & 63;
  int grp = lane >> 4, l = lane & 15;
  int n = swz*16 + wave*4 + grp;
  int o0 = offa[n], cnt = deg[n] + 1;
  float4 adv = *(const float4*)&adst[(size_t)n*4];
  float ad[4] = {adv.x, adv.y, adv.z, adv.w};
  int lim = (cnt < 16) ? cnt : 16;
  int s_l = elist[o0 + ((l < cnt) ? l : 0)];
  float4 asv = *(const float4*)&asrc[(size_t)s_l*4];
  float e_l[4];
  e_l[0] = lrelu_(asv.x + ad[0]); e_l[1] = lrelu_(asv.y + ad[1]);
  e_l[2] = lrelu_(asv.z + ad[2]); e_l[3] = lrelu_(asv.w + ad[3]);
  if (l < lim){
    sS[wave][grp][l] = s_l;
    *(float4*)&eS[wave][grp][l][0] = make_float4(e_l[0], e_l[1], e_l[2], e_l[3]);
  }
  float m[4];
  #pragma unroll
  for (int hh = 0; hh < 4; ++hh) m[hh] = (l < cnt) ? e_l[hh] : -1e30f;
  for (int i = 16 + l; i < cnt; i += 16){
    int s = elist[o0 + i];
    float4 a2 = *(const float4*)&asrc[(size_t)s*4];
    m[0] = fmaxf(m[0], lrelu_(a2.x + ad[0]));
    m[1] = fmaxf(m[1], lrelu_(a2.y + ad[1]));
    m[2] = fmaxf(m[2], lrelu_(a2.z + ad[2]));
    m[3] = fmaxf(m[3], lrelu_(a2.w + ad[3]));
  }
  #pragma unroll
  for (int mask = 1; mask < 16; mask <<= 1)
    #pragma unroll
    for (int hh = 0; hh < 4; ++hh) m[hh] = fmaxf(m[hh], __shfl_xor(m[hh], mask));
  int myh = l >> 2;
  float mm = m[myh];
  float den = 0.f;
  float accv[16] = {};
  for (int i = 0; i < lim; ++i){
    int s = sS[wave][grp][i];
    float e = eS[wave][grp][i][myh];
    float ex = __expf(e - mm);
    den += ex;
    const uint4* hp = (const uint4*)(h + (size_t)s*256 + l*16);
    uint4 h0 = hp[0], h1v = hp[1];
    uint_t uu[8] = {h0.x, h0.y, h0.z, h0.w, h1v.x, h1v.y, h1v.z, h1v.w};
    #pragma unroll
    for (int r = 0; r < 8; ++r){
      accv[2*r+0] = fmaf(ex, b2f(uu[r] & 0xffffu), accv[2*r+0]);
      accv[2*r+1] = fmaf(ex, b2f(uu[r] >> 16),     accv[2*r+1]);
    }
  }
  for (int i = 16; i < cnt; ++i){
    int s = elist[o0 + i];
    float4 a2 = *(const float4*)&asrc[(size_t)s*4];
    float e = lrelu_(((const float*)&a2)[myh] + ad[myh]);
    float ex = __expf(e - mm);
    den += ex;
    const uint4* hp = (const uint4*)(h + (size_t)s*256 + l*16);
    uint4 h0 = hp[0], h1v = hp[1];
    uint_t uu[8] = {h0.x, h0.y, h0.z, h0.w, h1v.x, h1v.y, h1v.z, h1v.w};
    #pragma unroll
    for (int r = 0; r < 8; ++r){
      accv[2*r+0] = fmaf(ex, b2f(uu[r] & 0xffffu), accv[2*r+0]);
      accv[2*r+1] = fmaf(ex, b2f(uu[r] >> 16),     accv[2*r+1]);
    }
  }
  float inv = 1.0f / den;
  if (LAYER == 1){
    #pragma unroll
    for (int r = 0; r < 4; ++r){
      int c = l*16 + r*4;
      float4 bv = *(const float4*)&bias[c];
      float o0v = fmaxf(accv[r*4+0]*inv + bv.x, 0.f);
      float o1v = fmaxf(accv[r*4+1]*inv + bv.y, 0.f);
      float o2v = fmaxf(accv[r*4+2]*inv + bv.z, 0.f);
      float o3v = fmaxf(accv[r*4+3]*inv + bv.w, 0.f);
      uint2 pk;
      pk.x = (uint_t)f2b(o0v) | ((uint_t)f2b(o1v) << 16);
      pk.y = (uint_t)f2b(o2v) | ((uint_t)f2b(o3v) << 16);
      *(uint2*)&outb[(size_t)n*256 + c] = pk;
    }
  } else {
    #pragma unroll
    for (int r = 0; r < 16; ++r) accv[r] *= inv;
    #pragma unroll
    for (int r = 0; r < 16; ++r){
      accv[r] += __shfl_xor(accv[r], 4);
      accv[r] += __shfl_xor(accv[r], 8);
    }
    if (l < 4){
      #pragma unroll
      for (int r = 0; r < 4; ++r){
        int c = l*16 + r*4;
        float4 bv = *(const float4*)&bias[c];
        float4 o;
        o.x = fmaxf(accv[r*4+0]*0.25f + bv.x, 0.f);
        o.y = fmaxf(accv[r*4+1]*0.25f + bv.y, 0.f);
        o.z = fmaxf(accv[r*4+2]*0.25f + bv.z, 0.f);
        o.w = fmaxf(accv[r*4+3]*0.25f + bv.w, 0.f);
        *(float4*)&outf[(size_t)n*64 + c] = o;
      }
    }
  }
}

// ---- pool via MFMA (k_base fused): block = 64 nodes x 64 outputs, K=192 ----
__global__ __launch_bounds__(256) void k_pool_mfma(
    const float* __restrict__ xr2,      // [N,64] f32
    const ushort_t* __restrict__ Wfct,  // [64,192] bf16 (W_fc[64:256]^T)
    const float* __restrict__ Wfc,      // [256,64] f32 (rows 0..63 used)
    const float* __restrict__ bfc,
    float* __restrict__ shat,
    float* __restrict__ ssum){
  __shared__ __align__(16) float xs[64][68];
  __shared__ float rls[64];
  __shared__ float bs[64];
  __shared__ float ls_sh[64];
  __shared__ float ls_s[64];
  int tid = threadIdx.x;
  int n0 = blockIdx.x * 64;
  int g = n0 >> 9;
  {
    int row = tid >> 4, col4 = (tid & 15) * 4;
    #pragma unroll
    for (int i = 0; i < 4; ++i){
      float4 v = *(const float4*)&xr2[(size_t)(n0 + row + i*16)*64 + col4];
      *(float4*)&xs[row + i*16][col4] = v;
    }
    if (tid < 16){
      float4 v = *(const float4*)&xr2[(size_t)((size_t)g*GGR)*64 + tid*4];
      *(float4*)&rls[tid*4] = v;
    }
    if (tid >= 128 && tid < 192){ ls_sh[tid-128] = 0.f; ls_s[tid-128] = 0.f; }
  }
  __syncthreads();
  if (tid < 64){
    float b = bfc[tid];
    for (int j = 0; j < 64; ++j) b = fmaf(rls[j], Wfc[j*64 + tid], b);
    bs[tid] = b;
  }
  __syncthreads();
  int w = tid >> 6, lane = tid & 63;
  int lr = lane & 15, lk = lane >> 4;
  f32x4 acc[4];
  #pragma unroll
  for (int ci = 0; ci < 4; ++ci) acc[ci] = (f32x4){0.f,0.f,0.f,0.f};
  int arow = w*16 + lr;
  #pragma unroll
  for (int k0 = 0; k0 < 192; k0 += 32){
    int seg = k0 >> 6;
    int cb = (k0 & 63) + lk*8;
    bf16x8 af;
    #pragma unroll
    for (int j = 0; j < 8; ++j){
      float xv = xs[arow][cb + j];
      float rv = rls[cb + j];
      float v = (seg == 0) ? xv : (seg == 1 ? xv*rv : fabsf(rv - xv));
      af[j] = (short)f2b(v);
    }
    #pragma unroll
    for (int ci = 0; ci < 4; ++ci){
      bf16x8 bfv = *(const bf16x8*)(Wfct + (size_t)(ci*16+lr)*192 + k0 + lk*8);
      acc[ci] = __builtin_amdgcn_mfma_f32_16x16x32_bf16(af, bfv, acc[ci], 0, 0, 0);
    }
  }
  float bsv[4];
  #pragma unroll
  for (int ci = 0; ci < 4; ++ci) bsv[ci] = bs[ci*16 + lr];
  float c_sh[4] = {0.f,0.f,0.f,0.f}, c_s[4] = {0.f,0.f,0.f,0.f};
  #pragma unroll
  for (int q = 0; q < 4; ++q){
    int rrow = w*16 + lk*4 + q;
    float t[4];
    float mx = -1e30f;
    #pragma unroll
    for (int ci = 0; ci < 4; ++ci){
      t[ci] = tanhf_(acc[ci][q] + bsv[ci]);
      mx = fmaxf(mx, t[ci]);
    }
    #pragma unroll
    for (int mask = 1; mask < 16; mask <<= 1) mx = fmaxf(mx, __shfl_xor(mx, mask));
    float e[4], s = 0.f;
    #pragma unroll
    for (int ci = 0; ci < 4; ++ci){ e[ci] = __expf(t[ci] - mx); s += e[ci]; }
    #pragma unroll
    for (int mask = 1; mask < 16; mask <<= 1) s += __shfl_xor(s, mask);
    float invs = 1.0f / s;
    #pragma unroll
    for (int ci = 0; ci < 4; ++ci){
      float xv = xs[rrow][ci*16 + lr];
      c_sh[ci] = fmaf(e[ci]*invs, xv, c_sh[ci]);
      c_s[ci] += xv;
    }
  }
  #pragma unroll
  for (int ci = 0; ci < 4; ++ci){
    c_sh[ci] += __shfl_xor(c_sh[ci], 16); c_sh[ci] += __shfl_xor(c_sh[ci], 32);
    c_s[ci]  += __shfl_xor(c_s[ci], 16);  c_s[ci]  += __shfl_xor(c_s[ci], 32);
  }
  if (lk == 0){
    #pragma unroll
    for (int ci = 0; ci < 4; ++ci){
      atomicAdd(&ls_sh[ci*16 + lr], c_sh[ci]);
      atomicAdd(&ls_s[ci*16 + lr], c_s[ci]);
    }
  }
  __syncthreads();
  if (tid < 64){
    atomicAdd(&shat[g*64 + tid], ls_sh[tid]);
    atomicAdd(&ssum[g*64 + tid], ls_s[tid]);
  }
}

// ------------- final logits + log_softmax -------------
__global__ void k_final(const float* __restrict__ shat, const float* __restrict__ ssum,
                        const float* __restrict__ Wc, const float* __restrict__ bc,
                        float* __restrict__ outp){
  int g = threadIdx.x;   // 128 graphs
  float l0 = bc[0], l1 = bc[1], l2 = bc[2], l3 = bc[3];
  const float s512 = 1.0f/512.0f;
  for (int j = 0; j < 64; ++j){
    float sh = shat[g*64 + j]*s512;
    float ss = ssum[g*64 + j]*s512;
    float4 w1 = *(const float4*)&Wc[j*4];
    float4 w2 = *(const float4*)&Wc[(64+j)*4];
    l0 = fmaf(sh, w1.x, fmaf(ss, w2.x, l0));
    l1 = fmaf(sh, w1.y, fmaf(ss, w2.y, l1));
    l2 = fmaf(sh, w1.z, fmaf(ss, w2.z, l2));
    l3 = fmaf(sh, w1.w, fmaf(ss, w2.w, l3));
  }
  float mx = fmaxf(fmaxf(l0,l1), fmaxf(l2,l3));
  float s = __expf(l0-mx)+__expf(l1-mx)+__expf(l2-mx)+__expf(l3-mx);
  float lse = mx + logf(s);
  outp[g*4+0] = l0 - lse;
  outp[g*4+1] = l1 - lse;
  outp[g*4+2] = l2 - lse;
  outp[g*4+3] = l3 - lse;
}

extern "C" void kernel_launch(void* const* d_in, const int* in_sizes, int n_in,
                              void* d_out, int out_size, void* d_ws, size_t ws_size,
                              hipStream_t stream){
  const float* x        = (const float*)d_in[0];
  const float* root     = (const float*)d_in[1];
  const int*   ei       = (const int*)d_in[2];
  const float* W_post1  = (const float*)d_in[5];
  const float* W_claim1 = (const float*)d_in[6];
  const float* W1       = (const float*)d_in[7];
  const float* att_src1 = (const float*)d_in[8];
  const float* att_dst1 = (const float*)d_in[9];
  const float* b1       = (const float*)d_in[10];
  const float* W_post2  = (const float*)d_in[11];
  const float* W_claim2 = (const float*)d_in[12];
  const float* W2       = (const float*)d_in[13];
  const float* att_src2 = (const float*)d_in[14];
  const float* att_dst2 = (const float*)d_in[15];
  const float* b2       = (const float*)d_in[16];
  const float* W_fc     = (const float*)d_in[17];
  const float* b_fc     = (const float*)d_in[18];
  const float* W_clf    = (const float*)d_in[19];
  const float* b_clf    = (const float*)d_in[20];
  float* out = (float*)d_out;

  char* w = (char*)d_ws;
  size_t o = 0;
  auto alloc = [&](size_t bytes)->char*{ char* p = w + o; o += (bytes + 255) & ~(size_t)255; return p; };
  ushort_t* RB   = (ushort_t*)alloc((size_t)NN*256*2);   // h2b then h3b
  ushort_t* xrb  = (ushort_t*)alloc((size_t)NN*256*2);
  float* xr2  = (float*)alloc((size_t)NN*64*4);
  float* asrc = (float*)alloc((size_t)NN*4*4);
  float* adst = (float*)alloc((size_t)NN*4*4);
  float* hc1  = (float*)alloc(128*64*4);
  float* hc2  = (float*)alloc(128*64*4);
  ushort_t* W1t  = (ushort_t*)alloc((size_t)256*128*2);
  ushort_t* W2t  = (ushort_t*)alloc((size_t)256*512*2);
  ushort_t* Wp1t = (ushort_t*)alloc((size_t)64*512*2);
  ushort_t* Wp2t = (ushort_t*)alloc((size_t)64*64*2);
  ushort_t* Wfct = (ushort_t*)alloc((size_t)64*192*2);
  int*   deg  = (int*)alloc((size_t)NN*4);
  int*   cur  = (int*)alloc((size_t)NN*4);      // adjacent to deg: one memset
  int*   offa = (int*)alloc((size_t)NN*4);
  int*   bsum = (int*)alloc(256*4);
  int*   elist= (int*)alloc((size_t)(2*EE+NN)*4);
  float* shat = (float*)alloc(128*64*4);
  float* ssumv= (float*)alloc(128*64*4);        // adjacent to shat: one memset

  ushort_t* h2b = RB;    // [N,256] bf16
  ushort_t* h3b = RB;    // [N,256] bf16 (h2b dead by then)

  hipMemsetAsync(deg,  0, (size_t)NN*8, stream);     // deg + cur
  hipMemsetAsync(shat, 0, 2*128*64*4, stream);       // shat + ssumv

  k_prep<<<960, 256, 0, stream>>>(W1, W2, W_post1, W_post2, W_fc,
                                  W1t, W2t, Wp1t, Wp2t, Wfct,
                                  root, W_claim1, W_claim2, hc1, hc2);
  k_count<<<256, 256, 0, stream>>>(ei, deg);
  k_scan1<<<256, 256, 0, stream>>>(deg, offa, bsum);
  k_scan2<<<1, 256, 0, stream>>>(bsum);
  k_scan3<<<256, 256, 0, stream>>>(offa, bsum);
  k_fill<<<256, 256, 0, stream>>>(ei, offa, cur, elist);
  k_l1<<<1024, 256, 0, stream>>>(x, Wp1t, hc1, W1t, att_src1, att_dst1, h2b, asrc, adst);
  k_agg<1><<<4096, 256, 0, stream>>>(offa, deg, elist, h2b, asrc, adst, b1, xrb, nullptr);
  k_l2<<<1024, 256, 0, stream>>>(xrb, Wp2t, hc2, W2t, att_src2, att_dst2, h3b, asrc, adst);
  k_agg<2><<<4096, 256, 0, stream>>>(offa, deg, elist, h3b, asrc, adst, b2, nullptr, xr2);
  k_pool_mfma<<<1024, 256, 0, stream>>>(xr2, Wfct, W_fc, b_fc, shat, ssumv);
  k_final<<<1, 128, 0, stream>>>(shat, ssumv, W_clf, b_clf, out);
  (void)in_sizes; (void)n_in; (void)out_size; (void)ws_size;
}

// Round 9
// 245.343 us; speedup vs baseline: 3.1369x; 1.0467x over previous
//
#include <hip/hip_runtime.h>
#include <math.h>

#define NN   65536
#define BB   128
#define GGR  512
#define EE   65536
#define INF_ 512
#define HIDD 64

typedef __attribute__((ext_vector_type(8))) short bf16x8;
typedef __attribute__((ext_vector_type(4))) float f32x4;
typedef unsigned short ushort_t;
typedef unsigned int uint_t;

static __device__ __forceinline__ float sigmoidf_(float x){ return 1.0f/(1.0f+__expf(-x)); }
static __device__ __forceinline__ float lrelu_(float x){ return x>=0.0f ? x : 0.2f*x; }
static __device__ __forceinline__ float tanhf_(float x){
  float e = __expf(2.f*x);
  return 1.f - 2.f/(e + 1.f);
}

// f32 -> bf16 bits, round-to-nearest-even
static __device__ __forceinline__ ushort_t f2b(float f){
  union { float f; uint_t u; } v; v.f = f;
  uint_t u = v.u;
  uint_t r = (u + 0x7fffu + ((u >> 16) & 1u)) >> 16;
  return (ushort_t)r;
}
// bf16 bits -> f32 (exact)
static __device__ __forceinline__ float b2f(uint_t u16){
  union { uint_t u; float f; } v; v.u = u16 << 16; return v.f;
}

// ---- fused prep: weight transpose+casts, plus hc1/hc2 (blocks >= 832) ----
__global__ void k_prep(const float* __restrict__ W1, const float* __restrict__ W2,
                       const float* __restrict__ Wp1, const float* __restrict__ Wp2,
                       const float* __restrict__ Wfc,
                       ushort_t* __restrict__ W1t, ushort_t* __restrict__ W2t,
                       ushort_t* __restrict__ Wp1t, ushort_t* __restrict__ Wp2t,
                       ushort_t* __restrict__ Wfct,
                       const float* __restrict__ root, const float* __restrict__ Wc1,
                       const float* __restrict__ Wc2, float* __restrict__ hc1,
                       float* __restrict__ hc2){
  if (blockIdx.x >= 832){
    int b = blockIdx.x - 832;
    int f = threadIdx.x;
    if (f < 64){
      const float* r = root + (size_t)b*INF_;
      float a1 = 0.f, a2 = 0.f;
      for (int k = 0; k < INF_; ++k){
        float rv = r[k];
        a1 = fmaf(rv, Wc1[k*HIDD+f], a1);
        a2 = fmaf(rv, Wc2[k*HIDD+f], a2);
      }
      hc1[b*HIDD+f] = a1; hc2[b*HIDD+f] = a2;
    }
    return;
  }
  int idx = blockIdx.x*256 + threadIdx.x;
  if (idx < 32768){                     // W1 [128,256]
    int k = idx >> 8, c = idx & 255;
    W1t[(size_t)c*128 + k] = f2b(W1[idx]);
  } else if (idx < 163840){             // W2 [512,256]
    int j = idx - 32768; int k = j >> 8, c = j & 255;
    W2t[(size_t)c*512 + k] = f2b(W2[j]);
  } else if (idx < 196608){             // W_post1 [512,64]
    int j = idx - 163840; int k = j >> 6, c = j & 63;
    Wp1t[(size_t)c*512 + k] = f2b(Wp1[j]);
  } else if (idx < 200704){             // W_post2 [64,64]
    int j = idx - 196608; int k = j >> 6, c = j & 63;
    Wp2t[(size_t)c*64 + k] = f2b(Wp2[j]);
  } else if (idx < 212992){             // W_fc rows 64..255 [192,64]
    int j = idx - 200704; int k = j >> 6, c = j & 63;
    Wfct[(size_t)c*192 + k] = f2b(Wfc[4096 + j]);
  }
}

// ==== fused layer 1 (register-A): h1 = gated(x@W_post1, hc1) -> H = h1@W1 + att logits ====
// Phase A loads A-fragments straight from global f32 x into registers (lane-private rows)
// -> f2b -> MFMA. No LDS, no barriers in phase A. LDS = 16 KB h1 handoff tile only.
__global__ __launch_bounds__(256) void k_l1(
    const float* __restrict__ x,        // [N,512] f32
    const ushort_t* __restrict__ Wp1t,  // [64,512] bf16
    const float* __restrict__ hc1,      // [128,64]
    const ushort_t* __restrict__ W1t,   // [256,128] bf16
    const float* __restrict__ att_s, const float* __restrict__ att_d,
    ushort_t* __restrict__ Hout,        // [N,256] bf16
    float* __restrict__ asrc, float* __restrict__ adst){
  __shared__ __align__(16) char Hc[16384];   // h1 tile (swizzled 256 B rows)
  int tid = threadIdx.x;
  int w = tid >> 6, lane = tid & 63;
  int lr = lane & 15, lk = lane >> 4;
  int n0 = blockIdx.x * 64;
  int g = n0 >> 9;
  int sw = (lr & 7) << 4;
  // ---- phase A: rows w*16+lr, K=512, A from global registers ----
  f32x4 accA[4];
  #pragma unroll
  for (int ci = 0; ci < 4; ++ci) accA[ci] = (f32x4){0.f,0.f,0.f,0.f};
  const char* xrow = (const char*)x + (size_t)(n0 + w*16 + lr)*2048 + lk*32;
  const ushort_t* BbA = Wp1t + (size_t)lr*512 + lk*8;
  #pragma unroll
  for (int j = 0; j < 16; ++j){
    float4 a0 = *(const float4*)(xrow + j*128);
    float4 a1 = *(const float4*)(xrow + j*128 + 16);
    bf16x8 af;
    af[0]=(short)f2b(a0.x); af[1]=(short)f2b(a0.y); af[2]=(short)f2b(a0.z); af[3]=(short)f2b(a0.w);
    af[4]=(short)f2b(a1.x); af[5]=(short)f2b(a1.y); af[6]=(short)f2b(a1.z); af[7]=(short)f2b(a1.w);
    #pragma unroll
    for (int ci = 0; ci < 4; ++ci){
      bf16x8 bfv = *(const bf16x8*)(BbA + (size_t)ci*16*512 + j*32);
      accA[ci] = __builtin_amdgcn_mfma_f32_16x16x32_bf16(af, bfv, accA[ci], 0, 0, 0);
    }
  }
  // gate + write h1 tile into LDS (XOR-swizzled rows, 256 B/row)
  #pragma unroll
  for (int ci = 0; ci < 4; ++ci){
    int col = ci*16 + lr;
    float hc = hc1[g*64 + col];
    #pragma unroll
    for (int q = 0; q < 4; ++q){
      int row = w*16 + lk*4 + q;
      int swr = (row & 7) << 4;
      float hx = accA[ci][q];
      float gg = sigmoidf_(hx + hc);
      float fo = gg*hx + (1.f-gg)*hc;
      *(ushort_t*)(Hc + ((row*256 + col*2) ^ swr))        = f2b(fo);
      *(ushort_t*)(Hc + ((row*256 + (64 + col)*2) ^ swr)) = f2b(hx);
    }
  }
  __syncthreads();
  // ---------- phase B: H = h1 @ W1 (K=128), wave = output head ----------
  int c0 = w * 64;
  f32x4 acc[4][4];
  #pragma unroll
  for (int ri = 0; ri < 4; ++ri)
    #pragma unroll
    for (int ci = 0; ci < 4; ++ci) acc[ri][ci] = (f32x4){0.f,0.f,0.f,0.f};
  #pragma unroll
  for (int k0 = 0; k0 < 128; k0 += 32){
    bf16x8 af[4], bfv[4];
    #pragma unroll
    for (int ri = 0; ri < 4; ++ri){
      int lg = (ri*16 + lr)*256 + (k0 + lk*8)*2;
      af[ri] = *(const bf16x8*)(Hc + (lg ^ sw));
    }
    #pragma unroll
    for (int ci = 0; ci < 4; ++ci)
      bfv[ci] = *(const bf16x8*)(W1t + (size_t)(c0 + ci*16 + lr)*128 + k0 + lk*8);
    #pragma unroll
    for (int ri = 0; ri < 4; ++ri)
      #pragma unroll
      for (int ci = 0; ci < 4; ++ci)
        acc[ri][ci] = __builtin_amdgcn_mfma_f32_16x16x32_bf16(af[ri], bfv[ci], acc[ri][ci], 0, 0, 0);
  }
  float as_[4], ad_[4];
  #pragma unroll
  for (int ci = 0; ci < 4; ++ci){
    as_[ci] = att_s[c0 + ci*16 + lr];
    ad_[ci] = att_d[c0 + ci*16 + lr];
  }
  #pragma unroll
  for (int ri = 0; ri < 4; ++ri){
    #pragma unroll
    for (int q = 0; q < 4; ++q){
      int row = n0 + ri*16 + lk*4 + q;
      float ps = 0.f, pd = 0.f;
      #pragma unroll
      for (int ci = 0; ci < 4; ++ci){
        float v = acc[ri][ci][q];
        Hout[(size_t)row*256 + c0 + ci*16 + lr] = f2b(v);
        ps = fmaf(v, as_[ci], ps);
        pd = fmaf(v, ad_[ci], pd);
      }
      #pragma unroll
      for (int m = 1; m < 16; m <<= 1){
        ps += __shfl_xor(ps, m);
        pd += __shfl_xor(pd, m);
      }
      if (lr == 0){
        asrc[(size_t)row*4 + w] = ps;
        adst[(size_t)row*4 + w] = pd;
      }
    }
  }
}

// ==== fused layer 2 (register-A phase A): x3 slab in LDS -> H = x3@W2 + att logits ====
__global__ __launch_bounds__(256) void k_l2(
    const ushort_t* __restrict__ xrb,   // [N,256] bf16
    const ushort_t* __restrict__ Wp2t,  // [64,64] bf16
    const float* __restrict__ hc2,      // [128,64]
    const ushort_t* __restrict__ W2t,   // [256,512] bf16
    const float* __restrict__ att_s, const float* __restrict__ att_d,
    ushort_t* __restrict__ Hout,        // [N,256] bf16
    float* __restrict__ asrc, float* __restrict__ adst){
  __shared__ __align__(16) ushort_t x3s[64*128];  // 16 KB x3 slab (swizzled)
  int tid = threadIdx.x;
  int w = tid >> 6, lane = tid & 63;
  int lr = lane & 15, lk = lane >> 4;
  int n0 = blockIdx.x * 64;
  int g = n0 >> 9;
  int sw = (lr & 7) << 4;
  char* Sc = (char*)x3s;
  const ushort_t* Ab = xrb + (size_t)(n0 + w*16 + lr)*256 + lk*8;
  int c0 = w * 64;
  f32x4 acc[4][4];
  #pragma unroll
  for (int ri = 0; ri < 4; ++ri)
    #pragma unroll
    for (int ci = 0; ci < 4; ++ci) acc[ri][ci] = (f32x4){0.f,0.f,0.f,0.f};
  for (int hd = 0; hd < 4; ++hd){
    // ---- phase A: hs rows w*16..+15 for head hd (K=64), A direct from global bf16 ----
    f32x4 acc2[4];
    #pragma unroll
    for (int ci = 0; ci < 4; ++ci) acc2[ci] = (f32x4){0.f,0.f,0.f,0.f};
    #pragma unroll
    for (int k0 = 0; k0 < 64; k0 += 32){
      bf16x8 af = *(const bf16x8*)(Ab + hd*64 + k0);
      #pragma unroll
      for (int ci = 0; ci < 4; ++ci){
        bf16x8 bfv = *(const bf16x8*)(Wp2t + (size_t)(ci*16 + lr)*64 + k0 + lk*8);
        acc2[ci] = __builtin_amdgcn_mfma_f32_16x16x32_bf16(af, bfv, acc2[ci], 0, 0, 0);
      }
    }
    #pragma unroll
    for (int ci = 0; ci < 4; ++ci){
      int col = ci*16 + lr;
      float hc = hc2[g*64 + col];
      #pragma unroll
      for (int q = 0; q < 4; ++q){
        int row = w*16 + lk*4 + q;
        int swr = (row & 7) << 4;
        float a = acc2[ci][q];
        float gg = sigmoidf_(a + hc);
        *(ushort_t*)(Sc + ((row*256 + col*2) ^ swr))        = f2b(gg*a + (1.f-gg)*hc);
        *(ushort_t*)(Sc + ((row*256 + (64 + col)*2) ^ swr)) = f2b(a);
      }
    }
    __syncthreads();
    // ---- phase B: K-slab 128 of the GAT GEMM, wave = output head ----
    #pragma unroll
    for (int k0 = 0; k0 < 128; k0 += 32){
      bf16x8 af[4], bfv[4];
      #pragma unroll
      for (int ri = 0; ri < 4; ++ri){
        int lg = (ri*16 + lr)*256 + (k0 + lk*8)*2;
        af[ri] = *(const bf16x8*)(Sc + (lg ^ sw));
      }
      #pragma unroll
      for (int ci = 0; ci < 4; ++ci)
        bfv[ci] = *(const bf16x8*)(W2t + (size_t)(c0 + ci*16 + lr)*512 + hd*128 + k0 + lk*8);
      #pragma unroll
      for (int ri = 0; ri < 4; ++ri)
        #pragma unroll
        for (int ci = 0; ci < 4; ++ci)
          acc[ri][ci] = __builtin_amdgcn_mfma_f32_16x16x32_bf16(af[ri], bfv[ci], acc[ri][ci], 0, 0, 0);
    }
    if (hd < 3) __syncthreads();
  }
  float as_[4], ad_[4];
  #pragma unroll
  for (int ci = 0; ci < 4; ++ci){
    as_[ci] = att_s[c0 + ci*16 + lr];
    ad_[ci] = att_d[c0 + ci*16 + lr];
  }
  #pragma unroll
  for (int ri = 0; ri < 4; ++ri){
    #pragma unroll
    for (int q = 0; q < 4; ++q){
      int row = n0 + ri*16 + lk*4 + q;
      float ps = 0.f, pd = 0.f;
      #pragma unroll
      for (int ci = 0; ci < 4; ++ci){
        float v = acc[ri][ci][q];
        Hout[(size_t)row*256 + c0 + ci*16 + lr] = f2b(v);
        ps = fmaf(v, as_[ci], ps);
        pd = fmaf(v, ad_[ci], pd);
      }
      #pragma unroll
      for (int m = 1; m < 16; m <<= 1){
        ps += __shfl_xor(ps, m);
        pd += __shfl_xor(pd, m);
      }
      if (lr == 0){
        asrc[(size_t)row*4 + w] = ps;
        adst[(size_t)row*4 + w] = pd;
      }
    }
  }
}

// ---------------- CSR build ----------------
__global__ void k_count(const int* __restrict__ ei, int* __restrict__ deg){
  int t = blockIdx.x*256 + threadIdx.x;
  int s = ei[t], d = ei[EE + t];
  atomicAdd(&deg[d], 1);
  atomicAdd(&deg[s], 1);
}

__global__ void k_scan1(const int* __restrict__ deg, int* __restrict__ offa,
                        int* __restrict__ bsum){
  __shared__ int sm[256];
  int tid = threadIdx.x, idx = blockIdx.x*256 + tid;
  int v = deg[idx] + 1;                 // +1 self-loop
  sm[tid] = v; __syncthreads();
  for (int o = 1; o < 256; o <<= 1){
    int t = (tid >= o) ? sm[tid-o] : 0;
    __syncthreads();
    sm[tid] += t;
    __syncthreads();
  }
  offa[idx] = sm[tid] - v;
  if (tid == 255) bsum[blockIdx.x] = sm[255];
}

__global__ void k_scan2(int* __restrict__ bsum){
  __shared__ int sm[256];
  int tid = threadIdx.x;
  int v = bsum[tid];
  sm[tid] = v; __syncthreads();
  for (int o = 1; o < 256; o <<= 1){
    int t = (tid >= o) ? sm[tid-o] : 0;
    __syncthreads();
    sm[tid] += t;
    __syncthreads();
  }
  bsum[tid] = sm[tid] - v;
}

__global__ void k_scan3(int* __restrict__ offa, const int* __restrict__ bsum){
  int idx = blockIdx.x*256 + threadIdx.x;
  offa[idx] += bsum[idx >> 8];
}

__global__ void k_fill(const int* __restrict__ ei, const int* __restrict__ offa,
                       int* __restrict__ cur, int* __restrict__ elist){
  int t = blockIdx.x*256 + threadIdx.x;
  int s = ei[t], d = ei[EE + t];
  int p = atomicAdd(&cur[d], 1); elist[offa[d] + p] = s;   // TD edge
  p = atomicAdd(&cur[s], 1);     elist[offa[s] + p] = d;   // BU (flipped) edge
  p = atomicAdd(&cur[t], 1);     elist[offa[t] + p] = t;   // self-loop (E==N)
}

// ------ GAT softmax-aggregate (h bf16); XCD-swizzled; e-values cached in LDS ------
template<int LAYER>
__global__ __launch_bounds__(256) void k_agg(const int* __restrict__ offa,
                                             const int* __restrict__ deg,
                                             const int* __restrict__ elist,
                                             const ushort_t* __restrict__ h,  // [N,256] bf16
                                             const float* __restrict__ asrc,
                                             const float* __restrict__ adst,
                                             const float* __restrict__ bias,
                                             ushort_t* __restrict__ outb,
                                             float* __restrict__ outf){
  __shared__ float eS[4][4][17][4];     // [wave][grp][edge(pad17)][head]
  __shared__ int   sS[4][4][17];
  int bid = blockIdx.x;
  int swz = (bid & 7) * (4096/8) + (bid >> 3);   // XCD-contiguous graphs
  int tid = threadIdx.x;
  int wave = tid >> 6, lane = tid & 63;
  int grp = lane >> 4, l = lane & 15;
  int n = swz*16 + wave*4 + grp;
  int o0 = offa[n], cnt = deg[n] + 1;
  float4 adv = *(const float4*)&adst[(size_t)n*4];
  float ad[4] = {adv.x, adv.y, adv.z, adv.w};
  int lim = (cnt < 16) ? cnt : 16;
  int s_l = elist[o0 + ((l < cnt) ? l : 0)];
  float4 asv = *(const float4*)&asrc[(size_t)s_l*4];
  float e_l[4];
  e_l[0] = lrelu_(asv.x + ad[0]); e_l[1] = lrelu_(asv.y + ad[1]);
  e_l[2] = lrelu_(asv.z + ad[2]); e_l[3] = lrelu_(asv.w + ad[3]);
  if (l < lim){
    sS[wave][grp][l] = s_l;
    *(float4*)&eS[wave][grp][l][0] = make_float4(e_l[0], e_l[1], e_l[2], e_l[3]);
  }
  float m[4];
  #pragma unroll
  for (int hh = 0; hh < 4; ++hh) m[hh] = (l < cnt) ? e_l[hh] : -1e30f;
  for (int i = 16 + l; i < cnt; i += 16){
    int s = elist[o0 + i];
    float4 a2 = *(const float4*)&asrc[(size_t)s*4];
    m[0] = fmaxf(m[0], lrelu_(a2.x + ad[0]));
    m[1] = fmaxf(m[1], lrelu_(a2.y + ad[1]));
    m[2] = fmaxf(m[2], lrelu_(a2.z + ad[2]));
    m[3] = fmaxf(m[3], lrelu_(a2.w + ad[3]));
  }
  #pragma unroll
  for (int mask = 1; mask < 16; mask <<= 1)
    #pragma unroll
    for (int hh = 0; hh < 4; ++hh) m[hh] = fmaxf(m[hh], __shfl_xor(m[hh], mask));
  int myh = l >> 2;
  float mm = m[myh];
  float den = 0.f;
  float accv[16] = {};
  for (int i = 0; i < lim; ++i){
    int s = sS[wave][grp][i];
    float e = eS[wave][grp][i][myh];
    float ex = __expf(e - mm);
    den += ex;
    const uint4* hp = (const uint4*)(h + (size_t)s*256 + l*16);
    uint4 h0 = hp[0], h1v = hp[1];
    uint_t uu[8] = {h0.x, h0.y, h0.z, h0.w, h1v.x, h1v.y, h1v.z, h1v.w};
    #pragma unroll
    for (int r = 0; r < 8; ++r){
      accv[2*r+0] = fmaf(ex, b2f(uu[r] & 0xffffu), accv[2*r+0]);
      accv[2*r+1] = fmaf(ex, b2f(uu[r] >> 16),     accv[2*r+1]);
    }
  }
  for (int i = 16; i < cnt; ++i){
    int s = elist[o0 + i];
    float4 a2 = *(const float4*)&asrc[(size_t)s*4];
    float e = lrelu_(((const float*)&a2)[myh] + ad[myh]);
    float ex = __expf(e - mm);
    den += ex;
    const uint4* hp = (const uint4*)(h + (size_t)s*256 + l*16);
    uint4 h0 = hp[0], h1v = hp[1];
    uint_t uu[8] = {h0.x, h0.y, h0.z, h0.w, h1v.x, h1v.y, h1v.z, h1v.w};
    #pragma unroll
    for (int r = 0; r < 8; ++r){
      accv[2*r+0] = fmaf(ex, b2f(uu[r] & 0xffffu), accv[2*r+0]);
      accv[2*r+1] = fmaf(ex, b2f(uu[r] >> 16),     accv[2*r+1]);
    }
  }
  float inv = 1.0f / den;
  if (LAYER == 1){
    #pragma unroll
    for (int r = 0; r < 4; ++r){
      int c = l*16 + r*4;
      float4 bv = *(const float4*)&bias[c];
      float o0v = fmaxf(accv[r*4+0]*inv + bv.x, 0.f);
      float o1v = fmaxf(accv[r*4+1]*inv + bv.y, 0.f);
      float o2v = fmaxf(accv[r*4+2]*inv + bv.z, 0.f);
      float o3v = fmaxf(accv[r*4+3]*inv + bv.w, 0.f);
      uint2 pk;
      pk.x = (uint_t)f2b(o0v) | ((uint_t)f2b(o1v) << 16);
      pk.y = (uint_t)f2b(o2v) | ((uint_t)f2b(o3v) << 16);
      *(uint2*)&outb[(size_t)n*256 + c] = pk;
    }
  } else {
    #pragma unroll
    for (int r = 0; r < 16; ++r) accv[r] *= inv;
    #pragma unroll
    for (int r = 0; r < 16; ++r){
      accv[r] += __shfl_xor(accv[r], 4);
      accv[r] += __shfl_xor(accv[r], 8);
    }
    if (l < 4){
      #pragma unroll
      for (int r = 0; r < 4; ++r){
        int c = l*16 + r*4;
        float4 bv = *(const float4*)&bias[c];
        float4 o;
        o.x = fmaxf(accv[r*4+0]*0.25f + bv.x, 0.f);
        o.y = fmaxf(accv[r*4+1]*0.25f + bv.y, 0.f);
        o.z = fmaxf(accv[r*4+2]*0.25f + bv.z, 0.f);
        o.w = fmaxf(accv[r*4+3]*0.25f + bv.w, 0.f);
        *(float4*)&outf[(size_t)n*64 + c] = o;
      }
    }
  }
}

// ---- pool via MFMA (k_base fused): block = 64 nodes x 64 outputs, K=192 ----
__global__ __launch_bounds__(256) void k_pool_mfma(
    const float* __restrict__ xr2,      // [N,64] f32
    const ushort_t* __restrict__ Wfct,  // [64,192] bf16 (W_fc[64:256]^T)
    const float* __restrict__ Wfc,      // [256,64] f32 (rows 0..63 used)
    const float* __restrict__ bfc,
    float* __restrict__ shat,
    float* __restrict__ ssum){
  __shared__ __align__(16) float xs[64][68];
  __shared__ float rls[64];
  __shared__ float bs[64];
  __shared__ float ls_sh[64];
  __shared__ float ls_s[64];
  int tid = threadIdx.x;
  int n0 = blockIdx.x * 64;
  int g = n0 >> 9;
  {
    int row = tid >> 4, col4 = (tid & 15) * 4;
    #pragma unroll
    for (int i = 0; i < 4; ++i){
      float4 v = *(const float4*)&xr2[(size_t)(n0 + row + i*16)*64 + col4];
      *(float4*)&xs[row + i*16][col4] = v;
    }
    if (tid < 16){
      float4 v = *(const float4*)&xr2[(size_t)((size_t)g*GGR)*64 + tid*4];
      *(float4*)&rls[tid*4] = v;
    }
    if (tid >= 128 && tid < 192){ ls_sh[tid-128] = 0.f; ls_s[tid-128] = 0.f; }
  }
  __syncthreads();
  if (tid < 64){
    float b = bfc[tid];
    for (int j = 0; j < 64; ++j) b = fmaf(rls[j], Wfc[j*64 + tid], b);
    bs[tid] = b;
  }
  __syncthreads();
  int w = tid >> 6, lane = tid & 63;
  int lr = lane & 15, lk = lane >> 4;
  f32x4 acc[4];
  #pragma unroll
  for (int ci = 0; ci < 4; ++ci) acc[ci] = (f32x4){0.f,0.f,0.f,0.f};
  int arow = w*16 + lr;
  #pragma unroll
  for (int k0 = 0; k0 < 192; k0 += 32){
    int seg = k0 >> 6;
    int cb = (k0 & 63) + lk*8;
    bf16x8 af;
    #pragma unroll
    for (int j = 0; j < 8; ++j){
      float xv = xs[arow][cb + j];
      float rv = rls[cb + j];
      float v = (seg == 0) ? xv : (seg == 1 ? xv*rv : fabsf(rv - xv));
      af[j] = (short)f2b(v);
    }
    #pragma unroll
    for (int ci = 0; ci < 4; ++ci){
      bf16x8 bfv = *(const bf16x8*)(Wfct + (size_t)(ci*16+lr)*192 + k0 + lk*8);
      acc[ci] = __builtin_amdgcn_mfma_f32_16x16x32_bf16(af, bfv, acc[ci], 0, 0, 0);
    }
  }
  float bsv[4];
  #pragma unroll
  for (int ci = 0; ci < 4; ++ci) bsv[ci] = bs[ci*16 + lr];
  float c_sh[4] = {0.f,0.f,0.f,0.f}, c_s[4] = {0.f,0.f,0.f,0.f};
  #pragma unroll
  for (int q = 0; q < 4; ++q){
    int rrow = w*16 + lk*4 + q;
    float t[4];
    float mx = -1e30f;
    #pragma unroll
    for (int ci = 0; ci < 4; ++ci){
      t[ci] = tanhf_(acc[ci][q] + bsv[ci]);
      mx = fmaxf(mx, t[ci]);
    }
    #pragma unroll
    for (int mask = 1; mask < 16; mask <<= 1) mx = fmaxf(mx, __shfl_xor(mx, mask));
    float e[4], s = 0.f;
    #pragma unroll
    for (int ci = 0; ci < 4; ++ci){ e[ci] = __expf(t[ci] - mx); s += e[ci]; }
    #pragma unroll
    for (int mask = 1; mask < 16; mask <<= 1) s += __shfl_xor(s, mask);
    float invs = 1.0f / s;
    #pragma unroll
    for (int ci = 0; ci < 4; ++ci){
      float xv = xs[rrow][ci*16 + lr];
      c_sh[ci] = fmaf(e[ci]*invs, xv, c_sh[ci]);
      c_s[ci] += xv;
    }
  }
  #pragma unroll
  for (int ci = 0; ci < 4; ++ci){
    c_sh[ci] += __shfl_xor(c_sh[ci], 16); c_sh[ci] += __shfl_xor(c_sh[ci], 32);
    c_s[ci]  += __shfl_xor(c_s[ci], 16);  c_s[ci]  += __shfl_xor(c_s[ci], 32);
  }
  if (lk == 0){
    #pragma unroll
    for (int ci = 0; ci < 4; ++ci){
      atomicAdd(&ls_sh[ci*16 + lr], c_sh[ci]);
      atomicAdd(&ls_s[ci*16 + lr], c_s[ci]);
    }
  }
  __syncthreads();
  if (tid < 64){
    atomicAdd(&shat[g*64 + tid], ls_sh[tid]);
    atomicAdd(&ssum[g*64 + tid], ls_s[tid]);
  }
}

// ------------- final logits + log_softmax -------------
__global__ void k_final(const float* __restrict__ shat, const float* __restrict__ ssum,
                        const float* __restrict__ Wc, const float* __restrict__ bc,
                        float* __restrict__ outp){
  int g = threadIdx.x;   // 128 graphs
  float l0 = bc[0], l1 = bc[1], l2 = bc[2], l3 = bc[3];
  const float s512 = 1.0f/512.0f;
  for (int j = 0; j < 64; ++j){
    float sh = shat[g*64 + j]*s512;
    float ss = ssum[g*64 + j]*s512;
    float4 w1 = *(const float4*)&Wc[j*4];
    float4 w2 = *(const float4*)&Wc[(64+j)*4];
    l0 = fmaf(sh, w1.x, fmaf(ss, w2.x, l0));
    l1 = fmaf(sh, w1.y, fmaf(ss, w2.y, l1));
    l2 = fmaf(sh, w1.z, fmaf(ss, w2.z, l2));
    l3 = fmaf(sh, w1.w, fmaf(ss, w2.w, l3));
  }
  float mx = fmaxf(fmaxf(l0,l1), fmaxf(l2,l3));
  float s = __expf(l0-mx)+__expf(l1-mx)+__expf(l2-mx)+__expf(l3-mx);
  float lse = mx + logf(s);
  outp[g*4+0] = l0 - lse;
  outp[g*4+1] = l1 - lse;
  outp[g*4+2] = l2 - lse;
  outp[g*4+3] = l3 - lse;
}

extern "C" void kernel_launch(void* const* d_in, const int* in_sizes, int n_in,
                              void* d_out, int out_size, void* d_ws, size_t ws_size,
                              hipStream_t stream){
  const float* x        = (const float*)d_in[0];
  const float* root     = (const float*)d_in[1];
  const int*   ei       = (const int*)d_in[2];
  const float* W_post1  = (const float*)d_in[5];
  const float* W_claim1 = (const float*)d_in[6];
  const float* W1       = (const float*)d_in[7];
  const float* att_src1 = (const float*)d_in[8];
  const float* att_dst1 = (const float*)d_in[9];
  const float* b1       = (const float*)d_in[10];
  const float* W_post2  = (const float*)d_in[11];
  const float* W_claim2 = (const float*)d_in[12];
  const float* W2       = (const float*)d_in[13];
  const float* att_src2 = (const float*)d_in[14];
  const float* att_dst2 = (const float*)d_in[15];
  const float* b2       = (const float*)d_in[16];
  const float* W_fc     = (const float*)d_in[17];
  const float* b_fc     = (const float*)d_in[18];
  const float* W_clf    = (const float*)d_in[19];
  const float* b_clf    = (const float*)d_in[20];
  float* out = (float*)d_out;

  char* w = (char*)d_ws;
  size_t o = 0;
  auto alloc = [&](size_t bytes)->char*{ char* p = w + o; o += (bytes + 255) & ~(size_t)255; return p; };
  ushort_t* RB   = (ushort_t*)alloc((size_t)NN*256*2);   // h2b then h3b
  ushort_t* xrb  = (ushort_t*)alloc((size_t)NN*256*2);
  float* xr2  = (float*)alloc((size_t)NN*64*4);
  float* asrc = (float*)alloc((size_t)NN*4*4);
  float* adst = (float*)alloc((size_t)NN*4*4);
  float* hc1  = (float*)alloc(128*64*4);
  float* hc2  = (float*)alloc(128*64*4);
  ushort_t* W1t  = (ushort_t*)alloc((size_t)256*128*2);
  ushort_t* W2t  = (ushort_t*)alloc((size_t)256*512*2);
  ushort_t* Wp1t = (ushort_t*)alloc((size_t)64*512*2);
  ushort_t* Wp2t = (ushort_t*)alloc((size_t)64*64*2);
  ushort_t* Wfct = (ushort_t*)alloc((size_t)64*192*2);
  int*   deg  = (int*)alloc((size_t)NN*4);
  int*   cur  = (int*)alloc((size_t)NN*4);      // adjacent to deg: one memset
  int*   offa = (int*)alloc((size_t)NN*4);
  int*   bsum = (int*)alloc(256*4);
  int*   elist= (int*)alloc((size_t)(2*EE+NN)*4);
  float* shat = (float*)alloc(128*64*4);
  float* ssumv= (float*)alloc(128*64*4);        // adjacent to shat: one memset

  ushort_t* h2b = RB;    // [N,256] bf16
  ushort_t* h3b = RB;    // [N,256] bf16 (h2b dead by then)

  hipMemsetAsync(deg,  0, (size_t)NN*8, stream);     // deg + cur
  hipMemsetAsync(shat, 0, 2*128*64*4, stream);       // shat + ssumv

  k_prep<<<960, 256, 0, stream>>>(W1, W2, W_post1, W_post2, W_fc,
                                  W1t, W2t, Wp1t, Wp2t, Wfct,
                                  root, W_claim1, W_claim2, hc1, hc2);
  k_count<<<256, 256, 0, stream>>>(ei, deg);
  k_scan1<<<256, 256, 0, stream>>>(deg, offa, bsum);
  k_scan2<<<1, 256, 0, stream>>>(bsum);
  k_scan3<<<256, 256, 0, stream>>>(offa, bsum);
  k_fill<<<256, 256, 0, stream>>>(ei, offa, cur, elist);
  k_l1<<<1024, 256, 0, stream>>>(x, Wp1t, hc1, W1t, att_src1, att_dst1, h2b, asrc, adst);
  k_agg<1><<<4096, 256, 0, stream>>>(offa, deg, elist, h2b, asrc, adst, b1, xrb, nullptr);
  k_l2<<<1024, 256, 0, stream>>>(xrb, Wp2t, hc2, W2t, att_src2, att_dst2, h3b, asrc, adst);
  k_agg<2><<<4096, 256, 0, stream>>>(offa, deg, elist, h3b, asrc, adst, b2, nullptr, xr2);
  k_pool_mfma<<<1024, 256, 0, stream>>>(xr2, Wfct, W_fc, b_fc, shat, ssumv);
  k_final<<<1, 128, 0, stream>>>(shat, ssumv, W_clf, b_clf, out);
  (void)in_sizes; (void)n_in; (void)out_size; (void)ws_size;
}